// Round 7
// baseline (394.945 us; speedup 1.0000x reference)
//
#include <hip/hip_runtime.h>
#include <math.h>

#define NN 200000
#define EEDGE 500000
#define BB 4096
#define KK 20
#define MM 100000
#define Q3 (3*BB)

typedef _Float16 __attribute__((ext_vector_type(8))) f16x8;
typedef _Float16 __attribute__((ext_vector_type(4))) f16x4;
typedef _Float16 __attribute__((ext_vector_type(2))) f16x2;
typedef float __attribute__((ext_vector_type(4))) f32x4;

#define MFMA16(a,b,c) __builtin_amdgcn_mfma_f32_16x16x32_f16(a,b,c,0,0,0)

// cos(a) for |a| up to ~1e7: f64 range-reduction to revolutions + v_cos_f32.
__device__ __forceinline__ float fast_cos(float a) {
    double ad = (double)a * 0.15915494309189535;   // 1/(2*pi)
    double fr = ad - floor(ad);                    // [0,1) revolutions
    return __builtin_amdgcn_cosf((float)fr);       // cos(2*pi*x)
}

// time encoding matching numpy's f32 arg rounding — NO fma contraction.
__device__ __forceinline__ float tenc(float dt, float w, float b) {
    float p = __fmul_rn(dt, w);
    float a = __fadd_rn(p, b);
    return fast_cos(a);
}

__device__ __forceinline__ float fsigm(float x) {
    return __builtin_amdgcn_rcpf(1.f + __expf(-x));
}
__device__ __forceinline__ float ftanh(float x) {
    return 1.f - 2.f * __builtin_amdgcn_rcpf(1.f + __expf(2.f * x));
}

__device__ __forceinline__ f32x4 z4() {
    f32x4 v; v[0] = 0.f; v[1] = 0.f; v[2] = 0.f; v[3] = 0.f; return v;
}

__global__ void k_init(int* lastpos, int* inv, int* count) {
    int i = blockIdx.x * 256 + threadIdx.x;
    if (i < NN) { lastpos[i] = -1; inv[i] = -1; }
    if (i == 0) *count = 0;
}

__global__ void k_scatter(const int* __restrict__ msg_src, int* __restrict__ lastpos) {
    int i = blockIdx.x * 256 + threadIdx.x;
    if (i < MM) atomicMax(&lastpos[msg_src[i]], i);
}

__global__ void k_compact(const int* __restrict__ lastpos, int* __restrict__ inv,
                          int* __restrict__ comp, int* __restrict__ count) {
    int n = blockIdx.x * 256 + threadIdx.x;
    if (n < NN && lastpos[n] >= 0) {
        int j = atomicAdd(count, 1);
        comp[j] = n;
        inv[n] = j;
    }
}

// f32 -> f16 weight conversion into MFMA FRAGMENT ORDER (stage1 + merge mats):
// elem offset = matbase + ((cgrp*KS + ks)*64 + lane)*8 + e
__global__ void k_cvtw(const float* __restrict__ W1, const float* __restrict__ W2,
                       const float* __restrict__ Wi, const float* __restrict__ Wh,
                       const float* __restrict__ mW1, const float* __restrict__ mW2,
                       _Float16* __restrict__ dst) {
    int f = blockIdx.x * 256 + threadIdx.x;   // fragment id, 40960 total
    if (f >= 40960) return;
    const float* src; int dstoff, K, lf;
    if      (f < 16384) { src = W1;  dstoff = 0;      K = 512; lf = f; }
    else if (f < 20480) { src = W2;  dstoff = 131072; K = 256; lf = f - 16384; }
    else if (f < 26624) { src = Wi;  dstoff = 163840; K = 128; lf = f - 20480; }
    else if (f < 32768) { src = Wh;  dstoff = 212992; K = 128; lf = f - 26624; }
    else if (f < 38912) { src = mW1; dstoff = 262144; K = 384; lf = f - 32768; }
    else                { src = mW2; dstoff = 311296; K = 128; lf = f - 38912; }
    int KS = K >> 5;
    int cgrp = lf / (KS * 64);
    int rem  = lf - cgrp * (KS * 64);
    int ks = rem >> 6, lane = rem & 63;
    int kg = lane >> 4, arow = lane & 15;
    int col = cgrp * 16 + arow;
    int k0 = ks * 32 + kg * 8;
    const float* p = src + (size_t)col * K + k0;
    float4 a = *(const float4*)p;
    float4 b = *(const float4*)(p + 4);
    f16x8 h;
    h[0] = (_Float16)a.x; h[1] = (_Float16)a.y; h[2] = (_Float16)a.z; h[3] = (_Float16)a.w;
    h[4] = (_Float16)b.x; h[5] = (_Float16)b.y; h[6] = (_Float16)b.z; h[7] = (_Float16)b.w;
    *(f16x8*)(dst + dstoff + (size_t)lf * 8) = h;
}

// k_fold: build folded attention matrices (f32 math, f16 fragment-order out).
//  QKW_h[c][j] = sum_d Wq[(h*128+d)*256+c] * Wk[(h*128+d)*384+j]   (B for qk GEMM, K=256,N=384/head)
//  B2_h[j]     = sum_d bq[h*128+d] * Wk[(h*128+d)*384+j]
//  WoV[o][h*384+j] = sum_d Wo[o*256+h*128+d] * Wv[(h*128+d)*384+j] (B for ov GEMM, K=768,N=256)
//  bo2[o]      = bo[o] + sum_k Wo[o*256+k]*bv[k]
//  wqbk_h[c]   = sum_d Wq[(h*128+d)*256+c]*bk[h*128+d];  bqbk_h = bq_h.bk_h
__global__ __launch_bounds__(256)
void k_fold(const float* __restrict__ Wq, const float* __restrict__ bq,
            const float* __restrict__ Wk, const float* __restrict__ bk,
            const float* __restrict__ Wv, const float* __restrict__ bv,
            const float* __restrict__ Wo, const float* __restrict__ bo,
            _Float16* __restrict__ QKW, _Float16* __restrict__ WoV,
            float* __restrict__ B2, float* __restrict__ wqbk,
            float* __restrict__ bqbk, float* __restrict__ bo2)
{
    int b = blockIdx.x, t = threadIdx.x;
    if (b < 768) {
        int h = b / 384, j = b % 384;
        __shared__ float wk[128];
        if (t < 128) wk[t] = Wk[(size_t)(h * 128 + t) * 384 + j];
        __syncthreads();
        float acc = 0.f;
        #pragma unroll 4
        for (int d = 0; d < 128; d++)
            acc += Wq[(size_t)(h * 128 + d) * 256 + t] * wk[d];
        int cgrp = j >> 4, arow = j & 15, ks = t >> 5, kg = (t >> 3) & 3, e = t & 7;
        int lane = kg * 16 + arow;
        QKW[(size_t)h * 98304 + (((size_t)cgrp * 8 + ks) * 64 + lane) * 8 + e] = (_Float16)acc;
        if (t == 0) {
            float a2 = 0.f;
            for (int d = 0; d < 128; d++) a2 += bq[h * 128 + d] * wk[d];
            B2[h * 384 + j] = a2;
        }
    } else if (b < 1024) {
        int o = b - 768;
        __shared__ float wo[256];
        wo[t] = Wo[(size_t)o * 256 + t];
        __syncthreads();
        #pragma unroll
        for (int it = 0; it < 3; it++) {
            int hj = t + it * 256;
            int h = hj / 384, j = hj % 384;
            float acc = 0.f;
            #pragma unroll 4
            for (int d = 0; d < 128; d++)
                acc += wo[h * 128 + d] * Wv[(size_t)(h * 128 + d) * 384 + j];
            int cgrp = o >> 4, arow = o & 15, ks = hj >> 5, kg = (hj >> 3) & 3, e = hj & 7;
            int lane = kg * 16 + arow;
            WoV[(((size_t)cgrp * 24 + ks) * 64 + lane) * 8 + e] = (_Float16)acc;
        }
        if (t == 0) {
            float a2 = bo[o];
            for (int k = 0; k < 256; k++) a2 += wo[k] * bv[k];
            bo2[o] = a2;
        }
    } else {
        int h = b - 1024;
        float acc = 0.f;
        #pragma unroll 4
        for (int d = 0; d < 128; d++)
            acc += Wq[(size_t)(h * 128 + d) * 256 + t] * bk[h * 128 + d];
        wqbk[h * 256 + t] = acc;
        if (t == 0) {
            float a2 = 0.f;
            for (int d = 0; d < 128; d++) a2 += bq[h * 128 + d] * bk[h * 128 + d];
            bqbk[h] = a2;
        }
    }
}

// ---------------- Stage 1: 64 rows/block, 512 threads / 8 waves ----------------
__device__ __forceinline__ int SWA(int r, int byteofs) {
    return r * 1024 + (byteofs ^ ((r & 7) << 4));
}

__device__ __forceinline__ f16x8 ldw4(const _Float16* W, int cg, int ks, int lane) {
    return *(const f16x8*)(W + (((size_t)cg * 4 + ks) * 64 + lane) * 8);
}

__global__ __launch_bounds__(512, 4)
void k_stage1(const int* __restrict__ comp, const int* __restrict__ count,
              const int* __restrict__ lastpos,
              const int* __restrict__ msg_dst, const int* __restrict__ msg_eidx,
              const int* __restrict__ msg_t, const int* __restrict__ last_update,
              const float* __restrict__ memory, const float* __restrict__ edge_feats,
              const float* __restrict__ time_w, const float* __restrict__ time_b,
              const _Float16* __restrict__ W1h, const float* __restrict__ b1,
              const _Float16* __restrict__ W2h, const float* __restrict__ b2,
              const _Float16* __restrict__ Wih, const _Float16* __restrict__ Whh,
              const float* __restrict__ bi, const float* __restrict__ bh,
              _Float16* __restrict__ new_mem)
{
    __shared__ char rawb[64 * 1024];
    __shared__ int sn[64], sd[64], se[64];
    __shared__ float sdt[64];

    int cnt = *count;
    int r0 = blockIdx.x * 64;
    if (r0 >= cnt) return;
    int tid = threadIdx.x;

    if (tid < 64) {
        int rr = r0 + tid;
        int j = (rr < cnt) ? rr : r0;
        int n = comp[j];
        int idx = lastpos[n];
        sn[tid] = n;
        sd[tid] = msg_dst[idx];
        se[tid] = msg_eidx[idx];
        sdt[tid] = (float)(msg_t[idx] - last_update[n]);
    }
    __syncthreads();

    // data pass: 64 rows x 48 granules (mem[n] | mem[d] | edge)
    #pragma unroll
    for (int it = 0; it < 6; it++) {
        int gi = tid + it * 512;
        int r = gi / 48, g = gi - r * 48;
        const float* src;
        if (g < 16)      src = memory + (size_t)sn[r] * 128 + g * 8;
        else if (g < 32) src = memory + (size_t)sd[r] * 128 + (g - 16) * 8;
        else             src = edge_feats + (size_t)se[r] * 128 + (g - 32) * 8;
        float4 a = *(const float4*)src;
        float4 b = *(const float4*)(src + 4);
        f16x8 h;
        h[0] = (_Float16)a.x; h[1] = (_Float16)a.y; h[2] = (_Float16)a.z; h[3] = (_Float16)a.w;
        h[4] = (_Float16)b.x; h[5] = (_Float16)b.y; h[6] = (_Float16)b.z; h[7] = (_Float16)b.w;
        *(f16x8*)(rawb + SWA(r, g * 16)) = h;
    }
    // tenc pass: 64 rows x 16 granules
    #pragma unroll
    for (int it = 0; it < 2; it++) {
        int gi = tid + it * 512;
        int r = gi >> 4, g = gi & 15;
        int c = g * 8;
        float dt = sdt[r];
        float4 w0 = *(const float4*)(time_w + c);
        float4 w1 = *(const float4*)(time_w + c + 4);
        float4 t0 = *(const float4*)(time_b + c);
        float4 t1 = *(const float4*)(time_b + c + 4);
        f16x8 h;
        h[0] = (_Float16)tenc(dt, w0.x, t0.x); h[1] = (_Float16)tenc(dt, w0.y, t0.y);
        h[2] = (_Float16)tenc(dt, w0.z, t0.z); h[3] = (_Float16)tenc(dt, w0.w, t0.w);
        h[4] = (_Float16)tenc(dt, w1.x, t1.x); h[5] = (_Float16)tenc(dt, w1.y, t1.y);
        h[6] = (_Float16)tenc(dt, w1.z, t1.z); h[7] = (_Float16)tenc(dt, w1.w, t1.w);
        *(f16x8*)(rawb + SWA(r, (48 + g) * 16)) = h;
    }
    __syncthreads();

    int wv = tid >> 6, lane = tid & 63;
    int arow = lane & 15, kg = lane >> 4;

    // GEMM1: h1[64][256], K=512; wave owns 2 col-groups; depth-1 B prefetch
    f32x4 acc1[2][4];
    #pragma unroll
    for (int c = 0; c < 2; c++)
        #pragma unroll
        for (int rt = 0; rt < 4; rt++) acc1[c][rt] = z4();
    {
        const _Float16* Wb0 = W1h + (((size_t)(wv * 2 + 0) * 16) * 64 + lane) * 8;
        const _Float16* Wb1 = W1h + (((size_t)(wv * 2 + 1) * 16) * 64 + lane) * 8;
        f16x8 b0 = *(const f16x8*)Wb0;
        f16x8 b1 = *(const f16x8*)Wb1;
        for (int ks = 0; ks < 16; ks++) {
            f16x8 a[4];
            #pragma unroll
            for (int rt = 0; rt < 4; rt++)
                a[rt] = *(const f16x8*)(rawb + SWA(rt * 16 + arow, ks * 64 + kg * 16));
            int ksn = ks + 1 < 16 ? ks + 1 : 15;
            f16x8 nb0 = *(const f16x8*)(Wb0 + (size_t)ksn * 512);
            f16x8 nb1 = *(const f16x8*)(Wb1 + (size_t)ksn * 512);
            #pragma unroll
            for (int rt = 0; rt < 4; rt++) acc1[0][rt] = MFMA16(a[rt], b0, acc1[0][rt]);
            #pragma unroll
            for (int rt = 0; rt < 4; rt++) acc1[1][rt] = MFMA16(a[rt], b1, acc1[1][rt]);
            b0 = nb0; b1 = nb1;
        }
    }
    __syncthreads();

    #pragma unroll
    for (int c = 0; c < 2; c++) {
        int col = (wv * 2 + c) * 16 + arow;
        float bb = b1[col];
        #pragma unroll
        for (int rt = 0; rt < 4; rt++)
            #pragma unroll
            for (int rg = 0; rg < 4; rg++) {
                int row = rt * 16 + kg * 4 + rg;
                float v = fmaxf(acc1[c][rt][rg] + bb, 0.f);
                *(_Float16*)(rawb + SWA(row, 384 + col * 2)) = (_Float16)v;
            }
    }
    __syncthreads();

    // GEMM2: msg[64][128], K=256; depth-1 B prefetch
    f32x4 acc2[4];
    #pragma unroll
    for (int rt = 0; rt < 4; rt++) acc2[rt] = z4();
    {
        const _Float16* Wb = W2h + (((size_t)wv * 8) * 64 + lane) * 8;
        f16x8 b = *(const f16x8*)Wb;
        for (int ks = 0; ks < 8; ks++) {
            int ksn = ks + 1 < 8 ? ks + 1 : 7;
            f16x8 nb = *(const f16x8*)(Wb + (size_t)ksn * 512);
            #pragma unroll
            for (int rt = 0; rt < 4; rt++) {
                f16x8 a = *(const f16x8*)(rawb + SWA(rt * 16 + arow, 384 + ks * 64 + kg * 16));
                acc2[rt] = MFMA16(a, b, acc2[rt]);
            }
            b = nb;
        }
    }
    __syncthreads();

    {
        int col = wv * 16 + arow;
        float bb = b2[col];
        #pragma unroll
        for (int rt = 0; rt < 4; rt++)
            #pragma unroll
            for (int rg = 0; rg < 4; rg++) {
                int row = rt * 16 + kg * 4 + rg;
                *(_Float16*)(rawb + SWA(row, 384 + col * 2)) =
                    (_Float16)(acc2[rt][rg] + bb);
            }
    }
    __syncthreads();

    // GRU gates, one gate-pass at a time
    f32x4 aR[4], aZ[4], aNi[4], aNh[4];
    #pragma unroll
    for (int rt = 0; rt < 4; rt++) { aR[rt] = z4(); aZ[rt] = z4(); aNi[rt] = z4(); aNh[rt] = z4(); }
    for (int ks = 0; ks < 4; ks++) {   // r gate
        f16x8 bi_ = ldw4(Wih, wv, ks, lane);
        f16x8 bh_ = ldw4(Whh, wv, ks, lane);
        #pragma unroll
        for (int rt = 0; rt < 4; rt++) {
            f16x8 m = *(const f16x8*)(rawb + SWA(rt * 16 + arow, 384 + ks * 64 + kg * 16));
            f16x8 hh = *(const f16x8*)(rawb + SWA(rt * 16 + arow, ks * 64 + kg * 16));
            aR[rt] = MFMA16(m, bi_, aR[rt]);
            aR[rt] = MFMA16(hh, bh_, aR[rt]);
        }
    }
    for (int ks = 0; ks < 4; ks++) {   // z gate
        f16x8 bi_ = ldw4(Wih, 8 + wv, ks, lane);
        f16x8 bh_ = ldw4(Whh, 8 + wv, ks, lane);
        #pragma unroll
        for (int rt = 0; rt < 4; rt++) {
            f16x8 m = *(const f16x8*)(rawb + SWA(rt * 16 + arow, 384 + ks * 64 + kg * 16));
            f16x8 hh = *(const f16x8*)(rawb + SWA(rt * 16 + arow, ks * 64 + kg * 16));
            aZ[rt] = MFMA16(m, bi_, aZ[rt]);
            aZ[rt] = MFMA16(hh, bh_, aZ[rt]);
        }
    }
    for (int ks = 0; ks < 4; ks++) {   // n gates
        f16x8 bi_ = ldw4(Wih, 16 + wv, ks, lane);
        f16x8 bh_ = ldw4(Whh, 16 + wv, ks, lane);
        #pragma unroll
        for (int rt = 0; rt < 4; rt++) {
            f16x8 m = *(const f16x8*)(rawb + SWA(rt * 16 + arow, 384 + ks * 64 + kg * 16));
            f16x8 hh = *(const f16x8*)(rawb + SWA(rt * 16 + arow, ks * 64 + kg * 16));
            aNi[rt] = MFMA16(m, bi_, aNi[rt]);
            aNh[rt] = MFMA16(hh, bh_, aNh[rt]);
        }
    }

    {
        int col = wv * 16 + arow;
        float bir = bi[col],        bhr = bh[col];
        float biz = bi[128 + col],  bhz = bh[128 + col];
        float bin_ = bi[256 + col], bhn_ = bh[256 + col];
        #pragma unroll
        for (int rt = 0; rt < 4; rt++)
            #pragma unroll
            for (int rg = 0; rg < 4; rg++) {
                int row = rt * 16 + kg * 4 + rg;
                int rr = r0 + row;
                if (rr < cnt) {
                    float r_ = fsigm(aR[rt][rg] + bir + bhr);
                    float zg = fsigm(aZ[rt][rg] + biz + bhz);
                    float ng = ftanh(aNi[rt][rg] + bin_ + r_ * (aNh[rt][rg] + bhn_));
                    float om = (float)*(const _Float16*)(rawb + SWA(row, col * 2));
                    new_mem[(size_t)rr * 128 + col] = (_Float16)((1.f - zg) * ng + zg * om);
                }
            }
    }
}

// k_feat: feat[n] = (updated ? new_mem[inv[n]] : memory[n]) + node_feats[n], f16
__global__ __launch_bounds__(256)
void k_feat(const int* __restrict__ inv, const _Float16* __restrict__ new_mem,
            const float* __restrict__ memory, const float* __restrict__ node_feats,
            _Float16* __restrict__ feat)
{
    int idx = blockIdx.x * 256 + threadIdx.x;
    if (idx >= NN * 16) return;
    int n = idx >> 4, g = idx & 15;
    int c = g * 8;
    int iv = inv[n];
    float4 n0 = *(const float4*)(node_feats + (size_t)n * 128 + c);
    float4 n1 = *(const float4*)(node_feats + (size_t)n * 128 + c + 4);
    f16x8 o;
    if (iv >= 0) {
        f16x8 mv = *(const f16x8*)(new_mem + (size_t)iv * 128 + c);
        o[0] = (_Float16)((float)mv[0] + n0.x); o[1] = (_Float16)((float)mv[1] + n0.y);
        o[2] = (_Float16)((float)mv[2] + n0.z); o[3] = (_Float16)((float)mv[3] + n0.w);
        o[4] = (_Float16)((float)mv[4] + n1.x); o[5] = (_Float16)((float)mv[5] + n1.y);
        o[6] = (_Float16)((float)mv[6] + n1.z); o[7] = (_Float16)((float)mv[7] + n1.w);
    } else {
        float4 m0 = *(const float4*)(memory + (size_t)n * 128 + c);
        float4 m1 = *(const float4*)(memory + (size_t)n * 128 + c + 4);
        o[0] = (_Float16)(m0.x + n0.x); o[1] = (_Float16)(m0.y + n0.y);
        o[2] = (_Float16)(m0.z + n0.z); o[3] = (_Float16)(m0.w + n0.w);
        o[4] = (_Float16)(m1.x + n1.x); o[5] = (_Float16)(m1.y + n1.y);
        o[6] = (_Float16)(m1.z + n1.z); o[7] = (_Float16)(m1.w + n1.w);
    }
    *(f16x8*)(feat + (size_t)n * 128 + c) = o;
}

// ---------------- Stage 2 ----------------
__global__ void k2a(const int* __restrict__ src_nodes, const int* __restrict__ dst_nodes,
                    const int* __restrict__ neg_nodes, const _Float16* __restrict__ feat,
                    const float* __restrict__ time_b,
                    _Float16* __restrict__ q_in, _Float16* __restrict__ acat)
{
    __shared__ int snode[32];
    int tid = threadIdx.x;
    int r0 = blockIdx.x * 32;
    if (tid < 32) {
        int q = r0 + tid;
        snode[tid] = (q < BB) ? src_nodes[q] : (q < 2 * BB) ? dst_nodes[q - BB] : neg_nodes[q - 2 * BB];
    }
    __syncthreads();
    #pragma unroll
    for (int it = 0; it < 4; it++) {
        int gi = tid + it * 256;
        int r = gi >> 5, ch = gi & 31;
        int c = ch * 4;
        int node = snode[r];
        f16x4 sf = *(const f16x4*)(feat + (size_t)node * 128 + c);
        size_t q = (size_t)(r0 + r);
        *(f16x4*)(q_in + q * 256 + c) = sf;
        *(f16x4*)(acat + q * 384 + 256 + c) = sf;
        float4 tb = *(const float4*)(time_b + c);
        f16x4 te;
        te[0] = (_Float16)fast_cos(tb.x); te[1] = (_Float16)fast_cos(tb.y);
        te[2] = (_Float16)fast_cos(tb.z); te[3] = (_Float16)fast_cos(tb.w);
        *(f16x4*)(q_in + q * 256 + 128 + c) = te;
    }
}

// generic 32-row-tile MFMA GEMM, fragment-ordered B.
template<int KD, int NFRAG, bool RELU>
__global__ __launch_bounds__(256, 4)
void k_gemm(const _Float16* __restrict__ A, int lda, int a_ys,
            const _Float16* __restrict__ B, int b_ys,
            const float* __restrict__ bias, int bias_ys,
            _Float16* __restrict__ C, int ldc, int c_ys,
            float* __restrict__ C32,
            const int* __restrict__ rowmask)
{
    constexpr int ROWB = KD * 2;
    __shared__ char As[32 * ROWB];
    int tid = threadIdx.x;
    int r0 = blockIdx.x * 32;
    int aoff = blockIdx.y * a_ys;
    const _Float16* Bp = B + (size_t)blockIdx.y * b_ys;
    int coff = blockIdx.y * c_ys;

    #pragma unroll
    for (int t = 0; t < (32 * KD / 8) / 256; t++) {
        int gi = tid + t * 256;
        int r = gi / (KD / 8), g = gi % (KD / 8);
        f16x8 v = *(const f16x8*)(A + (size_t)(r0 + r) * lda + aoff + g * 8);
        *(f16x8*)(&As[r * ROWB + ((g * 16) ^ ((r & 7) << 4))]) = v;
    }
    __syncthreads();

    int wv = tid >> 6, lane = tid & 63;
    int arow = lane & 15, kg = lane >> 4;
    f32x4 acc[NFRAG][2];
    #pragma unroll
    for (int c = 0; c < NFRAG; c++) { acc[c][0] = z4(); acc[c][1] = z4(); }

    #pragma unroll
    for (int ks = 0; ks < KD / 32; ks++) {
        f16x8 a0 = *(const f16x8*)(&As[arow * ROWB + ((ks * 64 + kg * 16) ^ ((arow & 7) << 4))]);
        f16x8 a1 = *(const f16x8*)(&As[(16 + arow) * ROWB + ((ks * 64 + kg * 16) ^ ((arow & 7) << 4))]);
        #pragma unroll
        for (int c = 0; c < NFRAG; c++) {
            f16x8 b = *(const f16x8*)(Bp +
                (((size_t)(wv * NFRAG + c) * (KD / 32) + ks) * 64 + lane) * 8);
            acc[c][0] = MFMA16(a0, b, acc[c][0]);
            acc[c][1] = MFMA16(a1, b, acc[c][1]);
        }
    }

    #pragma unroll
    for (int c = 0; c < NFRAG; c++) {
        int cg = (wv * NFRAG + c) * 16 + arow;
        float bb = bias ? bias[blockIdx.y * bias_ys + cg] : 0.f;
        #pragma unroll
        for (int rt = 0; rt < 2; rt++)
            #pragma unroll
            for (int rg = 0; rg < 4; rg++) {
                int grow = r0 + rt * 16 + kg * 4 + rg;
                float v = acc[c][rt][rg] + bb;
                if (RELU) v = fmaxf(v, 0.f);
                if (rowmask && rowmask[grow]) v = 0.f;
                if (C)   C[(size_t)grow * ldc + coff + cg] = (_Float16)v;
                if (C32) C32[(size_t)grow * ldc + coff + cg] = v;
            }
    }
}

// k2d: attention core. 1 query per FULL wave (both heads share k-loads),
// lane owns 6 of 384 k_in elems; depth-1 pipelined gathers; no LDS/barriers.
__global__ __launch_bounds__(256)
void k2d(const int* __restrict__ neighbors, const int* __restrict__ nb_eidx,
         const int* __restrict__ nb_et, const int* __restrict__ edge_times,
         const _Float16* __restrict__ feat, const float* __restrict__ edge_feats,
         const float* __restrict__ time_w, const float* __restrict__ time_b,
         const float* __restrict__ wqbk, const float* __restrict__ bqbk,
         const _Float16* __restrict__ q_in, _Float16* __restrict__ qk_wsum,
         int* __restrict__ allm)
{
    int tid = threadIdx.x;
    int qi = blockIdx.x * 4 + (tid >> 6);
    int lane = tid & 63;
    int c2 = lane * 2;

    float tw0 = time_w[c2], tw1 = time_w[c2 + 1];
    float tb0 = time_b[c2], tb1 = time_b[c2 + 1];

    // qk coefficients: qh[h][6] (elems c2,c2+1 of each 128-segment)
    const _Float16* qkrow = qk_wsum + (size_t)qi * 768;
    float qh[2][6];
    #pragma unroll
    for (int h = 0; h < 2; h++)
        #pragma unroll
        for (int s = 0; s < 3; s++) {
            f16x2 v = *(const f16x2*)(qkrow + h * 384 + s * 128 + c2);
            qh[h][s * 2] = (float)v[0];
            qh[h][s * 2 + 1] = (float)v[1];
        }

    // cb_h = q_in . wqbk_h + bqbk_h
    float cb0, cb1;
    {
        int c4 = lane * 4;
        f16x4 qv = *(const f16x4*)(q_in + (size_t)qi * 256 + c4);
        float4 w0 = *(const float4*)(wqbk + c4);
        float4 w1 = *(const float4*)(wqbk + 256 + c4);
        cb0 = (float)qv[0] * w0.x + (float)qv[1] * w0.y + (float)qv[2] * w0.z + (float)qv[3] * w0.w;
        cb1 = (float)qv[0] * w1.x + (float)qv[1] * w1.y + (float)qv[2] * w1.z + (float)qv[3] * w1.w;
        #pragma unroll
        for (int d = 1; d < 64; d <<= 1) {
            cb0 += __shfl_xor(cb0, d);
            cb1 += __shfl_xor(cb1, d);
        }
        cb0 += bqbk[0];
        cb1 += bqbk[1];
    }

    float ts = (float)edge_times[qi & (BB - 1)];
    float m0 = -3.0e38f, l0 = 0.f, m1 = -3.0e38f, l1 = 0.f;
    float wa0[6] = {0,0,0,0,0,0}, wa1[6] = {0,0,0,0,0,0};
    int anyv = 0;
    const float inv_sqrt = 0.08838834764831845f;

    int base = qi * KK;
    int nb_c = neighbors[base];
    int ei_c = nb_eidx[base];
    int et_c = nb_et[base];
    f16x2 fv = *(const f16x2*)(feat + (size_t)nb_c * 128 + c2);
    float2 ev = *(const float2*)(edge_feats + (size_t)ei_c * 128 + c2);

    for (int j = 0; j < KK; j++) {
        int nb_n = 0, ei_n = 0, et_n = 0;
        f16x2 fv_n = {0, 0};
        float2 ev_n = {0, 0};
        if (j + 1 < KK) {
            nb_n = neighbors[base + j + 1];
            ei_n = nb_eidx[base + j + 1];
            et_n = nb_et[base + j + 1];
            fv_n = *(const f16x2*)(feat + (size_t)nb_n * 128 + c2);
            ev_n = *(const float2*)(edge_feats + (size_t)ei_n * 128 + c2);
        }

        float dtf = ts - (float)et_c;
        anyv |= (nb_c != 0);
        float k[6];
        k[0] = (float)fv[0]; k[1] = (float)fv[1];
        k[2] = tenc(dtf, tw0, tb0); k[3] = tenc(dtf, tw1, tb1);
        k[4] = ev.x; k[5] = ev.y;

        float sp0 = 0.f, sp1 = 0.f;
        #pragma unroll
        for (int t = 0; t < 6; t++) {
            sp0 += qh[0][t] * k[t];
            sp1 += qh[1][t] * k[t];
        }
        #pragma unroll
        for (int d = 1; d < 64; d <<= 1) {
            sp0 += __shfl_xor(sp0, d);
            sp1 += __shfl_xor(sp1, d);
        }

        float s0 = (sp0 + cb0) * inv_sqrt;
        float s1 = (sp1 + cb1) * inv_sqrt;
        if (nb_c == 0) { s0 = -1e9f; s1 = -1e9f; }
        {
            float mn = fmaxf(m0, s0);
            float sc = __expf(m0 - mn);
            float p = __expf(s0 - mn);
            l0 = l0 * sc + p;
            #pragma unroll
            for (int t = 0; t < 6; t++) wa0[t] = wa0[t] * sc + p * k[t];
            m0 = mn;
        }
        {
            float mn = fmaxf(m1, s1);
            float sc = __expf(m1 - mn);
            float p = __expf(s1 - mn);
            l1 = l1 * sc + p;
            #pragma unroll
            for (int t = 0; t < 6; t++) wa1[t] = wa1[t] * sc + p * k[t];
            m1 = mn;
        }

        nb_c = nb_n; ei_c = ei_n; et_c = et_n;
        fv = fv_n; ev = ev_n;
    }

    float li0 = __builtin_amdgcn_rcpf(l0);
    float li1 = __builtin_amdgcn_rcpf(l1);
    _Float16* wp = qk_wsum + (size_t)qi * 768;
    #pragma unroll
    for (int s = 0; s < 3; s++) {
        f16x2 o0, o1;
        o0[0] = (_Float16)(wa0[s * 2] * li0);     o0[1] = (_Float16)(wa0[s * 2 + 1] * li0);
        o1[0] = (_Float16)(wa1[s * 2] * li1);     o1[1] = (_Float16)(wa1[s * 2 + 1] * li1);
        *(f16x2*)(wp + s * 128 + c2) = o0;
        *(f16x2*)(wp + 384 + s * 128 + c2) = o1;
    }
    if (lane == 0) allm[qi] = anyv ? 0 : 1;
}

extern "C" void kernel_launch(void* const* d_in, const int* in_sizes, int n_in,
                              void* d_out, int out_size, void* d_ws, size_t ws_size,
                              hipStream_t stream) {
    (void)in_sizes; (void)n_in; (void)out_size; (void)ws_size;
    const int* src_nodes  = (const int*)d_in[0];
    const int* dst_nodes  = (const int*)d_in[1];
    const int* neg_nodes  = (const int*)d_in[2];
    const int* edge_times = (const int*)d_in[3];
    const int* neighbors  = (const int*)d_in[4];
    const int* nb_eidx    = (const int*)d_in[5];
    const int* nb_et      = (const int*)d_in[6];
    const int* msg_src    = (const int*)d_in[7];
    const int* msg_dst    = (const int*)d_in[8];
    const int* msg_eidx   = (const int*)d_in[9];
    const int* msg_t      = (const int*)d_in[10];
    const int* last_update= (const int*)d_in[11];
    const float* node_feats = (const float*)d_in[12];
    const float* edge_feats = (const float*)d_in[13];
    const float* memory     = (const float*)d_in[14];
    const float* time_w = (const float*)d_in[15];
    const float* time_b = (const float*)d_in[16];
    const float* W1 = (const float*)d_in[17];
    const float* b1 = (const float*)d_in[18];
    const float* W2 = (const float*)d_in[19];
    const float* b2 = (const float*)d_in[20];
    const float* gWi = (const float*)d_in[21];
    const float* gWh = (const float*)d_in[22];
    const float* gbi = (const float*)d_in[23];
    const float* gbh = (const float*)d_in[24];
    const float* Wq = (const float*)d_in[25];
    const float* bq = (const float*)d_in[26];
    const float* Wk = (const float*)d_in[27];
    const float* bk = (const float*)d_in[28];
    const float* Wv = (const float*)d_in[29];
    const float* bv = (const float*)d_in[30];
    const float* Wo = (const float*)d_in[31];
    const float* bo = (const float*)d_in[32];
    const float* mW1 = (const float*)d_in[33];
    const float* mb1 = (const float*)d_in[34];
    const float* mW2 = (const float*)d_in[35];
    const float* mb2 = (const float*)d_in[36];
    float* out = (float*)d_out;

    char* w = (char*)d_ws;
    int* lastpos = (int*)w;
    int* inv  = lastpos + NN;
    int* comp = inv + NN;
    int* count = comp + NN;
    size_t off = ((size_t)(3 * NN + 1) * 4 + 255) & ~(size_t)255;
    _Float16* new_mem = (_Float16*)(w + off);         // MM*128 f16
    size_t foff = off + (size_t)MM * 128 * 2;
    _Float16* feat = (_Float16*)(w + foff);           // NN*128 f16
    size_t woff = foff + (size_t)NN * 128 * 2;

    _Float16* Hpool = (_Float16*)(w + woff);          // 327680 f16, fragment order
    _Float16* W1h  = Hpool;
    _Float16* W2h  = Hpool + 131072;
    _Float16* Wih  = Hpool + 163840;
    _Float16* Whh  = Hpool + 212992;
    _Float16* mW1h = Hpool + 262144;
    _Float16* mW2h = Hpool + 311296;
    _Float16* QKW  = Hpool + 327680;                  // 196608 f16
    _Float16* WoV  = QKW + 196608;                    // 196608 f16
    float* B2   = (float*)(WoV + 196608);             // 768
    float* wqbk = B2 + 768;                           // 512
    float* bqbk = wqbk + 512;                         // 2
    float* bo2  = bqbk + 2;                           // 256

    _Float16* qin   = (_Float16*)(bo2 + 256);         // Q3*256
    _Float16* qk_ws = qin + (size_t)Q3 * 256;         // Q3*768
    _Float16* acat  = qk_ws + (size_t)Q3 * 768;       // Q3*384
    _Float16* q_hm  = acat + (size_t)Q3 * 384;        // Q3*128
    int* allm       = (int*)(q_hm + (size_t)Q3 * 128);

    k_init<<<dim3((NN + 255) / 256), dim3(256), 0, stream>>>(lastpos, inv, count);
    k_scatter<<<dim3((MM + 255) / 256), dim3(256), 0, stream>>>(msg_src, lastpos);
    k_compact<<<dim3((NN + 255) / 256), dim3(256), 0, stream>>>(lastpos, inv, comp, count);
    k_cvtw<<<dim3(160), dim3(256), 0, stream>>>(W1, W2, gWi, gWh, mW1, mW2, Hpool);
    k_fold<<<dim3(1026), dim3(256), 0, stream>>>(Wq, bq, Wk, bk, Wv, bv, Wo, bo,
                                                 QKW, WoV, B2, wqbk, bqbk, bo2);
    k_stage1<<<dim3((MM + 63) / 64), dim3(512), 0, stream>>>(
        comp, count, lastpos, msg_dst, msg_eidx, msg_t, last_update,
        memory, edge_feats, time_w, time_b,
        W1h, b1, W2h, b2, Wih, Whh, gbi, gbh, new_mem);
    k_feat<<<dim3(NN * 16 / 256), dim3(256), 0, stream>>>(
        inv, new_mem, memory, node_feats, feat);

    k2a<<<dim3(Q3 / 32), dim3(256), 0, stream>>>(
        src_nodes, dst_nodes, neg_nodes, feat, time_b, qin, acat);
    // qk = q_in @ QKW_h + B2_h   (folded Wq,Wk) -> qk_ws
    k_gemm<256, 6, false><<<dim3(Q3 / 32, 2), dim3(256), 0, stream>>>(
        qin, 256, 0, QKW, 98304, B2, 384, qk_ws, 768, 384, nullptr, nullptr);
    k2d<<<dim3(Q3 / 4), dim3(256), 0, stream>>>(
        neighbors, nb_eidx, nb_et, edge_times, feat, edge_feats,
        time_w, time_b, wqbk, bqbk, qin, qk_ws, allm);
    // attn_out = wsum @ WoV + bo2 (folded Wv,Wo), masked rows -> 0, into acat cols 0-255
    k_gemm<768, 4, false><<<dim3(Q3 / 32, 1), dim3(256), 0, stream>>>(
        qk_ws, 768, 0, WoV, 0, bo2, 0, acat, 384, 0, nullptr, allm);
    // merge layer
    k_gemm<384, 2, true><<<dim3(Q3 / 32, 1), dim3(256), 0, stream>>>(
        acat, 384, 0, mW1h, 0, mb1, 0, q_hm, 128, 0, nullptr, nullptr);
    k_gemm<128, 2, false><<<dim3(Q3 / 32, 1), dim3(256), 0, stream>>>(
        q_hm, 128, 0, mW2h, 0, mb2, 0, nullptr, 128, 0, out, nullptr);
}

// Round 8
// 382.809 us; speedup vs baseline: 1.0317x; 1.0317x over previous
//
#include <hip/hip_runtime.h>
#include <math.h>

#define NN 200000
#define EEDGE 500000
#define BB 4096
#define KK 20
#define MM 100000
#define Q3 (3*BB)

typedef _Float16 __attribute__((ext_vector_type(8))) f16x8;
typedef _Float16 __attribute__((ext_vector_type(4))) f16x4;
typedef float __attribute__((ext_vector_type(4))) f32x4;

#define MFMA16(a,b,c) __builtin_amdgcn_mfma_f32_16x16x32_f16(a,b,c,0,0,0)

// cos(a) for |a| up to ~1e7: f64 range-reduction to revolutions + v_cos_f32.
__device__ __forceinline__ float fast_cos(float a) {
    double ad = (double)a * 0.15915494309189535;   // 1/(2*pi)
    double fr = ad - floor(ad);                    // [0,1) revolutions
    return __builtin_amdgcn_cosf((float)fr);       // cos(2*pi*x)
}

// time encoding matching numpy's f32 arg rounding — NO fma contraction.
__device__ __forceinline__ float tenc(float dt, float w, float b) {
    float p = __fmul_rn(dt, w);
    float a = __fadd_rn(p, b);
    return fast_cos(a);
}

__device__ __forceinline__ float fsigm(float x) {
    return __builtin_amdgcn_rcpf(1.f + __expf(-x));
}
__device__ __forceinline__ float ftanh(float x) {
    return 1.f - 2.f * __builtin_amdgcn_rcpf(1.f + __expf(2.f * x));
}

__device__ __forceinline__ f32x4 z4() {
    f32x4 v; v[0] = 0.f; v[1] = 0.f; v[2] = 0.f; v[3] = 0.f; return v;
}

__global__ void k_init(int* lastpos, int* inv, int* count) {
    int i = blockIdx.x * 256 + threadIdx.x;
    if (i < NN) { lastpos[i] = -1; inv[i] = -1; }
    if (i == 0) *count = 0;
}

__global__ void k_scatter(const int* __restrict__ msg_src, int* __restrict__ lastpos) {
    int i = blockIdx.x * 256 + threadIdx.x;
    if (i < MM) atomicMax(&lastpos[msg_src[i]], i);
}

__global__ void k_compact(const int* __restrict__ lastpos, int* __restrict__ inv,
                          int* __restrict__ comp, int* __restrict__ count) {
    int n = blockIdx.x * 256 + threadIdx.x;
    if (n < NN && lastpos[n] >= 0) {
        int j = atomicAdd(count, 1);
        comp[j] = n;
        inv[n] = j;
    }
}

// f32 -> f16 weight conversion into MFMA FRAGMENT ORDER (stage1 + merge mats):
// elem offset = matbase + ((cgrp*KS + ks)*64 + lane)*8 + e
__global__ void k_cvtw(const float* __restrict__ W1, const float* __restrict__ W2,
                       const float* __restrict__ Wi, const float* __restrict__ Wh,
                       const float* __restrict__ mW1, const float* __restrict__ mW2,
                       _Float16* __restrict__ dst) {
    int f = blockIdx.x * 256 + threadIdx.x;   // fragment id, 40960 total
    if (f >= 40960) return;
    const float* src; int dstoff, K, lf;
    if      (f < 16384) { src = W1;  dstoff = 0;      K = 512; lf = f; }
    else if (f < 20480) { src = W2;  dstoff = 131072; K = 256; lf = f - 16384; }
    else if (f < 26624) { src = Wi;  dstoff = 163840; K = 128; lf = f - 20480; }
    else if (f < 32768) { src = Wh;  dstoff = 212992; K = 128; lf = f - 26624; }
    else if (f < 38912) { src = mW1; dstoff = 262144; K = 384; lf = f - 32768; }
    else                { src = mW2; dstoff = 311296; K = 128; lf = f - 38912; }
    int KS = K >> 5;
    int cgrp = lf / (KS * 64);
    int rem  = lf - cgrp * (KS * 64);
    int ks = rem >> 6, lane = rem & 63;
    int kg = lane >> 4, arow = lane & 15;
    int col = cgrp * 16 + arow;
    int k0 = ks * 32 + kg * 8;
    const float* p = src + (size_t)col * K + k0;
    float4 a = *(const float4*)p;
    float4 b = *(const float4*)(p + 4);
    f16x8 h;
    h[0] = (_Float16)a.x; h[1] = (_Float16)a.y; h[2] = (_Float16)a.z; h[3] = (_Float16)a.w;
    h[4] = (_Float16)b.x; h[5] = (_Float16)b.y; h[6] = (_Float16)b.z; h[7] = (_Float16)b.w;
    *(f16x8*)(dst + dstoff + (size_t)lf * 8) = h;
}

// k_fold (tiled): folded attention matrices, LDS-staged shared operand.
// blocks [0..47]: QKW (h = b/24, 16 j-cols each); [48..63]: WoV (16 o each);
// [64..65]: wqbk per head.
__global__ __launch_bounds__(256)
void k_fold(const float* __restrict__ Wq, const float* __restrict__ bq,
            const float* __restrict__ Wk, const float* __restrict__ bk,
            const float* __restrict__ Wv, const float* __restrict__ bv,
            const float* __restrict__ Wo, const float* __restrict__ bo,
            _Float16* __restrict__ QKW, _Float16* __restrict__ WoV,
            float* __restrict__ B2, float* __restrict__ wqbk,
            float* __restrict__ bqbk, float* __restrict__ bo2)
{
    int b = blockIdx.x, t = threadIdx.x;
    if (b < 48) {
        int h = b / 24, j0 = (b % 24) * 16;
        __shared__ float wk[128][17];
        #pragma unroll
        for (int it = 0; it < 8; it++) {
            int gi = t + it * 256;
            int d = gi >> 4, jj = gi & 15;
            wk[d][jj] = Wk[(size_t)(h * 128 + d) * 384 + j0 + jj];
        }
        __syncthreads();
        float acc[16];
        #pragma unroll
        for (int jj = 0; jj < 16; jj++) acc[jj] = 0.f;
        for (int d = 0; d < 128; d++) {
            float wq = Wq[(size_t)(h * 128 + d) * 256 + t];
            #pragma unroll
            for (int jj = 0; jj < 16; jj++) acc[jj] += wq * wk[d][jj];
        }
        int ks = t >> 5, kg = (t >> 3) & 3, e = t & 7;
        #pragma unroll
        for (int jj = 0; jj < 16; jj++) {
            int j = j0 + jj;
            int cgrp = j >> 4, arow = j & 15;
            int lane = kg * 16 + arow;
            QKW[(size_t)h * 98304 + (((size_t)cgrp * 8 + ks) * 64 + lane) * 8 + e] = (_Float16)acc[jj];
        }
        if (t < 16) {
            float a2 = 0.f;
            for (int d = 0; d < 128; d++) a2 += bq[h * 128 + d] * wk[d][t];
            B2[h * 384 + j0 + t] = a2;
        }
    } else if (b < 64) {
        int o0 = (b - 48) * 16;
        __shared__ float wo[16][257];
        #pragma unroll
        for (int it = 0; it < 16; it++) {
            int gi = t + it * 256;
            int oo = gi >> 8, k = gi & 255;
            wo[oo][k] = Wo[(size_t)(o0 + oo) * 256 + k];
        }
        __syncthreads();
        #pragma unroll
        for (int it = 0; it < 3; it++) {
            int hj = t + it * 256;
            int h = hj / 384, j = hj % 384;
            float acc[16];
            #pragma unroll
            for (int oo = 0; oo < 16; oo++) acc[oo] = 0.f;
            for (int d = 0; d < 128; d++) {
                float wv = Wv[(size_t)(h * 128 + d) * 384 + j];
                #pragma unroll
                for (int oo = 0; oo < 16; oo++) acc[oo] += wo[oo][h * 128 + d] * wv;
            }
            int ks = hj >> 5, kg = (hj >> 3) & 3, e = hj & 7;
            #pragma unroll
            for (int oo = 0; oo < 16; oo++) {
                int o = o0 + oo;
                int cgrp = o >> 4, arow = o & 15;
                int lane = kg * 16 + arow;
                WoV[(((size_t)cgrp * 24 + ks) * 64 + lane) * 8 + e] = (_Float16)acc[oo];
            }
        }
        if (t < 16) {
            float a2 = bo[o0 + t];
            for (int k = 0; k < 256; k++) a2 += wo[t][k] * bv[k];
            bo2[o0 + t] = a2;
        }
    } else {
        int h = b - 64;
        float acc = 0.f;
        for (int d = 0; d < 128; d++)
            acc += Wq[(size_t)(h * 128 + d) * 256 + t] * bk[h * 128 + d];
        wqbk[h * 256 + t] = acc;
        if (t == 0) {
            float a2 = 0.f;
            for (int d = 0; d < 128; d++) a2 += bq[h * 128 + d] * bk[h * 128 + d];
            bqbk[h] = a2;
        }
    }
}

// ---------------- Stage 1: 64 rows/block, 512 threads / 8 waves (R6-exact) ----------------
__device__ __forceinline__ int SWA(int r, int byteofs) {
    return r * 1024 + (byteofs ^ ((r & 7) << 4));
}

__device__ __forceinline__ f16x8 ldw4(const _Float16* W, int cg, int ks, int lane) {
    return *(const f16x8*)(W + (((size_t)cg * 4 + ks) * 64 + lane) * 8);
}

__global__ __launch_bounds__(512, 4)
void k_stage1(const int* __restrict__ comp, const int* __restrict__ count,
              const int* __restrict__ lastpos,
              const int* __restrict__ msg_dst, const int* __restrict__ msg_eidx,
              const int* __restrict__ msg_t, const int* __restrict__ last_update,
              const float* __restrict__ memory, const float* __restrict__ edge_feats,
              const float* __restrict__ time_w, const float* __restrict__ time_b,
              const _Float16* __restrict__ W1h, const float* __restrict__ b1,
              const _Float16* __restrict__ W2h, const float* __restrict__ b2,
              const _Float16* __restrict__ Wih, const _Float16* __restrict__ Whh,
              const float* __restrict__ bi, const float* __restrict__ bh,
              _Float16* __restrict__ new_mem)
{
    __shared__ char rawb[64 * 1024];
    __shared__ int sn[64], sd[64], se[64];
    __shared__ float sdt[64];

    int cnt = *count;
    int r0 = blockIdx.x * 64;
    if (r0 >= cnt) return;
    int tid = threadIdx.x;

    if (tid < 64) {
        int rr = r0 + tid;
        int j = (rr < cnt) ? rr : r0;
        int n = comp[j];
        int idx = lastpos[n];
        sn[tid] = n;
        sd[tid] = msg_dst[idx];
        se[tid] = msg_eidx[idx];
        sdt[tid] = (float)(msg_t[idx] - last_update[n]);
    }
    __syncthreads();

    #pragma unroll
    for (int it = 0; it < 6; it++) {
        int gi = tid + it * 512;
        int r = gi / 48, g = gi - r * 48;
        const float* src;
        if (g < 16)      src = memory + (size_t)sn[r] * 128 + g * 8;
        else if (g < 32) src = memory + (size_t)sd[r] * 128 + (g - 16) * 8;
        else             src = edge_feats + (size_t)se[r] * 128 + (g - 32) * 8;
        float4 a = *(const float4*)src;
        float4 b = *(const float4*)(src + 4);
        f16x8 h;
        h[0] = (_Float16)a.x; h[1] = (_Float16)a.y; h[2] = (_Float16)a.z; h[3] = (_Float16)a.w;
        h[4] = (_Float16)b.x; h[5] = (_Float16)b.y; h[6] = (_Float16)b.z; h[7] = (_Float16)b.w;
        *(f16x8*)(rawb + SWA(r, g * 16)) = h;
    }
    #pragma unroll
    for (int it = 0; it < 2; it++) {
        int gi = tid + it * 512;
        int r = gi >> 4, g = gi & 15;
        int c = g * 8;
        float dt = sdt[r];
        float4 w0 = *(const float4*)(time_w + c);
        float4 w1 = *(const float4*)(time_w + c + 4);
        float4 t0 = *(const float4*)(time_b + c);
        float4 t1 = *(const float4*)(time_b + c + 4);
        f16x8 h;
        h[0] = (_Float16)tenc(dt, w0.x, t0.x); h[1] = (_Float16)tenc(dt, w0.y, t0.y);
        h[2] = (_Float16)tenc(dt, w0.z, t0.z); h[3] = (_Float16)tenc(dt, w0.w, t0.w);
        h[4] = (_Float16)tenc(dt, w1.x, t1.x); h[5] = (_Float16)tenc(dt, w1.y, t1.y);
        h[6] = (_Float16)tenc(dt, w1.z, t1.z); h[7] = (_Float16)tenc(dt, w1.w, t1.w);
        *(f16x8*)(rawb + SWA(r, (48 + g) * 16)) = h;
    }
    __syncthreads();

    int wv = tid >> 6, lane = tid & 63;
    int arow = lane & 15, kg = lane >> 4;

    f32x4 acc1[2][4];
    #pragma unroll
    for (int c = 0; c < 2; c++)
        #pragma unroll
        for (int rt = 0; rt < 4; rt++) acc1[c][rt] = z4();
    for (int ks = 0; ks < 16; ks++) {
        f16x8 a[4];
        #pragma unroll
        for (int rt = 0; rt < 4; rt++)
            a[rt] = *(const f16x8*)(rawb + SWA(rt * 16 + arow, ks * 64 + kg * 16));
        #pragma unroll
        for (int c = 0; c < 2; c++) {
            f16x8 b = *(const f16x8*)(W1h + (((size_t)(wv * 2 + c) * 16 + ks) * 64 + lane) * 8);
            #pragma unroll
            for (int rt = 0; rt < 4; rt++)
                acc1[c][rt] = MFMA16(a[rt], b, acc1[c][rt]);
        }
    }
    __syncthreads();

    #pragma unroll
    for (int c = 0; c < 2; c++) {
        int col = (wv * 2 + c) * 16 + arow;
        float bb = b1[col];
        #pragma unroll
        for (int rt = 0; rt < 4; rt++)
            #pragma unroll
            for (int rg = 0; rg < 4; rg++) {
                int row = rt * 16 + kg * 4 + rg;
                float v = fmaxf(acc1[c][rt][rg] + bb, 0.f);
                *(_Float16*)(rawb + SWA(row, 384 + col * 2)) = (_Float16)v;
            }
    }
    __syncthreads();

    f32x4 acc2[4];
    #pragma unroll
    for (int rt = 0; rt < 4; rt++) acc2[rt] = z4();
    for (int ks = 0; ks < 8; ks++) {
        f16x8 b = *(const f16x8*)(W2h + (((size_t)wv * 8 + ks) * 64 + lane) * 8);
        #pragma unroll
        for (int rt = 0; rt < 4; rt++) {
            f16x8 a = *(const f16x8*)(rawb + SWA(rt * 16 + arow, 384 + ks * 64 + kg * 16));
            acc2[rt] = MFMA16(a, b, acc2[rt]);
        }
    }
    __syncthreads();

    {
        int col = wv * 16 + arow;
        float bb = b2[col];
        #pragma unroll
        for (int rt = 0; rt < 4; rt++)
            #pragma unroll
            for (int rg = 0; rg < 4; rg++) {
                int row = rt * 16 + kg * 4 + rg;
                *(_Float16*)(rawb + SWA(row, 384 + col * 2)) =
                    (_Float16)(acc2[rt][rg] + bb);
            }
    }
    __syncthreads();

    f32x4 aR[4], aZ[4], aNi[4], aNh[4];
    #pragma unroll
    for (int rt = 0; rt < 4; rt++) { aR[rt] = z4(); aZ[rt] = z4(); aNi[rt] = z4(); aNh[rt] = z4(); }
    for (int ks = 0; ks < 4; ks++) {
        f16x8 bi_ = ldw4(Wih, wv, ks, lane);
        f16x8 bh_ = ldw4(Whh, wv, ks, lane);
        #pragma unroll
        for (int rt = 0; rt < 4; rt++) {
            f16x8 m = *(const f16x8*)(rawb + SWA(rt * 16 + arow, 384 + ks * 64 + kg * 16));
            f16x8 hh = *(const f16x8*)(rawb + SWA(rt * 16 + arow, ks * 64 + kg * 16));
            aR[rt] = MFMA16(m, bi_, aR[rt]);
            aR[rt] = MFMA16(hh, bh_, aR[rt]);
        }
    }
    for (int ks = 0; ks < 4; ks++) {
        f16x8 bi_ = ldw4(Wih, 8 + wv, ks, lane);
        f16x8 bh_ = ldw4(Whh, 8 + wv, ks, lane);
        #pragma unroll
        for (int rt = 0; rt < 4; rt++) {
            f16x8 m = *(const f16x8*)(rawb + SWA(rt * 16 + arow, 384 + ks * 64 + kg * 16));
            f16x8 hh = *(const f16x8*)(rawb + SWA(rt * 16 + arow, ks * 64 + kg * 16));
            aZ[rt] = MFMA16(m, bi_, aZ[rt]);
            aZ[rt] = MFMA16(hh, bh_, aZ[rt]);
        }
    }
    for (int ks = 0; ks < 4; ks++) {
        f16x8 bi_ = ldw4(Wih, 16 + wv, ks, lane);
        f16x8 bh_ = ldw4(Whh, 16 + wv, ks, lane);
        #pragma unroll
        for (int rt = 0; rt < 4; rt++) {
            f16x8 m = *(const f16x8*)(rawb + SWA(rt * 16 + arow, 384 + ks * 64 + kg * 16));
            f16x8 hh = *(const f16x8*)(rawb + SWA(rt * 16 + arow, ks * 64 + kg * 16));
            aNi[rt] = MFMA16(m, bi_, aNi[rt]);
            aNh[rt] = MFMA16(hh, bh_, aNh[rt]);
        }
    }

    {
        int col = wv * 16 + arow;
        float bir = bi[col],        bhr = bh[col];
        float biz = bi[128 + col],  bhz = bh[128 + col];
        float bin_ = bi[256 + col], bhn_ = bh[256 + col];
        #pragma unroll
        for (int rt = 0; rt < 4; rt++)
            #pragma unroll
            for (int rg = 0; rg < 4; rg++) {
                int row = rt * 16 + kg * 4 + rg;
                int rr = r0 + row;
                if (rr < cnt) {
                    float r_ = fsigm(aR[rt][rg] + bir + bhr);
                    float zg = fsigm(aZ[rt][rg] + biz + bhz);
                    float ng = ftanh(aNi[rt][rg] + bin_ + r_ * (aNh[rt][rg] + bhn_));
                    float om = (float)*(const _Float16*)(rawb + SWA(row, col * 2));
                    new_mem[(size_t)rr * 128 + col] = (_Float16)((1.f - zg) * ng + zg * om);
                }
            }
    }
}

// k_feat: feat[n] = (updated ? new_mem[inv[n]] : memory[n]) + node_feats[n], f16
__global__ __launch_bounds__(256)
void k_feat(const int* __restrict__ inv, const _Float16* __restrict__ new_mem,
            const float* __restrict__ memory, const float* __restrict__ node_feats,
            _Float16* __restrict__ feat)
{
    int idx = blockIdx.x * 256 + threadIdx.x;
    if (idx >= NN * 16) return;
    int n = idx >> 4, g = idx & 15;
    int c = g * 8;
    int iv = inv[n];
    float4 n0 = *(const float4*)(node_feats + (size_t)n * 128 + c);
    float4 n1 = *(const float4*)(node_feats + (size_t)n * 128 + c + 4);
    f16x8 o;
    if (iv >= 0) {
        f16x8 mv = *(const f16x8*)(new_mem + (size_t)iv * 128 + c);
        o[0] = (_Float16)((float)mv[0] + n0.x); o[1] = (_Float16)((float)mv[1] + n0.y);
        o[2] = (_Float16)((float)mv[2] + n0.z); o[3] = (_Float16)((float)mv[3] + n0.w);
        o[4] = (_Float16)((float)mv[4] + n1.x); o[5] = (_Float16)((float)mv[5] + n1.y);
        o[6] = (_Float16)((float)mv[6] + n1.z); o[7] = (_Float16)((float)mv[7] + n1.w);
    } else {
        float4 m0 = *(const float4*)(memory + (size_t)n * 128 + c);
        float4 m1 = *(const float4*)(memory + (size_t)n * 128 + c + 4);
        o[0] = (_Float16)(m0.x + n0.x); o[1] = (_Float16)(m0.y + n0.y);
        o[2] = (_Float16)(m0.z + n0.z); o[3] = (_Float16)(m0.w + n0.w);
        o[4] = (_Float16)(m1.x + n1.x); o[5] = (_Float16)(m1.y + n1.y);
        o[6] = (_Float16)(m1.z + n1.z); o[7] = (_Float16)(m1.w + n1.w);
    }
    *(f16x8*)(feat + (size_t)n * 128 + c) = o;
}

// ---------------- Stage 2 ----------------
__global__ void k2a(const int* __restrict__ src_nodes, const int* __restrict__ dst_nodes,
                    const int* __restrict__ neg_nodes, const _Float16* __restrict__ feat,
                    const float* __restrict__ time_b,
                    _Float16* __restrict__ q_in, _Float16* __restrict__ sfeat)
{
    __shared__ int snode[32];
    int tid = threadIdx.x;
    int r0 = blockIdx.x * 32;
    if (tid < 32) {
        int q = r0 + tid;
        snode[tid] = (q < BB) ? src_nodes[q] : (q < 2 * BB) ? dst_nodes[q - BB] : neg_nodes[q - 2 * BB];
    }
    __syncthreads();
    #pragma unroll
    for (int it = 0; it < 4; it++) {
        int gi = tid + it * 256;
        int r = gi >> 5, ch = gi & 31;
        int c = ch * 4;
        int node = snode[r];
        f16x4 sf = *(const f16x4*)(feat + (size_t)node * 128 + c);
        size_t q = (size_t)(r0 + r);
        *(f16x4*)(q_in + q * 256 + c) = sf;
        *(f16x4*)(sfeat + q * 128 + c) = sf;
        float4 tb = *(const float4*)(time_b + c);
        f16x4 te;
        te[0] = (_Float16)fast_cos(tb.x); te[1] = (_Float16)fast_cos(tb.y);
        te[2] = (_Float16)fast_cos(tb.z); te[3] = (_Float16)fast_cos(tb.w);
        *(f16x4*)(q_in + q * 256 + 128 + c) = te;
    }
}

// generic 32-row-tile MFMA GEMM, fragment-ordered B (used for qk fold GEMM).
template<int KD, int NFRAG, bool RELU>
__global__ __launch_bounds__(256, 4)
void k_gemm(const _Float16* __restrict__ A, int lda, int a_ys,
            const _Float16* __restrict__ B, int b_ys,
            const float* __restrict__ bias, int bias_ys,
            _Float16* __restrict__ C, int ldc, int c_ys,
            float* __restrict__ C32,
            const int* __restrict__ rowmask)
{
    constexpr int ROWB = KD * 2;
    __shared__ char As[32 * ROWB];
    int tid = threadIdx.x;
    int r0 = blockIdx.x * 32;
    int aoff = blockIdx.y * a_ys;
    const _Float16* Bp = B + (size_t)blockIdx.y * b_ys;
    int coff = blockIdx.y * c_ys;

    #pragma unroll
    for (int t = 0; t < (32 * KD / 8) / 256; t++) {
        int gi = tid + t * 256;
        int r = gi / (KD / 8), g = gi % (KD / 8);
        f16x8 v = *(const f16x8*)(A + (size_t)(r0 + r) * lda + aoff + g * 8);
        *(f16x8*)(&As[r * ROWB + ((g * 16) ^ ((r & 7) << 4))]) = v;
    }
    __syncthreads();

    int wv = tid >> 6, lane = tid & 63;
    int arow = lane & 15, kg = lane >> 4;
    f32x4 acc[NFRAG][2];
    #pragma unroll
    for (int c = 0; c < NFRAG; c++) { acc[c][0] = z4(); acc[c][1] = z4(); }

    #pragma unroll
    for (int ks = 0; ks < KD / 32; ks++) {
        f16x8 a0 = *(const f16x8*)(&As[arow * ROWB + ((ks * 64 + kg * 16) ^ ((arow & 7) << 4))]);
        f16x8 a1 = *(const f16x8*)(&As[(16 + arow) * ROWB + ((ks * 64 + kg * 16) ^ ((arow & 7) << 4))]);
        #pragma unroll
        for (int c = 0; c < NFRAG; c++) {
            f16x8 b = *(const f16x8*)(Bp +
                (((size_t)(wv * NFRAG + c) * (KD / 32) + ks) * 64 + lane) * 8);
            acc[c][0] = MFMA16(a0, b, acc[c][0]);
            acc[c][1] = MFMA16(a1, b, acc[c][1]);
        }
    }

    #pragma unroll
    for (int c = 0; c < NFRAG; c++) {
        int cg = (wv * NFRAG + c) * 16 + arow;
        float bb = bias ? bias[blockIdx.y * bias_ys + cg] : 0.f;
        #pragma unroll
        for (int rt = 0; rt < 2; rt++)
            #pragma unroll
            for (int rg = 0; rg < 4; rg++) {
                int grow = r0 + rt * 16 + kg * 4 + rg;
                float v = acc[c][rt][rg] + bb;
                if (RELU) v = fmaxf(v, 0.f);
                if (rowmask && rowmask[grow]) v = 0.f;
                if (C)   C[(size_t)grow * ldc + coff + cg] = (_Float16)v;
                if (C32) C32[(size_t)grow * ldc + coff + cg] = v;
            }
    }
}

// k2d: attention core (R6-proven half-wave structure; cb from folded wqbk).
__global__ __launch_bounds__(256)
void k2d(const int* __restrict__ neighbors, const int* __restrict__ nb_eidx,
         const int* __restrict__ nb_et, const int* __restrict__ edge_times,
         const _Float16* __restrict__ feat, const float* __restrict__ edge_feats,
         const float* __restrict__ time_w, const float* __restrict__ time_b,
         const float* __restrict__ wqbk, const float* __restrict__ bqbk,
         const _Float16* __restrict__ q_in, _Float16* __restrict__ qk_wsum,
         int* __restrict__ allm)
{
    int tid = threadIdx.x;
    int qi = blockIdx.x * 4 + (tid >> 6);
    int lane = tid & 63;
    int h = lane >> 5, l32 = lane & 31;
    int c0 = l32 * 4;

    float4 tw = *(const float4*)(time_w + c0);
    float4 tb = *(const float4*)(time_b + c0);

    const _Float16* qkp = qk_wsum + (size_t)qi * 768 + h * 384;
    f16x4 t0 = *(const f16x4*)(qkp + c0);
    f16x4 t1 = *(const f16x4*)(qkp + 128 + c0);
    f16x4 t2 = *(const f16x4*)(qkp + 256 + c0);
    float qk0[4], qk1[4], qk2[4];
    #pragma unroll
    for (int t = 0; t < 4; t++) { qk0[t] = (float)t0[t]; qk1[t] = (float)t1[t]; qk2[t] = (float)t2[t]; }

    // cb_h = q_in . wqbk_h + bqbk_h  (8 elems per half-wave lane)
    float cb;
    {
        int c8 = l32 * 8;
        f16x8 qv = *(const f16x8*)(q_in + (size_t)qi * 256 + c8);
        float4 wa = *(const float4*)(wqbk + h * 256 + c8);
        float4 wb = *(const float4*)(wqbk + h * 256 + c8 + 4);
        cb = (float)qv[0] * wa.x + (float)qv[1] * wa.y + (float)qv[2] * wa.z + (float)qv[3] * wa.w
           + (float)qv[4] * wb.x + (float)qv[5] * wb.y + (float)qv[6] * wb.z + (float)qv[7] * wb.w;
        cb += __shfl_xor(cb, 1, 32);
        cb += __shfl_xor(cb, 2, 32);
        cb += __shfl_xor(cb, 4, 32);
        cb += __shfl_xor(cb, 8, 32);
        cb += __shfl_xor(cb, 16, 32);
        cb += bqbk[h];
    }

    float ts = (float)edge_times[qi & (BB - 1)];
    float m_run = -3.0e38f, l_run = 0.f;
    float w0[4] = {0,0,0,0}, w1[4] = {0,0,0,0}, w2[4] = {0,0,0,0};
    int anyv = 0;
    const float inv_sqrt = 0.08838834764831845f;

    int base = qi * KK;
    int nb_c = neighbors[base];
    int ei_c = nb_eidx[base];
    int et_c = nb_et[base];
    f16x4 fv = *(const f16x4*)(feat + (size_t)nb_c * 128 + c0);
    float4 ef = *(const float4*)(edge_feats + (size_t)ei_c * 128 + c0);

    for (int j = 0; j < KK; j++) {
        int nb_n = 0, ei_n = 0, et_n = 0;
        f16x4 fv_n = {0, 0, 0, 0};
        float4 ef_n = {0, 0, 0, 0};
        if (j + 1 < KK) {
            nb_n = neighbors[base + j + 1];
            ei_n = nb_eidx[base + j + 1];
            et_n = nb_et[base + j + 1];
            fv_n = *(const f16x4*)(feat + (size_t)nb_n * 128 + c0);
            ef_n = *(const float4*)(edge_feats + (size_t)ei_n * 128 + c0);
        }

        float dtf = ts - (float)et_c;
        anyv |= (nb_c != 0);
        float k0[4] = { (float)fv[0], (float)fv[1], (float)fv[2], (float)fv[3] };
        float k1[4] = { tenc(dtf, tw.x, tb.x), tenc(dtf, tw.y, tb.y),
                        tenc(dtf, tw.z, tb.z), tenc(dtf, tw.w, tb.w) };
        float k2[4] = { ef.x, ef.y, ef.z, ef.w };

        float sp = 0.f;
        #pragma unroll
        for (int t = 0; t < 4; t++)
            sp += qk0[t] * k0[t] + qk1[t] * k1[t] + qk2[t] * k2[t];
        sp += __shfl_xor(sp, 1, 32);
        sp += __shfl_xor(sp, 2, 32);
        sp += __shfl_xor(sp, 4, 32);
        sp += __shfl_xor(sp, 8, 32);
        sp += __shfl_xor(sp, 16, 32);

        float s = (sp + cb) * inv_sqrt;
        if (nb_c == 0) s = -1e9f;
        float m_new = fmaxf(m_run, s);
        float sc = __expf(m_run - m_new);
        float p = __expf(s - m_new);
        l_run = l_run * sc + p;
        #pragma unroll
        for (int t = 0; t < 4; t++) {
            w0[t] = w0[t] * sc + p * k0[t];
            w1[t] = w1[t] * sc + p * k1[t];
            w2[t] = w2[t] * sc + p * k2[t];
        }
        m_run = m_new;

        nb_c = nb_n; ei_c = ei_n; et_c = et_n;
        fv = fv_n; ef = ef_n;
    }

    float linv = __builtin_amdgcn_rcpf(l_run);
    _Float16* wp = qk_wsum + (size_t)qi * 768 + h * 384;
    f16x4 o0, o1, o2;
    #pragma unroll
    for (int t = 0; t < 4; t++) {
        o0[t] = (_Float16)(w0[t] * linv);
        o1[t] = (_Float16)(w1[t] * linv);
        o2[t] = (_Float16)(w2[t] * linv);
    }
    *(f16x4*)(wp + c0) = o0;
    *(f16x4*)(wp + 128 + c0) = o1;
    *(f16x4*)(wp + 256 + c0) = o2;
    if (lane == 0) allm[qi] = anyv ? 0 : 1;
}

// k2t: fused tail. attn = wsum@WoV + bo2 (masked) -> hm = relu([attn|sfeat]@mW1+mb1)
// -> out = hm@mW2 + mb2. One LDS round-trip, no HBM intermediates.
__global__ __launch_bounds__(256, 3)
void k2t(const _Float16* __restrict__ wsum, const _Float16* __restrict__ sfeat,
         const _Float16* __restrict__ WoV, const float* __restrict__ bo2,
         const _Float16* __restrict__ mW1h, const float* __restrict__ mb1,
         const _Float16* __restrict__ mW2h, const float* __restrict__ mb2,
         const int* __restrict__ allm, float* __restrict__ out)
{
    __shared__ char lds[48 * 1024];
    int tid = threadIdx.x;
    int r0 = blockIdx.x * 32;

    // stage wsum tile [32][768] f16, swizzled rows of 1536B
    #pragma unroll
    for (int t = 0; t < 12; t++) {
        int gi = tid + t * 256;
        int r = gi / 96, g = gi - r * 96;
        f16x8 v = *(const f16x8*)(wsum + (size_t)(r0 + r) * 768 + g * 8);
        *(f16x8*)(&lds[r * 1536 + ((g * 16) ^ ((r & 7) << 4))]) = v;
    }
    __syncthreads();

    int wv = tid >> 6, lane = tid & 63;
    int arow = lane & 15, kg = lane >> 4;

    // attn GEMM: K=768 (KS=24), NFRAG=4
    f32x4 acc[4][2];
    #pragma unroll
    for (int c = 0; c < 4; c++) { acc[c][0] = z4(); acc[c][1] = z4(); }
    for (int ks = 0; ks < 24; ks++) {
        f16x8 a0 = *(const f16x8*)(&lds[arow * 1536 + ((ks * 64 + kg * 16) ^ ((arow & 7) << 4))]);
        f16x8 a1 = *(const f16x8*)(&lds[(16 + arow) * 1536 + ((ks * 64 + kg * 16) ^ ((arow & 7) << 4))]);
        #pragma unroll
        for (int c = 0; c < 4; c++) {
            f16x8 b = *(const f16x8*)(WoV + (((size_t)(wv * 4 + c) * 24 + ks) * 64 + lane) * 8);
            acc[c][0] = MFMA16(a0, b, acc[c][0]);
            acc[c][1] = MFMA16(a1, b, acc[c][1]);
        }
    }
    __syncthreads();   // all wsum reads done; reuse lds for [attn|sfeat] rows of 768B

    #pragma unroll
    for (int c = 0; c < 4; c++) {
        int col = (wv * 4 + c) * 16 + arow;
        float bb = bo2[col];
        #pragma unroll
        for (int rt = 0; rt < 2; rt++)
            #pragma unroll
            for (int rg = 0; rg < 4; rg++) {
                int row = rt * 16 + kg * 4 + rg;
                float v = allm[r0 + row] ? 0.f : (acc[c][rt][rg] + bb);
                *(_Float16*)(&lds[row * 768 + ((col * 2) ^ ((row & 7) << 4))]) = (_Float16)v;
            }
    }
    #pragma unroll
    for (int t = 0; t < 2; t++) {
        int gi = tid + t * 256;
        int r = gi >> 4, g = gi & 15;
        f16x8 v = *(const f16x8*)(sfeat + (size_t)(r0 + r) * 128 + g * 8);
        *(f16x8*)(&lds[r * 768 + ((512 + g * 16) ^ ((r & 7) << 4))]) = v;
    }
    __syncthreads();

    // merge GEMM1: K=384 (KS=12), NFRAG=2 -> relu -> hm into lds @24576 (rows of 256B)
    f32x4 acc2[2][2];
    #pragma unroll
    for (int c = 0; c < 2; c++) { acc2[c][0] = z4(); acc2[c][1] = z4(); }
    for (int ks = 0; ks < 12; ks++) {
        f16x8 a0 = *(const f16x8*)(&lds[arow * 768 + ((ks * 64 + kg * 16) ^ ((arow & 7) << 4))]);
        f16x8 a1 = *(const f16x8*)(&lds[(16 + arow) * 768 + ((ks * 64 + kg * 16) ^ ((arow & 7) << 4))]);
        #pragma unroll
        for (int c = 0; c < 2; c++) {
            f16x8 b = *(const f16x8*)(mW1h + (((size_t)(wv * 2 + c) * 12 + ks) * 64 + lane) * 8);
            acc2[c][0] = MFMA16(a0, b, acc2[c][0]);
            acc2[c][1] = MFMA16(a1, b, acc2[c][1]);
        }
    }
    #pragma unroll
    for (int c = 0; c < 2; c++) {
        int col = (wv * 2 + c) * 16 + arow;
        float bb = mb1[col];
        #pragma unroll
        for (int rt = 0; rt < 2; rt++)
            #pragma unroll
            for (int rg = 0; rg < 4; rg++) {
                int row = rt * 16 + kg * 4 + rg;
                float v = fmaxf(acc2[c][rt][rg] + bb, 0.f);
                *(_Float16*)(&lds[24576 + row * 256 + ((col * 2) ^ ((row & 7) << 4))]) = (_Float16)v;
            }
    }
    __syncthreads();

    // merge GEMM2: K=128 (KS=4), NFRAG=2 -> out (f32)
    f32x4 acc3[2][2];
    #pragma unroll
    for (int c = 0; c < 2; c++) { acc3[c][0] = z4(); acc3[c][1] = z4(); }
    for (int ks = 0; ks < 4; ks++) {
        f16x8 a0 = *(const f16x8*)(&lds[24576 + arow * 256 + ((ks * 64 + kg * 16) ^ ((arow & 7) << 4))]);
        f16x8 a1 = *(const f16x8*)(&lds[24576 + (16 + arow) * 256 + ((ks * 64 + kg * 16) ^ ((arow & 7) << 4))]);
        #pragma unroll
        for (int c = 0; c < 2; c++) {
            f16x8 b = *(const f16x8*)(mW2h + (((size_t)(wv * 2 + c) * 4 + ks) * 64 + lane) * 8);
            acc3[c][0] = MFMA16(a0, b, acc3[c][0]);
            acc3[c][1] = MFMA16(a1, b, acc3[c][1]);
        }
    }
    #pragma unroll
    for (int c = 0; c < 2; c++) {
        int col = (wv * 2 + c) * 16 + arow;
        float bb = mb2[col];
        #pragma unroll
        for (int rt = 0; rt < 2; rt++)
            #pragma unroll
            for (int rg = 0; rg < 4; rg++) {
                int row = rt * 16 + kg * 4 + rg;
                out[(size_t)(r0 + row) * 128 + col] = acc3[c][rt][rg] + bb;
            }
    }
}

extern "C" void kernel_launch(void* const* d_in, const int* in_sizes, int n_in,
                              void* d_out, int out_size, void* d_ws, size_t ws_size,
                              hipStream_t stream) {
    (void)in_sizes; (void)n_in; (void)out_size; (void)ws_size;
    const int* src_nodes  = (const int*)d_in[0];
    const int* dst_nodes  = (const int*)d_in[1];
    const int* neg_nodes  = (const int*)d_in[2];
    const int* edge_times = (const int*)d_in[3];
    const int* neighbors  = (const int*)d_in[4];
    const int* nb_eidx    = (const int*)d_in[5];
    const int* nb_et      = (const int*)d_in[6];
    const int* msg_src    = (const int*)d_in[7];
    const int* msg_dst    = (const int*)d_in[8];
    const int* msg_eidx   = (const int*)d_in[9];
    const int* msg_t      = (const int*)d_in[10];
    const int* last_update= (const int*)d_in[11];
    const float* node_feats = (const float*)d_in[12];
    const float* edge_feats = (const float*)d_in[13];
    const float* memory     = (const float*)d_in[14];
    const float* time_w = (const float*)d_in[15];
    const float* time_b = (const float*)d_in[16];
    const float* W1 = (const float*)d_in[17];
    const float* b1 = (const float*)d_in[18];
    const float* W2 = (const float*)d_in[19];
    const float* b2 = (const float*)d_in[20];
    const float* gWi = (const float*)d_in[21];
    const float* gWh = (const float*)d_in[22];
    const float* gbi = (const float*)d_in[23];
    const float* gbh = (const float*)d_in[24];
    const float* Wq = (const float*)d_in[25];
    const float* bq = (const float*)d_in[26];
    const float* Wk = (const float*)d_in[27];
    const float* bk = (const float*)d_in[28];
    const float* Wv = (const float*)d_in[29];
    const float* bv = (const float*)d_in[30];
    const float* Wo = (const float*)d_in[31];
    const float* bo = (const float*)d_in[32];
    const float* mW1 = (const float*)d_in[33];
    const float* mb1 = (const float*)d_in[34];
    const float* mW2 = (const float*)d_in[35];
    const float* mb2 = (const float*)d_in[36];
    float* out = (float*)d_out;

    char* w = (char*)d_ws;
    int* lastpos = (int*)w;
    int* inv  = lastpos + NN;
    int* comp = inv + NN;
    int* count = comp + NN;
    size_t off = ((size_t)(3 * NN + 1) * 4 + 255) & ~(size_t)255;
    _Float16* new_mem = (_Float16*)(w + off);         // MM*128 f16
    size_t foff = off + (size_t)MM * 128 * 2;
    _Float16* feat = (_Float16*)(w + foff);           // NN*128 f16
    size_t woff = foff + (size_t)NN * 128 * 2;

    _Float16* Hpool = (_Float16*)(w + woff);          // 327680 f16, fragment order
    _Float16* W1h  = Hpool;
    _Float16* W2h  = Hpool + 131072;
    _Float16* Wih  = Hpool + 163840;
    _Float16* Whh  = Hpool + 212992;
    _Float16* mW1h = Hpool + 262144;
    _Float16* mW2h = Hpool + 311296;
    _Float16* QKW  = Hpool + 327680;                  // 196608 f16
    _Float16* WoV  = QKW + 196608;                    // 196608 f16
    float* B2   = (float*)(WoV + 196608);             // 768
    float* wqbk = B2 + 768;                           // 512
    float* bqbk = wqbk + 512;                         // 2
    float* bo2  = bqbk + 2;                           // 256

    _Float16* qin   = (_Float16*)(bo2 + 256);         // Q3*256
    _Float16* qk_ws = qin + (size_t)Q3 * 256;         // Q3*768
    _Float16* sfeat = qk_ws + (size_t)Q3 * 768;       // Q3*128
    int* allm       = (int*)(sfeat + (size_t)Q3 * 128);

    k_init<<<dim3((NN + 255) / 256), dim3(256), 0, stream>>>(lastpos, inv, count);
    k_scatter<<<dim3((MM + 255) / 256), dim3(256), 0, stream>>>(msg_src, lastpos);
    k_compact<<<dim3((NN + 255) / 256), dim3(256), 0, stream>>>(lastpos, inv, comp, count);
    k_cvtw<<<dim3(160), dim3(256), 0, stream>>>(W1, W2, gWi, gWh, mW1, mW2, Hpool);
    k_fold<<<dim3(66), dim3(256), 0, stream>>>(Wq, bq, Wk, bk, Wv, bv, Wo, bo,
                                               QKW, WoV, B2, wqbk, bqbk, bo2);
    k_stage1<<<dim3((MM + 63) / 64), dim3(512), 0, stream>>>(
        comp, count, lastpos, msg_dst, msg_eidx, msg_t, last_update,
        memory, edge_feats, time_w, time_b,
        W1h, b1, W2h, b2, Wih, Whh, gbi, gbh, new_mem);
    k_feat<<<dim3(NN * 16 / 256), dim3(256), 0, stream>>>(
        inv, new_mem, memory, node_feats, feat);

    k2a<<<dim3(Q3 / 32), dim3(256), 0, stream>>>(
        src_nodes, dst_nodes, neg_nodes, feat, time_b, qin, sfeat);
    // qk = q_in @ QKW_h + B2_h   (folded Wq,Wk)
    k_gemm<256, 6, false><<<dim3(Q3 / 32, 2), dim3(256), 0, stream>>>(
        qin, 256, 0, QKW, 98304, B2, 384, qk_ws, 768, 384, nullptr, nullptr);
    k2d<<<dim3(Q3 / 4), dim3(256), 0, stream>>>(
        neighbors, nb_eidx, nb_et, edge_times, feat, edge_feats,
        time_w, time_b, wqbk, bqbk, qin, qk_ws, allm);
    // fused tail: attn(WoV) -> merge MLP -> out
    k2t<<<dim3(Q3 / 32), dim3(256), 0, stream>>>(
        qk_ws, sfeat, WoV, bo2, mW1h, mb1, mW2h, mb2, allm, out);
}

// Round 9
// 332.043 us; speedup vs baseline: 1.1894x; 1.1529x over previous
//
#include <hip/hip_runtime.h>
#include <math.h>

#define NN 200000
#define EEDGE 500000
#define BB 4096
#define KK 20
#define MM 100000
#define Q3 (3*BB)
#define NBLK ((NN + 255) / 256)

typedef _Float16 __attribute__((ext_vector_type(8))) f16x8;
typedef _Float16 __attribute__((ext_vector_type(4))) f16x4;
typedef float __attribute__((ext_vector_type(4))) f32x4;

#define MFMA16(a,b,c) __builtin_amdgcn_mfma_f32_16x16x32_f16(a,b,c,0,0,0)

// cos(a) for |a| up to ~1e7: f64 range-reduction to revolutions + v_cos_f32.
__device__ __forceinline__ float fast_cos(float a) {
    double ad = (double)a * 0.15915494309189535;   // 1/(2*pi)
    double fr = ad - floor(ad);                    // [0,1) revolutions
    return __builtin_amdgcn_cosf((float)fr);       // cos(2*pi*x)
}

// time encoding matching numpy's f32 arg rounding — NO fma contraction.
__device__ __forceinline__ float tenc(float dt, float w, float b) {
    float p = __fmul_rn(dt, w);
    float a = __fadd_rn(p, b);
    return fast_cos(a);
}

__device__ __forceinline__ float fsigm(float x) {
    return __builtin_amdgcn_rcpf(1.f + __expf(-x));
}
__device__ __forceinline__ float ftanh(float x) {
    return 1.f - 2.f * __builtin_amdgcn_rcpf(1.f + __expf(2.f * x));
}

__device__ __forceinline__ f32x4 z4() {
    f32x4 v; v[0] = 0.f; v[1] = 0.f; v[2] = 0.f; v[3] = 0.f; return v;
}

__global__ void k_init(int* lastpos, int* inv) {
    int i = blockIdx.x * 256 + threadIdx.x;
    if (i < NN) { lastpos[i] = -1; inv[i] = -1; }
}

__global__ void k_scatter(const int* __restrict__ msg_src, int* __restrict__ lastpos) {
    int i = blockIdx.x * 256 + threadIdx.x;
    if (i < MM) atomicMax(&lastpos[msg_src[i]], i);
}

// ordered (sorted-by-node) compaction: count -> scan -> fill. Deterministic;
// makes comp[] ascending so stage1's memory[sn] gather streams instead of
// random-walking (R5 PMC: stage1 was random-row-BW-bound at 1.2 TB/s).
__global__ void k_count(const int* __restrict__ lastpos, int* __restrict__ bcnt) {
    int n = blockIdx.x * 256 + threadIdx.x;
    int flag = (n < NN && lastpos[n] >= 0) ? 1 : 0;
    unsigned long long m = __ballot(flag != 0);
    __shared__ int wc[4];
    int wave = threadIdx.x >> 6, lane = threadIdx.x & 63;
    if (lane == 0) wc[wave] = __popcll(m);
    __syncthreads();
    if (threadIdx.x == 0) bcnt[blockIdx.x] = wc[0] + wc[1] + wc[2] + wc[3];
}

__global__ void k_scan(const int* __restrict__ bcnt, int* __restrict__ boff,
                       int* __restrict__ count) {
    __shared__ int s[NBLK];
    int t = threadIdx.x;
    for (int i = t; i < NBLK; i += 256) s[i] = bcnt[i];
    __syncthreads();
    if (t == 0) {
        int acc = 0;
        for (int i = 0; i < NBLK; i++) { int v = s[i]; s[i] = acc; acc += v; }
        *count = acc;
    }
    __syncthreads();
    for (int i = t; i < NBLK; i += 256) boff[i] = s[i];
}

__global__ void k_fill(const int* __restrict__ lastpos, const int* __restrict__ boff,
                       int* __restrict__ comp, int* __restrict__ inv) {
    int n = blockIdx.x * 256 + threadIdx.x;
    int flag = (n < NN && lastpos[n] >= 0) ? 1 : 0;
    unsigned long long m = __ballot(flag != 0);
    __shared__ int wc[4];
    int wave = threadIdx.x >> 6, lane = threadIdx.x & 63;
    if (lane == 0) wc[wave] = __popcll(m);
    __syncthreads();
    int base = boff[blockIdx.x];
    for (int i = 0; i < wave; i++) base += wc[i];
    int rank = __popcll(m & ((1ull << lane) - 1));
    if (flag) {
        int pos = base + rank;
        comp[pos] = n;
        inv[n] = pos;
    }
}

// f32 -> f16 weight conversion into MFMA FRAGMENT ORDER (R6 version):
// elem offset = matbase + ((cgrp*KS + ks)*64 + lane)*8 + e
__global__ void k_cvtw(const float* __restrict__ W1, const float* __restrict__ W2,
                       const float* __restrict__ Wi, const float* __restrict__ Wh,
                       const float* __restrict__ Wq, const float* __restrict__ Wv,
                       const float* __restrict__ Wo, const float* __restrict__ mW1,
                       const float* __restrict__ mW2, const float* __restrict__ Wk,
                       _Float16* __restrict__ dst) {
    int f = blockIdx.x * 256 + threadIdx.x;   // fragment id, 81920 total
    if (f >= 81920) return;
    const float* src; int dstoff, K, lf, tr = -1;
    if      (f < 16384) { src = W1;  dstoff = 0;      K = 512; lf = f; }
    else if (f < 20480) { src = W2;  dstoff = 131072; K = 256; lf = f - 16384; }
    else if (f < 26624) { src = Wi;  dstoff = 163840; K = 128; lf = f - 20480; }
    else if (f < 32768) { src = Wh;  dstoff = 212992; K = 128; lf = f - 26624; }
    else if (f < 40960) { src = Wq;  dstoff = 262144; K = 256; lf = f - 32768; }
    else if (f < 47104) { src = Wv;  dstoff = 327680; K = 384; lf = f - 40960; }
    else if (f < 53248) { src = Wv + 128 * 384; dstoff = 376832; K = 384; lf = f - 47104; }
    else if (f < 61440) { src = Wo;  dstoff = 425984; K = 256; lf = f - 53248; }
    else if (f < 67584) { src = mW1; dstoff = 491520; K = 384; lf = f - 61440; }
    else if (f < 69632) { src = mW2; dstoff = 540672; K = 128; lf = f - 67584; }
    else if (f < 75776) { src = Wk;  dstoff = 557056; K = 128; lf = f - 69632; tr = 0; }
    else                { src = Wk;  dstoff = 606208; K = 128; lf = f - 75776; tr = 1; }
    int KS = K >> 5;
    int cgrp = lf / (KS * 64);
    int rem  = lf - cgrp * (KS * 64);
    int ks = rem >> 6, lane = rem & 63;
    int kg = lane >> 4, arow = lane & 15;
    int col = cgrp * 16 + arow;
    int k0 = ks * 32 + kg * 8;
    f16x8 h;
    if (tr < 0) {
        const float* p = src + (size_t)col * K + k0;
        float4 a = *(const float4*)p;
        float4 b = *(const float4*)(p + 4);
        h[0] = (_Float16)a.x; h[1] = (_Float16)a.y; h[2] = (_Float16)a.z; h[3] = (_Float16)a.w;
        h[4] = (_Float16)b.x; h[5] = (_Float16)b.y; h[6] = (_Float16)b.z; h[7] = (_Float16)b.w;
    } else {
        #pragma unroll
        for (int e = 0; e < 8; e++)
            h[e] = (_Float16)Wk[(size_t)(tr * 128 + k0 + e) * 384 + col];
    }
    *(f16x8*)(dst + dstoff + (size_t)lf * 8) = h;
}

// ---------------- Stage 1: 64 rows/block, 512 threads / 8 waves (R6-exact) ----------------
__device__ __forceinline__ int SWA(int r, int byteofs) {
    return r * 1024 + (byteofs ^ ((r & 7) << 4));
}

__device__ __forceinline__ f16x8 ldw4(const _Float16* W, int cg, int ks, int lane) {
    return *(const f16x8*)(W + (((size_t)cg * 4 + ks) * 64 + lane) * 8);
}

__global__ __launch_bounds__(512, 4)
void k_stage1(const int* __restrict__ comp, const int* __restrict__ count,
              const int* __restrict__ lastpos,
              const int* __restrict__ msg_dst, const int* __restrict__ msg_eidx,
              const int* __restrict__ msg_t, const int* __restrict__ last_update,
              const float* __restrict__ memory, const float* __restrict__ edge_feats,
              const float* __restrict__ time_w, const float* __restrict__ time_b,
              const _Float16* __restrict__ W1h, const float* __restrict__ b1,
              const _Float16* __restrict__ W2h, const float* __restrict__ b2,
              const _Float16* __restrict__ Wih, const _Float16* __restrict__ Whh,
              const float* __restrict__ bi, const float* __restrict__ bh,
              _Float16* __restrict__ new_mem)
{
    __shared__ char rawb[64 * 1024];
    __shared__ int sn[64], sd[64], se[64];
    __shared__ float sdt[64];

    int cnt = *count;
    int r0 = blockIdx.x * 64;
    if (r0 >= cnt) return;
    int tid = threadIdx.x;

    if (tid < 64) {
        int rr = r0 + tid;
        int j = (rr < cnt) ? rr : r0;
        int n = comp[j];
        int idx = lastpos[n];
        sn[tid] = n;
        sd[tid] = msg_dst[idx];
        se[tid] = msg_eidx[idx];
        sdt[tid] = (float)(msg_t[idx] - last_update[n]);
    }
    __syncthreads();

    #pragma unroll
    for (int it = 0; it < 6; it++) {
        int gi = tid + it * 512;
        int r = gi / 48, g = gi - r * 48;
        const float* src;
        if (g < 16)      src = memory + (size_t)sn[r] * 128 + g * 8;
        else if (g < 32) src = memory + (size_t)sd[r] * 128 + (g - 16) * 8;
        else             src = edge_feats + (size_t)se[r] * 128 + (g - 32) * 8;
        float4 a = *(const float4*)src;
        float4 b = *(const float4*)(src + 4);
        f16x8 h;
        h[0] = (_Float16)a.x; h[1] = (_Float16)a.y; h[2] = (_Float16)a.z; h[3] = (_Float16)a.w;
        h[4] = (_Float16)b.x; h[5] = (_Float16)b.y; h[6] = (_Float16)b.z; h[7] = (_Float16)b.w;
        *(f16x8*)(rawb + SWA(r, g * 16)) = h;
    }
    #pragma unroll
    for (int it = 0; it < 2; it++) {
        int gi = tid + it * 512;
        int r = gi >> 4, g = gi & 15;
        int c = g * 8;
        float dt = sdt[r];
        float4 w0 = *(const float4*)(time_w + c);
        float4 w1 = *(const float4*)(time_w + c + 4);
        float4 t0 = *(const float4*)(time_b + c);
        float4 t1 = *(const float4*)(time_b + c + 4);
        f16x8 h;
        h[0] = (_Float16)tenc(dt, w0.x, t0.x); h[1] = (_Float16)tenc(dt, w0.y, t0.y);
        h[2] = (_Float16)tenc(dt, w0.z, t0.z); h[3] = (_Float16)tenc(dt, w0.w, t0.w);
        h[4] = (_Float16)tenc(dt, w1.x, t1.x); h[5] = (_Float16)tenc(dt, w1.y, t1.y);
        h[6] = (_Float16)tenc(dt, w1.z, t1.z); h[7] = (_Float16)tenc(dt, w1.w, t1.w);
        *(f16x8*)(rawb + SWA(r, (48 + g) * 16)) = h;
    }
    __syncthreads();

    int wv = tid >> 6, lane = tid & 63;
    int arow = lane & 15, kg = lane >> 4;

    f32x4 acc1[2][4];
    #pragma unroll
    for (int c = 0; c < 2; c++)
        #pragma unroll
        for (int rt = 0; rt < 4; rt++) acc1[c][rt] = z4();
    for (int ks = 0; ks < 16; ks++) {
        f16x8 a[4];
        #pragma unroll
        for (int rt = 0; rt < 4; rt++)
            a[rt] = *(const f16x8*)(rawb + SWA(rt * 16 + arow, ks * 64 + kg * 16));
        #pragma unroll
        for (int c = 0; c < 2; c++) {
            f16x8 b = *(const f16x8*)(W1h + (((size_t)(wv * 2 + c) * 16 + ks) * 64 + lane) * 8);
            #pragma unroll
            for (int rt = 0; rt < 4; rt++)
                acc1[c][rt] = MFMA16(a[rt], b, acc1[c][rt]);
        }
    }
    __syncthreads();

    #pragma unroll
    for (int c = 0; c < 2; c++) {
        int col = (wv * 2 + c) * 16 + arow;
        float bb = b1[col];
        #pragma unroll
        for (int rt = 0; rt < 4; rt++)
            #pragma unroll
            for (int rg = 0; rg < 4; rg++) {
                int row = rt * 16 + kg * 4 + rg;
                float v = fmaxf(acc1[c][rt][rg] + bb, 0.f);
                *(_Float16*)(rawb + SWA(row, 384 + col * 2)) = (_Float16)v;
            }
    }
    __syncthreads();

    f32x4 acc2[4];
    #pragma unroll
    for (int rt = 0; rt < 4; rt++) acc2[rt] = z4();
    for (int ks = 0; ks < 8; ks++) {
        f16x8 b = *(const f16x8*)(W2h + (((size_t)wv * 8 + ks) * 64 + lane) * 8);
        #pragma unroll
        for (int rt = 0; rt < 4; rt++) {
            f16x8 a = *(const f16x8*)(rawb + SWA(rt * 16 + arow, 384 + ks * 64 + kg * 16));
            acc2[rt] = MFMA16(a, b, acc2[rt]);
        }
    }
    __syncthreads();

    {
        int col = wv * 16 + arow;
        float bb = b2[col];
        #pragma unroll
        for (int rt = 0; rt < 4; rt++)
            #pragma unroll
            for (int rg = 0; rg < 4; rg++) {
                int row = rt * 16 + kg * 4 + rg;
                *(_Float16*)(rawb + SWA(row, 384 + col * 2)) =
                    (_Float16)(acc2[rt][rg] + bb);
            }
    }
    __syncthreads();

    f32x4 aR[4], aZ[4], aNi[4], aNh[4];
    #pragma unroll
    for (int rt = 0; rt < 4; rt++) { aR[rt] = z4(); aZ[rt] = z4(); aNi[rt] = z4(); aNh[rt] = z4(); }
    for (int ks = 0; ks < 4; ks++) {
        f16x8 bi_ = ldw4(Wih, wv, ks, lane);
        f16x8 bh_ = ldw4(Whh, wv, ks, lane);
        #pragma unroll
        for (int rt = 0; rt < 4; rt++) {
            f16x8 m = *(const f16x8*)(rawb + SWA(rt * 16 + arow, 384 + ks * 64 + kg * 16));
            f16x8 hh = *(const f16x8*)(rawb + SWA(rt * 16 + arow, ks * 64 + kg * 16));
            aR[rt] = MFMA16(m, bi_, aR[rt]);
            aR[rt] = MFMA16(hh, bh_, aR[rt]);
        }
    }
    for (int ks = 0; ks < 4; ks++) {
        f16x8 bi_ = ldw4(Wih, 8 + wv, ks, lane);
        f16x8 bh_ = ldw4(Whh, 8 + wv, ks, lane);
        #pragma unroll
        for (int rt = 0; rt < 4; rt++) {
            f16x8 m = *(const f16x8*)(rawb + SWA(rt * 16 + arow, 384 + ks * 64 + kg * 16));
            f16x8 hh = *(const f16x8*)(rawb + SWA(rt * 16 + arow, ks * 64 + kg * 16));
            aZ[rt] = MFMA16(m, bi_, aZ[rt]);
            aZ[rt] = MFMA16(hh, bh_, aZ[rt]);
        }
    }
    for (int ks = 0; ks < 4; ks++) {
        f16x8 bi_ = ldw4(Wih, 16 + wv, ks, lane);
        f16x8 bh_ = ldw4(Whh, 16 + wv, ks, lane);
        #pragma unroll
        for (int rt = 0; rt < 4; rt++) {
            f16x8 m = *(const f16x8*)(rawb + SWA(rt * 16 + arow, 384 + ks * 64 + kg * 16));
            f16x8 hh = *(const f16x8*)(rawb + SWA(rt * 16 + arow, ks * 64 + kg * 16));
            aNi[rt] = MFMA16(m, bi_, aNi[rt]);
            aNh[rt] = MFMA16(hh, bh_, aNh[rt]);
        }
    }

    {
        int col = wv * 16 + arow;
        float bir = bi[col],        bhr = bh[col];
        float biz = bi[128 + col],  bhz = bh[128 + col];
        float bin_ = bi[256 + col], bhn_ = bh[256 + col];
        #pragma unroll
        for (int rt = 0; rt < 4; rt++)
            #pragma unroll
            for (int rg = 0; rg < 4; rg++) {
                int row = rt * 16 + kg * 4 + rg;
                int rr = r0 + row;
                if (rr < cnt) {
                    float r_ = fsigm(aR[rt][rg] + bir + bhr);
                    float zg = fsigm(aZ[rt][rg] + biz + bhz);
                    float ng = ftanh(aNi[rt][rg] + bin_ + r_ * (aNh[rt][rg] + bhn_));
                    float om = (float)*(const _Float16*)(rawb + SWA(row, col * 2));
                    new_mem[(size_t)rr * 128 + col] = (_Float16)((1.f - zg) * ng + zg * om);
                }
            }
    }
}

// k_feat: feat[n] = (updated ? new_mem[inv[n]] : memory[n]) + node_feats[n], f16
__global__ __launch_bounds__(256)
void k_feat(const int* __restrict__ inv, const _Float16* __restrict__ new_mem,
            const float* __restrict__ memory, const float* __restrict__ node_feats,
            _Float16* __restrict__ feat)
{
    int idx = blockIdx.x * 256 + threadIdx.x;
    if (idx >= NN * 16) return;
    int n = idx >> 4, g = idx & 15;
    int c = g * 8;
    int iv = inv[n];
    float4 n0 = *(const float4*)(node_feats + (size_t)n * 128 + c);
    float4 n1 = *(const float4*)(node_feats + (size_t)n * 128 + c + 4);
    f16x8 o;
    if (iv >= 0) {
        f16x8 mv = *(const f16x8*)(new_mem + (size_t)iv * 128 + c);
        o[0] = (_Float16)((float)mv[0] + n0.x); o[1] = (_Float16)((float)mv[1] + n0.y);
        o[2] = (_Float16)((float)mv[2] + n0.z); o[3] = (_Float16)((float)mv[3] + n0.w);
        o[4] = (_Float16)((float)mv[4] + n1.x); o[5] = (_Float16)((float)mv[5] + n1.y);
        o[6] = (_Float16)((float)mv[6] + n1.z); o[7] = (_Float16)((float)mv[7] + n1.w);
    } else {
        float4 m0 = *(const float4*)(memory + (size_t)n * 128 + c);
        float4 m1 = *(const float4*)(memory + (size_t)n * 128 + c + 4);
        o[0] = (_Float16)(m0.x + n0.x); o[1] = (_Float16)(m0.y + n0.y);
        o[2] = (_Float16)(m0.z + n0.z); o[3] = (_Float16)(m0.w + n0.w);
        o[4] = (_Float16)(m1.x + n1.x); o[5] = (_Float16)(m1.y + n1.y);
        o[6] = (_Float16)(m1.z + n1.z); o[7] = (_Float16)(m1.w + n1.w);
    }
    *(f16x8*)(feat + (size_t)n * 128 + c) = o;
}

// ---------------- Stage 2 (R6-exact) ----------------
__global__ void k2a(const int* __restrict__ src_nodes, const int* __restrict__ dst_nodes,
                    const int* __restrict__ neg_nodes, const _Float16* __restrict__ feat,
                    const float* __restrict__ time_b,
                    _Float16* __restrict__ q_in, _Float16* __restrict__ acat)
{
    __shared__ int snode[32];
    int tid = threadIdx.x;
    int r0 = blockIdx.x * 32;
    if (tid < 32) {
        int q = r0 + tid;
        snode[tid] = (q < BB) ? src_nodes[q] : (q < 2 * BB) ? dst_nodes[q - BB] : neg_nodes[q - 2 * BB];
    }
    __syncthreads();
    #pragma unroll
    for (int it = 0; it < 4; it++) {
        int gi = tid + it * 256;
        int r = gi >> 5, ch = gi & 31;
        int c = ch * 4;
        int node = snode[r];
        f16x4 sf = *(const f16x4*)(feat + (size_t)node * 128 + c);
        size_t q = (size_t)(r0 + r);
        *(f16x4*)(q_in + q * 256 + c) = sf;
        *(f16x4*)(acat + q * 384 + 256 + c) = sf;
        float4 tb = *(const float4*)(time_b + c);
        f16x4 te;
        te[0] = (_Float16)fast_cos(tb.x); te[1] = (_Float16)fast_cos(tb.y);
        te[2] = (_Float16)fast_cos(tb.z); te[3] = (_Float16)fast_cos(tb.w);
        *(f16x4*)(q_in + q * 256 + 128 + c) = te;
    }
}

// generic 32-row-tile MFMA GEMM, fragment-ordered B.
template<int KD, int NFRAG, bool RELU>
__global__ __launch_bounds__(256, 4)
void k_gemm(const _Float16* __restrict__ A, int lda, int a_ys,
            const _Float16* __restrict__ B, int b_ys,
            const float* __restrict__ bias, int bias_ys,
            _Float16* __restrict__ C, int ldc, int c_ys,
            float* __restrict__ C32,
            const int* __restrict__ rowmask)
{
    constexpr int ROWB = KD * 2;
    __shared__ char As[32 * ROWB];
    int tid = threadIdx.x;
    int r0 = blockIdx.x * 32;
    int aoff = blockIdx.y * a_ys;
    const _Float16* Bp = B + (size_t)blockIdx.y * b_ys;
    int coff = blockIdx.y * c_ys;

    #pragma unroll
    for (int t = 0; t < (32 * KD / 8) / 256; t++) {
        int gi = tid + t * 256;
        int r = gi / (KD / 8), g = gi % (KD / 8);
        f16x8 v = *(const f16x8*)(A + (size_t)(r0 + r) * lda + aoff + g * 8);
        *(f16x8*)(&As[r * ROWB + ((g * 16) ^ ((r & 7) << 4))]) = v;
    }
    __syncthreads();

    int wv = tid >> 6, lane = tid & 63;
    int arow = lane & 15, kg = lane >> 4;
    f32x4 acc[NFRAG][2];
    #pragma unroll
    for (int c = 0; c < NFRAG; c++) { acc[c][0] = z4(); acc[c][1] = z4(); }

    #pragma unroll
    for (int ks = 0; ks < KD / 32; ks++) {
        f16x8 a0 = *(const f16x8*)(&As[arow * ROWB + ((ks * 64 + kg * 16) ^ ((arow & 7) << 4))]);
        f16x8 a1 = *(const f16x8*)(&As[(16 + arow) * ROWB + ((ks * 64 + kg * 16) ^ ((arow & 7) << 4))]);
        #pragma unroll
        for (int c = 0; c < NFRAG; c++) {
            f16x8 b = *(const f16x8*)(Bp +
                (((size_t)(wv * NFRAG + c) * (KD / 32) + ks) * 64 + lane) * 8);
            acc[c][0] = MFMA16(a0, b, acc[c][0]);
            acc[c][1] = MFMA16(a1, b, acc[c][1]);
        }
    }

    #pragma unroll
    for (int c = 0; c < NFRAG; c++) {
        int cg = (wv * NFRAG + c) * 16 + arow;
        float bb = bias ? bias[blockIdx.y * bias_ys + cg] : 0.f;
        #pragma unroll
        for (int rt = 0; rt < 2; rt++)
            #pragma unroll
            for (int rg = 0; rg < 4; rg++) {
                int grow = r0 + rt * 16 + kg * 4 + rg;
                float v = acc[c][rt][rg] + bb;
                if (RELU) v = fmaxf(v, 0.f);
                if (rowmask && rowmask[grow]) v = 0.f;
                if (C)   C[(size_t)grow * ldc + coff + cg] = (_Float16)v;
                if (C32) C32[(size_t)grow * ldc + coff + cg] = v;
            }
    }
}

// k2d: attention core (R6-exact). 1 query/wave, head per half-wave, no LDS,
// depth-1 pipelined gathers; feat (f16) replaces mem+node_feats+inv.
__global__ __launch_bounds__(256)
void k2d(const int* __restrict__ neighbors, const int* __restrict__ nb_eidx,
         const int* __restrict__ nb_et, const int* __restrict__ edge_times,
         const _Float16* __restrict__ feat,
         const float* __restrict__ edge_feats, const float* __restrict__ time_w,
         const float* __restrict__ time_b, const float* __restrict__ bk,
         const _Float16* __restrict__ qbuf, _Float16* __restrict__ qk_wsum,
         int* __restrict__ allm)
{
    int tid = threadIdx.x;
    int qi = blockIdx.x * 4 + (tid >> 6);
    int lane = tid & 63;
    int h = lane >> 5, l32 = lane & 31;
    int c0 = l32 * 4;

    float4 tw = *(const float4*)(time_w + c0);
    float4 tb = *(const float4*)(time_b + c0);

    const _Float16* qkp = qk_wsum + (size_t)qi * 768 + h * 384;
    f16x4 t0 = *(const f16x4*)(qkp + c0);
    f16x4 t1 = *(const f16x4*)(qkp + 128 + c0);
    f16x4 t2 = *(const f16x4*)(qkp + 256 + c0);
    float qk0[4], qk1[4], qk2[4];
    #pragma unroll
    for (int t = 0; t < 4; t++) { qk0[t] = (float)t0[t]; qk1[t] = (float)t1[t]; qk2[t] = (float)t2[t]; }

    f16x4 qv = *(const f16x4*)(qbuf + (size_t)qi * 256 + h * 128 + c0);
    float4 bkv = *(const float4*)(bk + h * 128 + c0);
    float cb = (float)qv[0] * bkv.x + (float)qv[1] * bkv.y +
               (float)qv[2] * bkv.z + (float)qv[3] * bkv.w;
    cb += __shfl_xor(cb, 1, 32);
    cb += __shfl_xor(cb, 2, 32);
    cb += __shfl_xor(cb, 4, 32);
    cb += __shfl_xor(cb, 8, 32);
    cb += __shfl_xor(cb, 16, 32);

    float ts = (float)edge_times[qi & (BB - 1)];
    float m_run = -3.0e38f, l_run = 0.f;
    float w0[4] = {0,0,0,0}, w1[4] = {0,0,0,0}, w2[4] = {0,0,0,0};
    int anyv = 0;
    const float inv_sqrt = 0.08838834764831845f;

    int base = qi * KK;
    int nb_c = neighbors[base];
    int ei_c = nb_eidx[base];
    int et_c = nb_et[base];
    f16x4 fv;
    float4 ef;
    {
        fv = *(const f16x4*)(feat + (size_t)nb_c * 128 + c0);
        ef = *(const float4*)(edge_feats + (size_t)ei_c * 128 + c0);
    }

    for (int j = 0; j < KK; j++) {
        int nb_n = 0, ei_n = 0, et_n = 0;
        f16x4 fv_n = {0,0,0,0};
        float4 ef_n = {0,0,0,0};
        if (j + 1 < KK) {
            nb_n = neighbors[base + j + 1];
            ei_n = nb_eidx[base + j + 1];
            et_n = nb_et[base + j + 1];
            fv_n = *(const f16x4*)(feat + (size_t)nb_n * 128 + c0);
            ef_n = *(const float4*)(edge_feats + (size_t)ei_n * 128 + c0);
        }

        float dtf = ts - (float)et_c;
        anyv |= (nb_c != 0);
        float k0[4] = { (float)fv[0], (float)fv[1], (float)fv[2], (float)fv[3] };
        float k1[4] = { tenc(dtf, tw.x, tb.x), tenc(dtf, tw.y, tb.y),
                        tenc(dtf, tw.z, tb.z), tenc(dtf, tw.w, tb.w) };
        float k2[4] = { ef.x, ef.y, ef.z, ef.w };

        float sp = 0.f;
        #pragma unroll
        for (int t = 0; t < 4; t++)
            sp += qk0[t] * k0[t] + qk1[t] * k1[t] + qk2[t] * k2[t];
        sp += __shfl_xor(sp, 1, 32);
        sp += __shfl_xor(sp, 2, 32);
        sp += __shfl_xor(sp, 4, 32);
        sp += __shfl_xor(sp, 8, 32);
        sp += __shfl_xor(sp, 16, 32);

        float s = (sp + cb) * inv_sqrt;
        if (nb_c == 0) s = -1e9f;
        float m_new = fmaxf(m_run, s);
        float sc = __expf(m_run - m_new);
        float p = __expf(s - m_new);
        l_run = l_run * sc + p;
        #pragma unroll
        for (int t = 0; t < 4; t++) {
            w0[t] = w0[t] * sc + p * k0[t];
            w1[t] = w1[t] * sc + p * k1[t];
            w2[t] = w2[t] * sc + p * k2[t];
        }
        m_run = m_new;

        nb_c = nb_n; ei_c = ei_n; et_c = et_n;
        fv = fv_n; ef = ef_n;
    }

    float linv = __builtin_amdgcn_rcpf(l_run);
    _Float16* wp = qk_wsum + (size_t)qi * 768 + h * 384;
    f16x4 o0, o1, o2;
    #pragma unroll
    for (int t = 0; t < 4; t++) {
        o0[t] = (_Float16)(w0[t] * linv);
        o1[t] = (_Float16)(w1[t] * linv);
        o2[t] = (_Float16)(w2[t] * linv);
    }
    *(f16x4*)(wp + c0) = o0;
    *(f16x4*)(wp + 128 + c0) = o1;
    *(f16x4*)(wp + 256 + c0) = o2;
    if (lane == 0) allm[qi] = anyv ? 0 : 1;
}

extern "C" void kernel_launch(void* const* d_in, const int* in_sizes, int n_in,
                              void* d_out, int out_size, void* d_ws, size_t ws_size,
                              hipStream_t stream) {
    (void)in_sizes; (void)n_in; (void)out_size; (void)ws_size;
    const int* src_nodes  = (const int*)d_in[0];
    const int* dst_nodes  = (const int*)d_in[1];
    const int* neg_nodes  = (const int*)d_in[2];
    const int* edge_times = (const int*)d_in[3];
    const int* neighbors  = (const int*)d_in[4];
    const int* nb_eidx    = (const int*)d_in[5];
    const int* nb_et      = (const int*)d_in[6];
    const int* msg_src    = (const int*)d_in[7];
    const int* msg_dst    = (const int*)d_in[8];
    const int* msg_eidx   = (const int*)d_in[9];
    const int* msg_t      = (const int*)d_in[10];
    const int* last_update= (const int*)d_in[11];
    const float* node_feats = (const float*)d_in[12];
    const float* edge_feats = (const float*)d_in[13];
    const float* memory     = (const float*)d_in[14];
    const float* time_w = (const float*)d_in[15];
    const float* time_b = (const float*)d_in[16];
    const float* W1 = (const float*)d_in[17];
    const float* b1 = (const float*)d_in[18];
    const float* W2 = (const float*)d_in[19];
    const float* b2 = (const float*)d_in[20];
    const float* gWi = (const float*)d_in[21];
    const float* gWh = (const float*)d_in[22];
    const float* gbi = (const float*)d_in[23];
    const float* gbh = (const float*)d_in[24];
    const float* Wq = (const float*)d_in[25];
    const float* bq = (const float*)d_in[26];
    const float* Wk = (const float*)d_in[27];
    const float* bk = (const float*)d_in[28];
    const float* Wv = (const float*)d_in[29];
    const float* bv = (const float*)d_in[30];
    const float* Wo = (const float*)d_in[31];
    const float* bo = (const float*)d_in[32];
    const float* mW1 = (const float*)d_in[33];
    const float* mb1 = (const float*)d_in[34];
    const float* mW2 = (const float*)d_in[35];
    const float* mb2 = (const float*)d_in[36];
    float* out = (float*)d_out;

    char* w = (char*)d_ws;
    int* lastpos = (int*)w;
    int* inv  = lastpos + NN;
    int* comp = inv + NN;
    int* count = comp + NN;
    int* bcnt = count + 1;
    int* boff = bcnt + NBLK;
    size_t off = ((size_t)(3 * NN + 1 + 2 * NBLK) * 4 + 255) & ~(size_t)255;
    _Float16* new_mem = (_Float16*)(w + off);         // MM*128 f16
    size_t foff = off + (size_t)MM * 128 * 2;
    _Float16* feat = (_Float16*)(w + foff);           // NN*128 f16
    size_t woff = foff + (size_t)NN * 128 * 2;

    _Float16* Hpool = (_Float16*)(w + woff);          // 655360 f16, fragment order
    _Float16* W1h  = Hpool;
    _Float16* W2h  = Hpool + 131072;
    _Float16* Wih  = Hpool + 163840;
    _Float16* Whh  = Hpool + 212992;
    _Float16* Wqh  = Hpool + 262144;
    _Float16* Wvh  = Hpool + 327680;
    _Float16* Woh  = Hpool + 425984;
    _Float16* mW1h = Hpool + 491520;
    _Float16* mW2h = Hpool + 540672;
    _Float16* Wkth = Hpool + 557056;
    size_t boff2 = woff + (size_t)655360 * 2;

    _Float16* qin_ctx = (_Float16*)(w + boff2);
    _Float16* q_hm    = qin_ctx + (size_t)Q3 * 256;
    _Float16* qk_ws   = q_hm + (size_t)Q3 * 256;
    _Float16* acat    = qk_ws + (size_t)Q3 * 768;
    int* allm         = (int*)(acat + (size_t)Q3 * 384);

    k_init<<<dim3(NBLK), dim3(256), 0, stream>>>(lastpos, inv);
    k_scatter<<<dim3((MM + 255) / 256), dim3(256), 0, stream>>>(msg_src, lastpos);
    k_count<<<dim3(NBLK), dim3(256), 0, stream>>>(lastpos, bcnt);
    k_scan<<<dim3(1), dim3(256), 0, stream>>>(bcnt, boff, count);
    k_fill<<<dim3(NBLK), dim3(256), 0, stream>>>(lastpos, boff, comp, inv);
    k_cvtw<<<dim3(320), dim3(256), 0, stream>>>(W1, W2, gWi, gWh, Wq, Wv, Wo, mW1, mW2, Wk, Hpool);
    k_stage1<<<dim3((MM + 63) / 64), dim3(512), 0, stream>>>(
        comp, count, lastpos, msg_dst, msg_eidx, msg_t, last_update,
        memory, edge_feats, time_w, time_b,
        W1h, b1, W2h, b2, Wih, Whh, gbi, gbh, new_mem);
    k_feat<<<dim3(NN * 16 / 256), dim3(256), 0, stream>>>(
        inv, new_mem, memory, node_feats, feat);

    k2a<<<dim3(Q3 / 32), dim3(256), 0, stream>>>(
        src_nodes, dst_nodes, neg_nodes, feat, time_b, qin_ctx, acat);
    k_gemm<256, 4, false><<<dim3(Q3 / 32, 1), dim3(256), 0, stream>>>(
        qin_ctx, 256, 0, Wqh, 0, bq, 0, q_hm, 256, 0, nullptr, nullptr);
    k_gemm<128, 6, false><<<dim3(Q3 / 32, 2), dim3(256), 0, stream>>>(
        q_hm, 256, 128, Wkth, 384 * 128, nullptr, 0, qk_ws, 768, 384, nullptr, nullptr);
    k2d<<<dim3(Q3 / 4), dim3(256), 0, stream>>>(
        neighbors, nb_eidx, nb_et, edge_times, feat,
        edge_feats, time_w, time_b, bk, q_hm, qk_ws, allm);
    k_gemm<384, 2, false><<<dim3(Q3 / 32, 2), dim3(256), 0, stream>>>(
        qk_ws, 768, 384, Wvh, 128 * 384, bv, 128, qin_ctx, 256, 128, nullptr, nullptr);
    k_gemm<256, 4, false><<<dim3(Q3 / 32, 1), dim3(256), 0, stream>>>(
        qin_ctx, 256, 0, Woh, 0, bo, 0, acat, 384, 0, nullptr, allm);
    k_gemm<384, 2, true><<<dim3(Q3 / 32, 1), dim3(256), 0, stream>>>(
        acat, 384, 0, mW1h, 0, mb1, 0, q_hm, 128, 0, nullptr, nullptr);
    k_gemm<128, 2, false><<<dim3(Q3 / 32, 1), dim3(256), 0, stream>>>(
        q_hm, 128, 0, mW2h, 0, mb2, 0, nullptr, 128, 0, out, nullptr);
}

// Round 10
// 308.126 us; speedup vs baseline: 1.2818x; 1.0776x over previous
//
#include <hip/hip_runtime.h>
#include <math.h>

#define NN 200000
#define EEDGE 500000
#define BB 4096
#define KK 20
#define MM 100000
#define Q3 (3*BB)
#define NBLK ((NN + 255) / 256)

typedef _Float16 __attribute__((ext_vector_type(8))) f16x8;
typedef _Float16 __attribute__((ext_vector_type(4))) f16x4;
typedef float __attribute__((ext_vector_type(4))) f32x4;

#define MFMA16(a,b,c) __builtin_amdgcn_mfma_f32_16x16x32_f16(a,b,c,0,0,0)

// cos(a) for |a| up to ~1e7: f64 range-reduction to revolutions + v_cos_f32.
__device__ __forceinline__ float fast_cos(float a) {
    double ad = (double)a * 0.15915494309189535;   // 1/(2*pi)
    double fr = ad - floor(ad);                    // [0,1) revolutions
    return __builtin_amdgcn_cosf((float)fr);       // cos(2*pi*x)
}

// time encoding matching numpy's f32 arg rounding — NO fma contraction.
__device__ __forceinline__ float tenc(float dt, float w, float b) {
    float p = __fmul_rn(dt, w);
    float a = __fadd_rn(p, b);
    return fast_cos(a);
}

__device__ __forceinline__ float fsigm(float x) {
    return __builtin_amdgcn_rcpf(1.f + __expf(-x));
}
__device__ __forceinline__ float ftanh(float x) {
    return 1.f - 2.f * __builtin_amdgcn_rcpf(1.f + __expf(2.f * x));
}

__device__ __forceinline__ f32x4 z4() {
    f32x4 v; v[0] = 0.f; v[1] = 0.f; v[2] = 0.f; v[3] = 0.f; return v;
}

__global__ void k_init(int* lastpos, int* inv) {
    int i = blockIdx.x * 256 + threadIdx.x;
    if (i < NN) { lastpos[i] = -1; inv[i] = -1; }
}

__global__ void k_scatter(const int* __restrict__ msg_src, int* __restrict__ lastpos) {
    int i = blockIdx.x * 256 + threadIdx.x;
    if (i < MM) atomicMax(&lastpos[msg_src[i]], i);
}

// ordered (sorted-by-node) compaction: count -> scan -> fill (R9-proven: -26us)
__global__ void k_count(const int* __restrict__ lastpos, int* __restrict__ bcnt) {
    int n = blockIdx.x * 256 + threadIdx.x;
    int flag = (n < NN && lastpos[n] >= 0) ? 1 : 0;
    unsigned long long m = __ballot(flag != 0);
    __shared__ int wc[4];
    int wave = threadIdx.x >> 6, lane = threadIdx.x & 63;
    if (lane == 0) wc[wave] = __popcll(m);
    __syncthreads();
    if (threadIdx.x == 0) bcnt[blockIdx.x] = wc[0] + wc[1] + wc[2] + wc[3];
}

__global__ void k_scan(const int* __restrict__ bcnt, int* __restrict__ boff,
                       int* __restrict__ count) {
    __shared__ int s[NBLK];
    int t = threadIdx.x;
    for (int i = t; i < NBLK; i += 256) s[i] = bcnt[i];
    __syncthreads();
    if (t == 0) {
        int acc = 0;
        for (int i = 0; i < NBLK; i++) { int v = s[i]; s[i] = acc; acc += v; }
        *count = acc;
    }
    __syncthreads();
    for (int i = t; i < NBLK; i += 256) boff[i] = s[i];
}

__global__ void k_fill(const int* __restrict__ lastpos, const int* __restrict__ boff,
                       int* __restrict__ comp, int* __restrict__ inv) {
    int n = blockIdx.x * 256 + threadIdx.x;
    int flag = (n < NN && lastpos[n] >= 0) ? 1 : 0;
    unsigned long long m = __ballot(flag != 0);
    __shared__ int wc[4];
    int wave = threadIdx.x >> 6, lane = threadIdx.x & 63;
    if (lane == 0) wc[wave] = __popcll(m);
    __syncthreads();
    int base = boff[blockIdx.x];
    for (int i = 0; i < wave; i++) base += wc[i];
    int rank = __popcll(m & ((1ull << lane) - 1));
    if (flag) {
        int pos = base + rank;
        comp[pos] = n;
        inv[n] = pos;
    }
}

// f32 -> f16 weight conversion into MFMA FRAGMENT ORDER:
// elem offset = matbase + ((cgrp*KS + ks)*64 + lane)*8 + e
__global__ void k_cvtw(const float* __restrict__ W1, const float* __restrict__ W2,
                       const float* __restrict__ Wi, const float* __restrict__ Wh,
                       const float* __restrict__ Wq, const float* __restrict__ Wv,
                       const float* __restrict__ Wo, const float* __restrict__ mW1,
                       const float* __restrict__ mW2, const float* __restrict__ Wk,
                       _Float16* __restrict__ dst) {
    int f = blockIdx.x * 256 + threadIdx.x;   // fragment id, 81920 total
    if (f >= 81920) return;
    const float* src; int dstoff, K, lf, tr = -1;
    if      (f < 16384) { src = W1;  dstoff = 0;      K = 512; lf = f; }
    else if (f < 20480) { src = W2;  dstoff = 131072; K = 256; lf = f - 16384; }
    else if (f < 26624) { src = Wi;  dstoff = 163840; K = 128; lf = f - 20480; }
    else if (f < 32768) { src = Wh;  dstoff = 212992; K = 128; lf = f - 26624; }
    else if (f < 40960) { src = Wq;  dstoff = 262144; K = 256; lf = f - 32768; }
    else if (f < 47104) { src = Wv;  dstoff = 327680; K = 384; lf = f - 40960; }
    else if (f < 53248) { src = Wv + 128 * 384; dstoff = 376832; K = 384; lf = f - 47104; }
    else if (f < 61440) { src = Wo;  dstoff = 425984; K = 256; lf = f - 53248; }
    else if (f < 67584) { src = mW1; dstoff = 491520; K = 384; lf = f - 61440; }
    else if (f < 69632) { src = mW2; dstoff = 540672; K = 128; lf = f - 67584; }
    else if (f < 75776) { src = Wk;  dstoff = 557056; K = 128; lf = f - 69632; tr = 0; }
    else                { src = Wk;  dstoff = 606208; K = 128; lf = f - 75776; tr = 1; }
    int KS = K >> 5;
    int cgrp = lf / (KS * 64);
    int rem  = lf - cgrp * (KS * 64);
    int ks = rem >> 6, lane = rem & 63;
    int kg = lane >> 4, arow = lane & 15;
    int col = cgrp * 16 + arow;
    int k0 = ks * 32 + kg * 8;
    f16x8 h;
    if (tr < 0) {
        const float* p = src + (size_t)col * K + k0;
        float4 a = *(const float4*)p;
        float4 b = *(const float4*)(p + 4);
        h[0] = (_Float16)a.x; h[1] = (_Float16)a.y; h[2] = (_Float16)a.z; h[3] = (_Float16)a.w;
        h[4] = (_Float16)b.x; h[5] = (_Float16)b.y; h[6] = (_Float16)b.z; h[7] = (_Float16)b.w;
    } else {
        #pragma unroll
        for (int e = 0; e < 8; e++)
            h[e] = (_Float16)Wk[(size_t)(tr * 128 + k0 + e) * 384 + col];
    }
    *(f16x8*)(dst + dstoff + (size_t)lf * 8) = h;
}

// ---------------- Stage 1: 64 rows/block, 512 threads / 8 waves ----------------
// launch_bounds (512,2): occupancy is LDS-capped at 2 blocks/CU anyway;
// declaring 2 waves/EU gives the allocator 128 VGPRs for load pipelining.
__device__ __forceinline__ int SWA(int r, int byteofs) {
    return r * 1024 + (byteofs ^ ((r & 7) << 4));
}

__device__ __forceinline__ f16x8 ldw4(const _Float16* W, int cg, int ks, int lane) {
    return *(const f16x8*)(W + (((size_t)cg * 4 + ks) * 64 + lane) * 8);
}

__global__ __launch_bounds__(512, 2)
void k_stage1(const int* __restrict__ comp, const int* __restrict__ count,
              const int* __restrict__ lastpos,
              const int* __restrict__ msg_dst, const int* __restrict__ msg_eidx,
              const int* __restrict__ msg_t, const int* __restrict__ last_update,
              const float* __restrict__ memory, const float* __restrict__ edge_feats,
              const float* __restrict__ time_w, const float* __restrict__ time_b,
              const _Float16* __restrict__ W1h, const float* __restrict__ b1,
              const _Float16* __restrict__ W2h, const float* __restrict__ b2,
              const _Float16* __restrict__ Wih, const _Float16* __restrict__ Whh,
              const float* __restrict__ bi, const float* __restrict__ bh,
              _Float16* __restrict__ new_mem)
{
    __shared__ char rawb[64 * 1024];
    __shared__ int sn[64], sd[64], se[64];
    __shared__ float sdt[64];

    int cnt = *count;
    int r0 = blockIdx.x * 64;
    if (r0 >= cnt) return;
    int tid = threadIdx.x;

    if (tid < 64) {
        int rr = r0 + tid;
        int j = (rr < cnt) ? rr : r0;
        int n = comp[j];
        int idx = lastpos[n];
        sn[tid] = n;
        sd[tid] = msg_dst[idx];
        se[tid] = msg_eidx[idx];
        sdt[tid] = (float)(msg_t[idx] - last_update[n]);
    }
    __syncthreads();

    #pragma unroll
    for (int it = 0; it < 6; it++) {
        int gi = tid + it * 512;
        int r = gi / 48, g = gi - r * 48;
        const float* src;
        if (g < 16)      src = memory + (size_t)sn[r] * 128 + g * 8;
        else if (g < 32) src = memory + (size_t)sd[r] * 128 + (g - 16) * 8;
        else             src = edge_feats + (size_t)se[r] * 128 + (g - 32) * 8;
        float4 a = *(const float4*)src;
        float4 b = *(const float4*)(src + 4);
        f16x8 h;
        h[0] = (_Float16)a.x; h[1] = (_Float16)a.y; h[2] = (_Float16)a.z; h[3] = (_Float16)a.w;
        h[4] = (_Float16)b.x; h[5] = (_Float16)b.y; h[6] = (_Float16)b.z; h[7] = (_Float16)b.w;
        *(f16x8*)(rawb + SWA(r, g * 16)) = h;
    }
    #pragma unroll
    for (int it = 0; it < 2; it++) {
        int gi = tid + it * 512;
        int r = gi >> 4, g = gi & 15;
        int c = g * 8;
        float dt = sdt[r];
        float4 w0 = *(const float4*)(time_w + c);
        float4 w1 = *(const float4*)(time_w + c + 4);
        float4 t0 = *(const float4*)(time_b + c);
        float4 t1 = *(const float4*)(time_b + c + 4);
        f16x8 h;
        h[0] = (_Float16)tenc(dt, w0.x, t0.x); h[1] = (_Float16)tenc(dt, w0.y, t0.y);
        h[2] = (_Float16)tenc(dt, w0.z, t0.z); h[3] = (_Float16)tenc(dt, w0.w, t0.w);
        h[4] = (_Float16)tenc(dt, w1.x, t1.x); h[5] = (_Float16)tenc(dt, w1.y, t1.y);
        h[6] = (_Float16)tenc(dt, w1.z, t1.z); h[7] = (_Float16)tenc(dt, w1.w, t1.w);
        *(f16x8*)(rawb + SWA(r, (48 + g) * 16)) = h;
    }
    __syncthreads();

    int wv = tid >> 6, lane = tid & 63;
    int arow = lane & 15, kg = lane >> 4;

    f32x4 acc1[2][4];
    #pragma unroll
    for (int c = 0; c < 2; c++)
        #pragma unroll
        for (int rt = 0; rt < 4; rt++) acc1[c][rt] = z4();
    for (int ks = 0; ks < 16; ks++) {
        f16x8 a[4];
        #pragma unroll
        for (int rt = 0; rt < 4; rt++)
            a[rt] = *(const f16x8*)(rawb + SWA(rt * 16 + arow, ks * 64 + kg * 16));
        #pragma unroll
        for (int c = 0; c < 2; c++) {
            f16x8 b = *(const f16x8*)(W1h + (((size_t)(wv * 2 + c) * 16 + ks) * 64 + lane) * 8);
            #pragma unroll
            for (int rt = 0; rt < 4; rt++)
                acc1[c][rt] = MFMA16(a[rt], b, acc1[c][rt]);
        }
    }
    __syncthreads();

    #pragma unroll
    for (int c = 0; c < 2; c++) {
        int col = (wv * 2 + c) * 16 + arow;
        float bb = b1[col];
        #pragma unroll
        for (int rt = 0; rt < 4; rt++)
            #pragma unroll
            for (int rg = 0; rg < 4; rg++) {
                int row = rt * 16 + kg * 4 + rg;
                float v = fmaxf(acc1[c][rt][rg] + bb, 0.f);
                *(_Float16*)(rawb + SWA(row, 384 + col * 2)) = (_Float16)v;
            }
    }
    __syncthreads();

    f32x4 acc2[4];
    #pragma unroll
    for (int rt = 0; rt < 4; rt++) acc2[rt] = z4();
    for (int ks = 0; ks < 8; ks++) {
        f16x8 b = *(const f16x8*)(W2h + (((size_t)wv * 8 + ks) * 64 + lane) * 8);
        #pragma unroll
        for (int rt = 0; rt < 4; rt++) {
            f16x8 a = *(const f16x8*)(rawb + SWA(rt * 16 + arow, 384 + ks * 64 + kg * 16));
            acc2[rt] = MFMA16(a, b, acc2[rt]);
        }
    }
    __syncthreads();

    {
        int col = wv * 16 + arow;
        float bb = b2[col];
        #pragma unroll
        for (int rt = 0; rt < 4; rt++)
            #pragma unroll
            for (int rg = 0; rg < 4; rg++) {
                int row = rt * 16 + kg * 4 + rg;
                *(_Float16*)(rawb + SWA(row, 384 + col * 2)) =
                    (_Float16)(acc2[rt][rg] + bb);
            }
    }
    __syncthreads();

    f32x4 aR[4], aZ[4], aNi[4], aNh[4];
    #pragma unroll
    for (int rt = 0; rt < 4; rt++) { aR[rt] = z4(); aZ[rt] = z4(); aNi[rt] = z4(); aNh[rt] = z4(); }
    for (int ks = 0; ks < 4; ks++) {
        f16x8 bi_ = ldw4(Wih, wv, ks, lane);
        f16x8 bh_ = ldw4(Whh, wv, ks, lane);
        #pragma unroll
        for (int rt = 0; rt < 4; rt++) {
            f16x8 m = *(const f16x8*)(rawb + SWA(rt * 16 + arow, 384 + ks * 64 + kg * 16));
            f16x8 hh = *(const f16x8*)(rawb + SWA(rt * 16 + arow, ks * 64 + kg * 16));
            aR[rt] = MFMA16(m, bi_, aR[rt]);
            aR[rt] = MFMA16(hh, bh_, aR[rt]);
        }
    }
    for (int ks = 0; ks < 4; ks++) {
        f16x8 bi_ = ldw4(Wih, 8 + wv, ks, lane);
        f16x8 bh_ = ldw4(Whh, 8 + wv, ks, lane);
        #pragma unroll
        for (int rt = 0; rt < 4; rt++) {
            f16x8 m = *(const f16x8*)(rawb + SWA(rt * 16 + arow, 384 + ks * 64 + kg * 16));
            f16x8 hh = *(const f16x8*)(rawb + SWA(rt * 16 + arow, ks * 64 + kg * 16));
            aZ[rt] = MFMA16(m, bi_, aZ[rt]);
            aZ[rt] = MFMA16(hh, bh_, aZ[rt]);
        }
    }
    for (int ks = 0; ks < 4; ks++) {
        f16x8 bi_ = ldw4(Wih, 16 + wv, ks, lane);
        f16x8 bh_ = ldw4(Whh, 16 + wv, ks, lane);
        #pragma unroll
        for (int rt = 0; rt < 4; rt++) {
            f16x8 m = *(const f16x8*)(rawb + SWA(rt * 16 + arow, 384 + ks * 64 + kg * 16));
            f16x8 hh = *(const f16x8*)(rawb + SWA(rt * 16 + arow, ks * 64 + kg * 16));
            aNi[rt] = MFMA16(m, bi_, aNi[rt]);
            aNh[rt] = MFMA16(hh, bh_, aNh[rt]);
        }
    }

    {
        int col = wv * 16 + arow;
        float bir = bi[col],        bhr = bh[col];
        float biz = bi[128 + col],  bhz = bh[128 + col];
        float bin_ = bi[256 + col], bhn_ = bh[256 + col];
        #pragma unroll
        for (int rt = 0; rt < 4; rt++)
            #pragma unroll
            for (int rg = 0; rg < 4; rg++) {
                int row = rt * 16 + kg * 4 + rg;
                int rr = r0 + row;
                if (rr < cnt) {
                    float r_ = fsigm(aR[rt][rg] + bir + bhr);
                    float zg = fsigm(aZ[rt][rg] + biz + bhz);
                    float ng = ftanh(aNi[rt][rg] + bin_ + r_ * (aNh[rt][rg] + bhn_));
                    float om = (float)*(const _Float16*)(rawb + SWA(row, col * 2));
                    new_mem[(size_t)rr * 128 + col] = (_Float16)((1.f - zg) * ng + zg * om);
                }
            }
    }
}

// k_feat: feat[n] = (updated ? new_mem[inv[n]] : memory[n]) + node_feats[n], f16
__global__ __launch_bounds__(256)
void k_feat(const int* __restrict__ inv, const _Float16* __restrict__ new_mem,
            const float* __restrict__ memory, const float* __restrict__ node_feats,
            _Float16* __restrict__ feat)
{
    int idx = blockIdx.x * 256 + threadIdx.x;
    if (idx >= NN * 16) return;
    int n = idx >> 4, g = idx & 15;
    int c = g * 8;
    int iv = inv[n];
    float4 n0 = *(const float4*)(node_feats + (size_t)n * 128 + c);
    float4 n1 = *(const float4*)(node_feats + (size_t)n * 128 + c + 4);
    f16x8 o;
    if (iv >= 0) {
        f16x8 mv = *(const f16x8*)(new_mem + (size_t)iv * 128 + c);
        o[0] = (_Float16)((float)mv[0] + n0.x); o[1] = (_Float16)((float)mv[1] + n0.y);
        o[2] = (_Float16)((float)mv[2] + n0.z); o[3] = (_Float16)((float)mv[3] + n0.w);
        o[4] = (_Float16)((float)mv[4] + n1.x); o[5] = (_Float16)((float)mv[5] + n1.y);
        o[6] = (_Float16)((float)mv[6] + n1.z); o[7] = (_Float16)((float)mv[7] + n1.w);
    } else {
        float4 m0 = *(const float4*)(memory + (size_t)n * 128 + c);
        float4 m1 = *(const float4*)(memory + (size_t)n * 128 + c + 4);
        o[0] = (_Float16)(m0.x + n0.x); o[1] = (_Float16)(m0.y + n0.y);
        o[2] = (_Float16)(m0.z + n0.z); o[3] = (_Float16)(m0.w + n0.w);
        o[4] = (_Float16)(m1.x + n1.x); o[5] = (_Float16)(m1.y + n1.y);
        o[6] = (_Float16)(m1.z + n1.z); o[7] = (_Float16)(m1.w + n1.w);
    }
    *(f16x8*)(feat + (size_t)n * 128 + c) = o;
}

// ---------------- Stage 2 ----------------
__global__ void k2a(const int* __restrict__ src_nodes, const int* __restrict__ dst_nodes,
                    const int* __restrict__ neg_nodes, const _Float16* __restrict__ feat,
                    const float* __restrict__ time_b,
                    _Float16* __restrict__ q_in, _Float16* __restrict__ acat)
{
    __shared__ int snode[32];
    int tid = threadIdx.x;
    int r0 = blockIdx.x * 32;
    if (tid < 32) {
        int q = r0 + tid;
        snode[tid] = (q < BB) ? src_nodes[q] : (q < 2 * BB) ? dst_nodes[q - BB] : neg_nodes[q - 2 * BB];
    }
    __syncthreads();
    #pragma unroll
    for (int it = 0; it < 4; it++) {
        int gi = tid + it * 256;
        int r = gi >> 5, ch = gi & 31;
        int c = ch * 4;
        int node = snode[r];
        f16x4 sf = *(const f16x4*)(feat + (size_t)node * 128 + c);
        size_t q = (size_t)(r0 + r);
        *(f16x4*)(q_in + q * 256 + c) = sf;
        *(f16x4*)(acat + q * 384 + 256 + c) = sf;
        float4 tb = *(const float4*)(time_b + c);
        f16x4 te;
        te[0] = (_Float16)fast_cos(tb.x); te[1] = (_Float16)fast_cos(tb.y);
        te[2] = (_Float16)fast_cos(tb.z); te[3] = (_Float16)fast_cos(tb.w);
        *(f16x4*)(q_in + q * 256 + 128 + c) = te;
    }
}

// k2b: fused q-projection + qk-fold. stage q_in tile -> q = q_in@Wq^T+bq (LDS)
// -> qk_h = q_h @ Wkt_h (per head) -> qk_ws. No q intermediate in HBM.
__global__ __launch_bounds__(512, 2)
void k2b(const _Float16* __restrict__ q_in, const _Float16* __restrict__ Wqh,
         const float* __restrict__ bq, const _Float16* __restrict__ Wkth,
         _Float16* __restrict__ qk_ws)
{
    __shared__ char lds[32 * 1024];    // [0,16K): q_in tile; [16K,32K): q tile
    int tid = threadIdx.x;
    int r0 = blockIdx.x * 32;

    // stage q_in [32][256] f16, rows of 512B, swizzled
    #pragma unroll
    for (int t = 0; t < 2; t++) {
        int gi = tid + t * 512;
        int r = gi >> 5, g = gi & 31;
        f16x8 v = *(const f16x8*)(q_in + (size_t)(r0 + r) * 256 + g * 8);
        *(f16x8*)(&lds[r * 512 + ((g * 16) ^ ((r & 7) << 4))]) = v;
    }
    __syncthreads();

    int wv = tid >> 6, lane = tid & 63;
    int arow = lane & 15, kg = lane >> 4;

    // GEMM1: q = q_in @ Wq^T + bq; K=256 (KS=8), 16 cgrps / 8 waves -> NFRAG 2
    f32x4 acc[2][2];
    #pragma unroll
    for (int c = 0; c < 2; c++) { acc[c][0] = z4(); acc[c][1] = z4(); }
    for (int ks = 0; ks < 8; ks++) {
        f16x8 a0 = *(const f16x8*)(&lds[arow * 512 + ((ks * 64 + kg * 16) ^ ((arow & 7) << 4))]);
        f16x8 a1 = *(const f16x8*)(&lds[(16 + arow) * 512 + ((ks * 64 + kg * 16) ^ ((arow & 7) << 4))]);
        #pragma unroll
        for (int c = 0; c < 2; c++) {
            f16x8 b = *(const f16x8*)(Wqh + (((size_t)(wv * 2 + c) * 8 + ks) * 64 + lane) * 8);
            acc[c][0] = MFMA16(a0, b, acc[c][0]);
            acc[c][1] = MFMA16(a1, b, acc[c][1]);
        }
    }
    // write q into LDS region B (rows of 512B, swizzled)
    #pragma unroll
    for (int c = 0; c < 2; c++) {
        int col = (wv * 2 + c) * 16 + arow;
        float bb = bq[col];
        #pragma unroll
        for (int rt = 0; rt < 2; rt++)
            #pragma unroll
            for (int rg = 0; rg < 4; rg++) {
                int row = rt * 16 + kg * 4 + rg;
                *(_Float16*)(&lds[16384 + row * 512 + ((col * 2) ^ ((row & 7) << 4))]) =
                    (_Float16)(acc[c][rt][rg] + bb);
            }
    }
    __syncthreads();

    // GEMM2: qk_h = q_h @ Wkt_h; per-head K=128 (KS=4), 48 cgrps / 8 waves -> 6
    // waves 0-3: head 0, waves 4-7: head 1 (wave-uniform)
    int h = wv >> 2;
    f32x4 acc2[6][2];
    #pragma unroll
    for (int c = 0; c < 6; c++) { acc2[c][0] = z4(); acc2[c][1] = z4(); }
    for (int ks = 0; ks < 4; ks++) {
        f16x8 a0 = *(const f16x8*)(&lds[16384 + arow * 512 +
                    ((h * 256 + ks * 64 + kg * 16) ^ ((arow & 7) << 4))]);
        f16x8 a1 = *(const f16x8*)(&lds[16384 + (16 + arow) * 512 +
                    ((h * 256 + ks * 64 + kg * 16) ^ ((arow & 7) << 4))]);
        #pragma unroll
        for (int c = 0; c < 6; c++) {
            int cgh = (wv & 3) * 6 + c;    // within-head cgrp [0,24)
            f16x8 b = *(const f16x8*)(Wkth + (size_t)h * 49152 +
                       (((size_t)cgh * 4 + ks) * 64 + lane) * 8);
            acc2[c][0] = MFMA16(a0, b, acc2[c][0]);
            acc2[c][1] = MFMA16(a1, b, acc2[c][1]);
        }
    }
    #pragma unroll
    for (int c = 0; c < 6; c++) {
        int cgh = (wv & 3) * 6 + c;
        int col = h * 384 + cgh * 16 + arow;
        #pragma unroll
        for (int rt = 0; rt < 2; rt++)
            #pragma unroll
            for (int rg = 0; rg < 4; rg++) {
                int row = rt * 16 + kg * 4 + rg;
                qk_ws[(size_t)(r0 + row) * 768 + col] = (_Float16)acc2[c][rt][rg];
            }
    }
}

// generic 32-row-tile MFMA GEMM, fragment-ordered B.
template<int KD, int NFRAG, bool RELU>
__global__ __launch_bounds__(256, 4)
void k_gemm(const _Float16* __restrict__ A, int lda, int a_ys,
            const _Float16* __restrict__ B, int b_ys,
            const float* __restrict__ bias, int bias_ys,
            _Float16* __restrict__ C, int ldc, int c_ys,
            float* __restrict__ C32,
            const int* __restrict__ rowmask)
{
    constexpr int ROWB = KD * 2;
    __shared__ char As[32 * ROWB];
    int tid = threadIdx.x;
    int r0 = blockIdx.x * 32;
    int aoff = blockIdx.y * a_ys;
    const _Float16* Bp = B + (size_t)blockIdx.y * b_ys;
    int coff = blockIdx.y * c_ys;

    #pragma unroll
    for (int t = 0; t < (32 * KD / 8) / 256; t++) {
        int gi = tid + t * 256;
        int r = gi / (KD / 8), g = gi % (KD / 8);
        f16x8 v = *(const f16x8*)(A + (size_t)(r0 + r) * lda + aoff + g * 8);
        *(f16x8*)(&As[r * ROWB + ((g * 16) ^ ((r & 7) << 4))]) = v;
    }
    __syncthreads();

    int wv = tid >> 6, lane = tid & 63;
    int arow = lane & 15, kg = lane >> 4;
    f32x4 acc[NFRAG][2];
    #pragma unroll
    for (int c = 0; c < NFRAG; c++) { acc[c][0] = z4(); acc[c][1] = z4(); }

    #pragma unroll
    for (int ks = 0; ks < KD / 32; ks++) {
        f16x8 a0 = *(const f16x8*)(&As[arow * ROWB + ((ks * 64 + kg * 16) ^ ((arow & 7) << 4))]);
        f16x8 a1 = *(const f16x8*)(&As[(16 + arow) * ROWB + ((ks * 64 + kg * 16) ^ ((arow & 7) << 4))]);
        #pragma unroll
        for (int c = 0; c < NFRAG; c++) {
            f16x8 b = *(const f16x8*)(Bp +
                (((size_t)(wv * NFRAG + c) * (KD / 32) + ks) * 64 + lane) * 8);
            acc[c][0] = MFMA16(a0, b, acc[c][0]);
            acc[c][1] = MFMA16(a1, b, acc[c][1]);
        }
    }

    #pragma unroll
    for (int c = 0; c < NFRAG; c++) {
        int cg = (wv * NFRAG + c) * 16 + arow;
        float bb = bias ? bias[blockIdx.y * bias_ys + cg] : 0.f;
        #pragma unroll
        for (int rt = 0; rt < 2; rt++)
            #pragma unroll
            for (int rg = 0; rg < 4; rg++) {
                int grow = r0 + rt * 16 + kg * 4 + rg;
                float v = acc[c][rt][rg] + bb;
                if (RELU) v = fmaxf(v, 0.f);
                if (rowmask && rowmask[grow]) v = 0.f;
                if (C)   C[(size_t)grow * ldc + coff + cg] = (_Float16)v;
                if (C32) C32[(size_t)grow * ldc + coff + cg] = v;
            }
    }
}

// k2d: attention core. 1 query/wave, head per half-wave, no LDS, depth-1
// pipelined gathers. cb (=q.bk) dropped: softmax is shift-invariant, the
// per-(query,head)-constant q.bk cancels exactly in exp(s - m).
__global__ __launch_bounds__(256)
void k2d(const int* __restrict__ neighbors, const int* __restrict__ nb_eidx,
         const int* __restrict__ nb_et, const int* __restrict__ edge_times,
         const _Float16* __restrict__ feat,
         const float* __restrict__ edge_feats, const float* __restrict__ time_w,
         const float* __restrict__ time_b,
         _Float16* __restrict__ qk_wsum, int* __restrict__ allm)
{
    int tid = threadIdx.x;
    int qi = blockIdx.x * 4 + (tid >> 6);
    int lane = tid & 63;
    int h = lane >> 5, l32 = lane & 31;
    int c0 = l32 * 4;

    float4 tw = *(const float4*)(time_w + c0);
    float4 tb = *(const float4*)(time_b + c0);

    const _Float16* qkp = qk_wsum + (size_t)qi * 768 + h * 384;
    f16x4 t0 = *(const f16x4*)(qkp + c0);
    f16x4 t1 = *(const f16x4*)(qkp + 128 + c0);
    f16x4 t2 = *(const f16x4*)(qkp + 256 + c0);
    float qk0[4], qk1[4], qk2[4];
    #pragma unroll
    for (int t = 0; t < 4; t++) { qk0[t] = (float)t0[t]; qk1[t] = (float)t1[t]; qk2[t] = (float)t2[t]; }

    float ts = (float)edge_times[qi & (BB - 1)];
    float m_run = -3.0e38f, l_run = 0.f;
    float w0[4] = {0,0,0,0}, w1[4] = {0,0,0,0}, w2[4] = {0,0,0,0};
    int anyv = 0;
    const float inv_sqrt = 0.08838834764831845f;

    int base = qi * KK;
    int nb_c = neighbors[base];
    int ei_c = nb_eidx[base];
    int et_c = nb_et[base];
    f16x4 fv;
    float4 ef;
    {
        fv = *(const f16x4*)(feat + (size_t)nb_c * 128 + c0);
        ef = *(const float4*)(edge_feats + (size_t)ei_c * 128 + c0);
    }

    for (int j = 0; j < KK; j++) {
        int nb_n = 0, ei_n = 0, et_n = 0;
        f16x4 fv_n = {0,0,0,0};
        float4 ef_n = {0,0,0,0};
        if (j + 1 < KK) {
            nb_n = neighbors[base + j + 1];
            ei_n = nb_eidx[base + j + 1];
            et_n = nb_et[base + j + 1];
            fv_n = *(const f16x4*)(feat + (size_t)nb_n * 128 + c0);
            ef_n = *(const float4*)(edge_feats + (size_t)ei_n * 128 + c0);
        }

        float dtf = ts - (float)et_c;
        anyv |= (nb_c != 0);
        float k0[4] = { (float)fv[0], (float)fv[1], (float)fv[2], (float)fv[3] };
        float k1[4] = { tenc(dtf, tw.x, tb.x), tenc(dtf, tw.y, tb.y),
                        tenc(dtf, tw.z, tb.z), tenc(dtf, tw.w, tb.w) };
        float k2[4] = { ef.x, ef.y, ef.z, ef.w };

        float sp = 0.f;
        #pragma unroll
        for (int t = 0; t < 4; t++)
            sp += qk0[t] * k0[t] + qk1[t] * k1[t] + qk2[t] * k2[t];
        sp += __shfl_xor(sp, 1, 32);
        sp += __shfl_xor(sp, 2, 32);
        sp += __shfl_xor(sp, 4, 32);
        sp += __shfl_xor(sp, 8, 32);
        sp += __shfl_xor(sp, 16, 32);

        float s = sp * inv_sqrt;
        if (nb_c == 0) s = -1e9f;
        float m_new = fmaxf(m_run, s);
        float sc = __expf(m_run - m_new);
        float p = __expf(s - m_new);
        l_run = l_run * sc + p;
        #pragma unroll
        for (int t = 0; t < 4; t++) {
            w0[t] = w0[t] * sc + p * k0[t];
            w1[t] = w1[t] * sc + p * k1[t];
            w2[t] = w2[t] * sc + p * k2[t];
        }
        m_run = m_new;

        nb_c = nb_n; ei_c = ei_n; et_c = et_n;
        fv = fv_n; ef = ef_n;
    }

    float linv = __builtin_amdgcn_rcpf(l_run);
    _Float16* wp = qk_wsum + (size_t)qi * 768 + h * 384;
    f16x4 o0, o1, o2;
    #pragma unroll
    for (int t = 0; t < 4; t++) {
        o0[t] = (_Float16)(w0[t] * linv);
        o1[t] = (_Float16)(w1[t] * linv);
        o2[t] = (_Float16)(w2[t] * linv);
    }
    *(f16x4*)(wp + c0) = o0;
    *(f16x4*)(wp + 128 + c0) = o1;
    *(f16x4*)(wp + 256 + c0) = o2;
    if (lane == 0) allm[qi] = anyv ? 0 : 1;
}

extern "C" void kernel_launch(void* const* d_in, const int* in_sizes, int n_in,
                              void* d_out, int out_size, void* d_ws, size_t ws_size,
                              hipStream_t stream) {
    (void)in_sizes; (void)n_in; (void)out_size; (void)ws_size;
    const int* src_nodes  = (const int*)d_in[0];
    const int* dst_nodes  = (const int*)d_in[1];
    const int* neg_nodes  = (const int*)d_in[2];
    const int* edge_times = (const int*)d_in[3];
    const int* neighbors  = (const int*)d_in[4];
    const int* nb_eidx    = (const int*)d_in[5];
    const int* nb_et      = (const int*)d_in[6];
    const int* msg_src    = (const int*)d_in[7];
    const int* msg_dst    = (const int*)d_in[8];
    const int* msg_eidx   = (const int*)d_in[9];
    const int* msg_t      = (const int*)d_in[10];
    const int* last_update= (const int*)d_in[11];
    const float* node_feats = (const float*)d_in[12];
    const float* edge_feats = (const float*)d_in[13];
    const float* memory     = (const float*)d_in[14];
    const float* time_w = (const float*)d_in[15];
    const float* time_b = (const float*)d_in[16];
    const float* W1 = (const float*)d_in[17];
    const float* b1 = (const float*)d_in[18];
    const float* W2 = (const float*)d_in[19];
    const float* b2 = (const float*)d_in[20];
    const float* gWi = (const float*)d_in[21];
    const float* gWh = (const float*)d_in[22];
    const float* gbi = (const float*)d_in[23];
    const float* gbh = (const float*)d_in[24];
    const float* Wq = (const float*)d_in[25];
    const float* bq = (const float*)d_in[26];
    const float* Wk = (const float*)d_in[27];
    const float* bk = (const float*)d_in[28];
    const float* Wv = (const float*)d_in[29];
    const float* bv = (const float*)d_in[30];
    const float* Wo = (const float*)d_in[31];
    const float* bo = (const float*)d_in[32];
    const float* mW1 = (const float*)d_in[33];
    const float* mb1 = (const float*)d_in[34];
    const float* mW2 = (const float*)d_in[35];
    const float* mb2 = (const float*)d_in[36];
    float* out = (float*)d_out;
    (void)bk;

    char* w = (char*)d_ws;
    int* lastpos = (int*)w;
    int* inv  = lastpos + NN;
    int* comp = inv + NN;
    int* count = comp + NN;
    int* bcnt = count + 1;
    int* boff = bcnt + NBLK;
    size_t off = ((size_t)(3 * NN + 1 + 2 * NBLK) * 4 + 255) & ~(size_t)255;
    _Float16* new_mem = (_Float16*)(w + off);         // MM*128 f16
    size_t foff = off + (size_t)MM * 128 * 2;
    _Float16* feat = (_Float16*)(w + foff);           // NN*128 f16
    size_t woff = foff + (size_t)NN * 128 * 2;

    _Float16* Hpool = (_Float16*)(w + woff);          // 655360 f16, fragment order
    _Float16* W1h  = Hpool;
    _Float16* W2h  = Hpool + 131072;
    _Float16* Wih  = Hpool + 163840;
    _Float16* Whh  = Hpool + 212992;
    _Float16* Wqh  = Hpool + 262144;
    _Float16* Wvh  = Hpool + 327680;
    _Float16* Woh  = Hpool + 425984;
    _Float16* mW1h = Hpool + 491520;
    _Float16* mW2h = Hpool + 540672;
    _Float16* Wkth = Hpool + 557056;
    size_t boff2 = woff + (size_t)655360 * 2;

    _Float16* qin_ctx = (_Float16*)(w + boff2);
    _Float16* q_hm    = qin_ctx + (size_t)Q3 * 256;
    _Float16* qk_ws   = q_hm + (size_t)Q3 * 256;
    _Float16* acat    = qk_ws + (size_t)Q3 * 768;
    int* allm         = (int*)(acat + (size_t)Q3 * 384);

    k_init<<<dim3(NBLK), dim3(256), 0, stream>>>(lastpos, inv);
    k_scatter<<<dim3((MM + 255) / 256), dim3(256), 0, stream>>>(msg_src, lastpos);
    k_count<<<dim3(NBLK), dim3(256), 0, stream>>>(lastpos, bcnt);
    k_scan<<<dim3(1), dim3(256), 0, stream>>>(bcnt, boff, count);
    k_fill<<<dim3(NBLK), dim3(256), 0, stream>>>(lastpos, boff, comp, inv);
    k_cvtw<<<dim3(320), dim3(256), 0, stream>>>(W1, W2, gWi, gWh, Wq, Wv, Wo, mW1, mW2, Wk, Hpool);
    k_stage1<<<dim3((MM + 63) / 64), dim3(512), 0, stream>>>(
        comp, count, lastpos, msg_dst, msg_eidx, msg_t, last_update,
        memory, edge_feats, time_w, time_b,
        W1h, b1, W2h, b2, Wih, Whh, gbi, gbh, new_mem);
    k_feat<<<dim3(NN * 16 / 256), dim3(256), 0, stream>>>(
        inv, new_mem, memory, node_feats, feat);

    k2a<<<dim3(Q3 / 32), dim3(256), 0, stream>>>(
        src_nodes, dst_nodes, neg_nodes, feat, time_b, qin_ctx, acat);
    // fused: q = q_in@Wq^T+bq -> qk = q_h@Wkt_h (q never leaves LDS)
    k2b<<<dim3(Q3 / 32), dim3(512), 0, stream>>>(
        qin_ctx, Wqh, bq, Wkth, qk_ws);
    k2d<<<dim3(Q3 / 4), dim3(256), 0, stream>>>(
        neighbors, nb_eidx, nb_et, edge_times, feat,
        edge_feats, time_w, time_b, qk_ws, allm);
    k_gemm<384, 2, false><<<dim3(Q3 / 32, 2), dim3(256), 0, stream>>>(
        qk_ws, 768, 384, Wvh, 128 * 384, bv, 128, qin_ctx, 256, 128, nullptr, nullptr);
    k_gemm<256, 4, false><<<dim3(Q3 / 32, 1), dim3(256), 0, stream>>>(
        qin_ctx, 256, 0, Woh, 0, bo, 0, acat, 384, 0, nullptr, allm);
    k_gemm<384, 2, true><<<dim3(Q3 / 32, 1), dim3(256), 0, stream>>>(
        acat, 384, 0, mW1h, 0, mb1, 0, q_hm, 128, 0, nullptr, nullptr);
    k_gemm<128, 2, false><<<dim3(Q3 / 32, 1), dim3(256), 0, stream>>>(
        q_hm, 128, 0, mW2h, 0, mb2, 0, nullptr, 128, 0, out, nullptr);
}

// Round 12
// 284.447 us; speedup vs baseline: 1.3885x; 1.0832x over previous
//
#include <hip/hip_runtime.h>
#include <math.h>

#define NN 200000
#define EEDGE 500000
#define BB 4096
#define KK 20
#define MM 100000
#define Q3 (3*BB)
#define NBLK ((NN + 255) / 256)

typedef _Float16 __attribute__((ext_vector_type(8))) f16x8;
typedef _Float16 __attribute__((ext_vector_type(4))) f16x4;
typedef float __attribute__((ext_vector_type(4))) f32x4;

#define MFMA16(a,b,c) __builtin_amdgcn_mfma_f32_16x16x32_f16(a,b,c,0,0,0)

// cos(a) for |a| up to ~1e7: f64 range-reduction to revolutions + v_cos_f32.
__device__ __forceinline__ float fast_cos(float a) {
    double ad = (double)a * 0.15915494309189535;   // 1/(2*pi)
    double fr = ad - floor(ad);                    // [0,1) revolutions
    return __builtin_amdgcn_cosf((float)fr);       // cos(2*pi*x)
}

// time encoding matching numpy's f32 arg rounding — NO fma contraction.
__device__ __forceinline__ float tenc(float dt, float w, float b) {
    float p = __fmul_rn(dt, w);
    float a = __fadd_rn(p, b);
    return fast_cos(a);
}

__device__ __forceinline__ float fsigm(float x) {
    return __builtin_amdgcn_rcpf(1.f + __expf(-x));
}
__device__ __forceinline__ float ftanh(float x) {
    return 1.f - 2.f * __builtin_amdgcn_rcpf(1.f + __expf(2.f * x));
}

__device__ __forceinline__ f32x4 z4() {
    f32x4 v; v[0] = 0.f; v[1] = 0.f; v[2] = 0.f; v[3] = 0.f; return v;
}

__global__ void k_init(int* lastpos, int* inv, char* mask) {
    int i = blockIdx.x * 256 + threadIdx.x;
    if (i < NN) { lastpos[i] = -1; inv[i] = -1; mask[i] = 0; }
}

__global__ void k_scatter(const int* __restrict__ msg_src, int* __restrict__ lastpos) {
    int i = blockIdx.x * 256 + threadIdx.x;
    if (i < MM) atomicMax(&lastpos[msg_src[i]], i);
}

// mark nodes whose feat row is actually read (query nodes + all neighbors)
__global__ void k_mark(const int* __restrict__ src_nodes, const int* __restrict__ dst_nodes,
                       const int* __restrict__ neg_nodes, const int* __restrict__ neighbors,
                       char* __restrict__ mask) {
    int i = blockIdx.x * 256 + threadIdx.x;
    if (i < Q3) {
        int node = (i < BB) ? src_nodes[i] : (i < 2 * BB) ? dst_nodes[i - BB] : neg_nodes[i - 2 * BB];
        mask[node] = 1;
    } else {
        int e = i - Q3;
        if (e < Q3 * KK) mask[neighbors[e]] = 1;
    }
}

// ordered (sorted-by-node) compaction: count -> scan -> fill (R9-proven)
__global__ void k_count(const int* __restrict__ lastpos, int* __restrict__ bcnt) {
    int n = blockIdx.x * 256 + threadIdx.x;
    int flag = (n < NN && lastpos[n] >= 0) ? 1 : 0;
    unsigned long long m = __ballot(flag != 0);
    __shared__ int wc[4];
    int wave = threadIdx.x >> 6, lane = threadIdx.x & 63;
    if (lane == 0) wc[wave] = __popcll(m);
    __syncthreads();
    if (threadIdx.x == 0) bcnt[blockIdx.x] = wc[0] + wc[1] + wc[2] + wc[3];
}

__global__ void k_scan(const int* __restrict__ bcnt, int* __restrict__ boff,
                       int* __restrict__ count) {
    __shared__ int s[NBLK];
    int t = threadIdx.x;
    for (int i = t; i < NBLK; i += 256) s[i] = bcnt[i];
    __syncthreads();
    if (t == 0) {
        int acc = 0;
        for (int i = 0; i < NBLK; i++) { int v = s[i]; s[i] = acc; acc += v; }
        *count = acc;
    }
    __syncthreads();
    for (int i = t; i < NBLK; i += 256) boff[i] = s[i];
}

__global__ void k_fill(const int* __restrict__ lastpos, const int* __restrict__ boff,
                       int* __restrict__ comp, int* __restrict__ inv) {
    int n = blockIdx.x * 256 + threadIdx.x;
    int flag = (n < NN && lastpos[n] >= 0) ? 1 : 0;
    unsigned long long m = __ballot(flag != 0);
    __shared__ int wc[4];
    int wave = threadIdx.x >> 6, lane = threadIdx.x & 63;
    if (lane == 0) wc[wave] = __popcll(m);
    __syncthreads();
    int base = boff[blockIdx.x];
    for (int i = 0; i < wave; i++) base += wc[i];
    int rank = __popcll(m & ((1ull << lane) - 1));
    if (flag) {
        int pos = base + rank;
        comp[pos] = n;
        inv[n] = pos;
    }
}

// k_prep: bq2[c] = bq[c] + sum_d Wq[c][128+d] * cos(time_b[d])
// (time-encoding of t=0 is constant across queries -> fold into q bias)
__global__ void k_prep(const float* __restrict__ Wq, const float* __restrict__ bq,
                       const float* __restrict__ time_b, float* __restrict__ bq2) {
    __shared__ float cte[128];
    int t = threadIdx.x;
    if (t < 128) cte[t] = fast_cos(time_b[t]);
    __syncthreads();
    float acc = bq[t];
    #pragma unroll 4
    for (int d = 0; d < 128; d++)
        acc += Wq[(size_t)t * 256 + 128 + d] * cte[d];
    bq2[t] = acc;
}

// f32 -> f16 weight conversion into MFMA FRAGMENT ORDER.
// elem offset = matbase + ((cgrp*KS + ks)*64 + lane)*8 + e
__global__ void k_cvtw(const float* __restrict__ W1, const float* __restrict__ W2,
                       const float* __restrict__ Wi, const float* __restrict__ Wh,
                       const float* __restrict__ Wq, const float* __restrict__ Wv,
                       const float* __restrict__ Wo, const float* __restrict__ mW1,
                       const float* __restrict__ mW2, const float* __restrict__ Wk,
                       _Float16* __restrict__ dst) {
    int f = blockIdx.x * 256 + threadIdx.x;   // fragment id, 77824 total
    if (f >= 77824) return;
    const float* src; int dstoff, K, ldb, lf, tr = -1;
    if      (f < 16384) { src = W1;  dstoff = 0;      K = 512; ldb = 512; lf = f; }
    else if (f < 20480) { src = W2;  dstoff = 131072; K = 256; ldb = 256; lf = f - 16384; }
    else if (f < 26624) { src = Wi;  dstoff = 163840; K = 128; ldb = 128; lf = f - 20480; }
    else if (f < 32768) { src = Wh;  dstoff = 212992; K = 128; ldb = 128; lf = f - 26624; }
    else if (f < 36864) { src = Wq;  dstoff = 262144; K = 128; ldb = 256; lf = f - 32768; } // Wq left half
    else if (f < 43008) { src = Wv;  dstoff = 294912; K = 384; ldb = 384; lf = f - 36864; }
    else if (f < 49152) { src = Wv + 128 * 384; dstoff = 344064; K = 384; ldb = 384; lf = f - 43008; }
    else if (f < 57344) { src = Wo;  dstoff = 393216; K = 256; ldb = 256; lf = f - 49152; }
    else if (f < 63488) { src = mW1; dstoff = 458752; K = 384; ldb = 384; lf = f - 57344; }
    else if (f < 65536) { src = mW2; dstoff = 507904; K = 128; ldb = 128; lf = f - 63488; }
    else if (f < 71680) { src = Wk;  dstoff = 524288; K = 128; ldb = 0; lf = f - 65536; tr = 0; }
    else                { src = Wk;  dstoff = 573440; K = 128; ldb = 0; lf = f - 71680; tr = 1; }
    int KS = K >> 5;
    int cgrp = lf / (KS * 64);
    int rem  = lf - cgrp * (KS * 64);
    int ks = rem >> 6, lane = rem & 63;
    int kg = lane >> 4, arow = lane & 15;
    int col = cgrp * 16 + arow;
    int k0 = ks * 32 + kg * 8;
    f16x8 h;
    if (tr < 0) {
        const float* p = src + (size_t)col * ldb + k0;
        float4 a = *(const float4*)p;
        float4 b = *(const float4*)(p + 4);
        h[0] = (_Float16)a.x; h[1] = (_Float16)a.y; h[2] = (_Float16)a.z; h[3] = (_Float16)a.w;
        h[4] = (_Float16)b.x; h[5] = (_Float16)b.y; h[6] = (_Float16)b.z; h[7] = (_Float16)b.w;
    } else {
        #pragma unroll
        for (int e = 0; e < 8; e++)
            h[e] = (_Float16)Wk[(size_t)(tr * 128 + k0 + e) * 384 + col];
    }
    *(f16x8*)(dst + dstoff + (size_t)lf * 8) = h;
}

// ---------------- Stage 1: 64 rows/block, 512 threads / 8 waves (R10-exact) ----------------
__device__ __forceinline__ int SWA(int r, int byteofs) {
    return r * 1024 + (byteofs ^ ((r & 7) << 4));
}

__device__ __forceinline__ f16x8 ldw4(const _Float16* W, int cg, int ks, int lane) {
    return *(const f16x8*)(W + (((size_t)cg * 4 + ks) * 64 + lane) * 8);
}

__global__ __launch_bounds__(512, 2)
void k_stage1(const int* __restrict__ comp, const int* __restrict__ count,
              const int* __restrict__ lastpos,
              const int* __restrict__ msg_dst, const int* __restrict__ msg_eidx,
              const int* __restrict__ msg_t, const int* __restrict__ last_update,
              const float* __restrict__ memory, const float* __restrict__ edge_feats,
              const float* __restrict__ time_w, const float* __restrict__ time_b,
              const _Float16* __restrict__ W1h, const float* __restrict__ b1,
              const _Float16* __restrict__ W2h, const float* __restrict__ b2,
              const _Float16* __restrict__ Wih, const _Float16* __restrict__ Whh,
              const float* __restrict__ bi, const float* __restrict__ bh,
              _Float16* __restrict__ new_mem)
{
    __shared__ char rawb[64 * 1024];
    __shared__ int sn[64], sd[64], se[64];
    __shared__ float sdt[64];

    int cnt = *count;
    int r0 = blockIdx.x * 64;
    if (r0 >= cnt) return;
    int tid = threadIdx.x;

    if (tid < 64) {
        int rr = r0 + tid;
        int j = (rr < cnt) ? rr : r0;
        int n = comp[j];
        int idx = lastpos[n];
        sn[tid] = n;
        sd[tid] = msg_dst[idx];
        se[tid] = msg_eidx[idx];
        sdt[tid] = (float)(msg_t[idx] - last_update[n]);
    }
    __syncthreads();

    #pragma unroll
    for (int it = 0; it < 6; it++) {
        int gi = tid + it * 512;
        int r = gi / 48, g = gi - r * 48;
        const float* src;
        if (g < 16)      src = memory + (size_t)sn[r] * 128 + g * 8;
        else if (g < 32) src = memory + (size_t)sd[r] * 128 + (g - 16) * 8;
        else             src = edge_feats + (size_t)se[r] * 128 + (g - 32) * 8;
        float4 a = *(const float4*)src;
        float4 b = *(const float4*)(src + 4);
        f16x8 h;
        h[0] = (_Float16)a.x; h[1] = (_Float16)a.y; h[2] = (_Float16)a.z; h[3] = (_Float16)a.w;
        h[4] = (_Float16)b.x; h[5] = (_Float16)b.y; h[6] = (_Float16)b.z; h[7] = (_Float16)b.w;
        *(f16x8*)(rawb + SWA(r, g * 16)) = h;
    }
    #pragma unroll
    for (int it = 0; it < 2; it++) {
        int gi = tid + it * 512;
        int r = gi >> 4, g = gi & 15;
        int c = g * 8;
        float dt = sdt[r];
        float4 w0 = *(const float4*)(time_w + c);
        float4 w1 = *(const float4*)(time_w + c + 4);
        float4 t0 = *(const float4*)(time_b + c);
        float4 t1 = *(const float4*)(time_b + c + 4);
        f16x8 h;
        h[0] = (_Float16)tenc(dt, w0.x, t0.x); h[1] = (_Float16)tenc(dt, w0.y, t0.y);
        h[2] = (_Float16)tenc(dt, w0.z, t0.z); h[3] = (_Float16)tenc(dt, w0.w, t0.w);
        h[4] = (_Float16)tenc(dt, w1.x, t1.x); h[5] = (_Float16)tenc(dt, w1.y, t1.y);
        h[6] = (_Float16)tenc(dt, w1.z, t1.z); h[7] = (_Float16)tenc(dt, w1.w, t1.w);
        *(f16x8*)(rawb + SWA(r, (48 + g) * 16)) = h;
    }
    __syncthreads();

    int wv = tid >> 6, lane = tid & 63;
    int arow = lane & 15, kg = lane >> 4;

    f32x4 acc1[2][4];
    #pragma unroll
    for (int c = 0; c < 2; c++)
        #pragma unroll
        for (int rt = 0; rt < 4; rt++) acc1[c][rt] = z4();
    for (int ks = 0; ks < 16; ks++) {
        f16x8 a[4];
        #pragma unroll
        for (int rt = 0; rt < 4; rt++)
            a[rt] = *(const f16x8*)(rawb + SWA(rt * 16 + arow, ks * 64 + kg * 16));
        #pragma unroll
        for (int c = 0; c < 2; c++) {
            f16x8 b = *(const f16x8*)(W1h + (((size_t)(wv * 2 + c) * 16 + ks) * 64 + lane) * 8);
            #pragma unroll
            for (int rt = 0; rt < 4; rt++)
                acc1[c][rt] = MFMA16(a[rt], b, acc1[c][rt]);
        }
    }
    __syncthreads();

    #pragma unroll
    for (int c = 0; c < 2; c++) {
        int col = (wv * 2 + c) * 16 + arow;
        float bb = b1[col];
        #pragma unroll
        for (int rt = 0; rt < 4; rt++)
            #pragma unroll
            for (int rg = 0; rg < 4; rg++) {
                int row = rt * 16 + kg * 4 + rg;
                float v = fmaxf(acc1[c][rt][rg] + bb, 0.f);
                *(_Float16*)(rawb + SWA(row, 384 + col * 2)) = (_Float16)v;
            }
    }
    __syncthreads();

    f32x4 acc2[4];
    #pragma unroll
    for (int rt = 0; rt < 4; rt++) acc2[rt] = z4();
    for (int ks = 0; ks < 8; ks++) {
        f16x8 b = *(const f16x8*)(W2h + (((size_t)wv * 8 + ks) * 64 + lane) * 8);
        #pragma unroll
        for (int rt = 0; rt < 4; rt++) {
            f16x8 a = *(const f16x8*)(rawb + SWA(rt * 16 + arow, 384 + ks * 64 + kg * 16));
            acc2[rt] = MFMA16(a, b, acc2[rt]);
        }
    }
    __syncthreads();

    {
        int col = wv * 16 + arow;
        float bb = b2[col];
        #pragma unroll
        for (int rt = 0; rt < 4; rt++)
            #pragma unroll
            for (int rg = 0; rg < 4; rg++) {
                int row = rt * 16 + kg * 4 + rg;
                *(_Float16*)(rawb + SWA(row, 384 + col * 2)) =
                    (_Float16)(acc2[rt][rg] + bb);
            }
    }
    __syncthreads();

    f32x4 aR[4], aZ[4], aNi[4], aNh[4];
    #pragma unroll
    for (int rt = 0; rt < 4; rt++) { aR[rt] = z4(); aZ[rt] = z4(); aNi[rt] = z4(); aNh[rt] = z4(); }
    for (int ks = 0; ks < 4; ks++) {
        f16x8 bi_ = ldw4(Wih, wv, ks, lane);
        f16x8 bh_ = ldw4(Whh, wv, ks, lane);
        #pragma unroll
        for (int rt = 0; rt < 4; rt++) {
            f16x8 m = *(const f16x8*)(rawb + SWA(rt * 16 + arow, 384 + ks * 64 + kg * 16));
            f16x8 hh = *(const f16x8*)(rawb + SWA(rt * 16 + arow, ks * 64 + kg * 16));
            aR[rt] = MFMA16(m, bi_, aR[rt]);
            aR[rt] = MFMA16(hh, bh_, aR[rt]);
        }
    }
    for (int ks = 0; ks < 4; ks++) {
        f16x8 bi_ = ldw4(Wih, 8 + wv, ks, lane);
        f16x8 bh_ = ldw4(Whh, 8 + wv, ks, lane);
        #pragma unroll
        for (int rt = 0; rt < 4; rt++) {
            f16x8 m = *(const f16x8*)(rawb + SWA(rt * 16 + arow, 384 + ks * 64 + kg * 16));
            f16x8 hh = *(const f16x8*)(rawb + SWA(rt * 16 + arow, ks * 64 + kg * 16));
            aZ[rt] = MFMA16(m, bi_, aZ[rt]);
            aZ[rt] = MFMA16(hh, bh_, aZ[rt]);
        }
    }
    for (int ks = 0; ks < 4; ks++) {
        f16x8 bi_ = ldw4(Wih, 16 + wv, ks, lane);
        f16x8 bh_ = ldw4(Whh, 16 + wv, ks, lane);
        #pragma unroll
        for (int rt = 0; rt < 4; rt++) {
            f16x8 m = *(const f16x8*)(rawb + SWA(rt * 16 + arow, 384 + ks * 64 + kg * 16));
            f16x8 hh = *(const f16x8*)(rawb + SWA(rt * 16 + arow, ks * 64 + kg * 16));
            aNi[rt] = MFMA16(m, bi_, aNi[rt]);
            aNh[rt] = MFMA16(hh, bh_, aNh[rt]);
        }
    }

    {
        int col = wv * 16 + arow;
        float bir = bi[col],        bhr = bh[col];
        float biz = bi[128 + col],  bhz = bh[128 + col];
        float bin_ = bi[256 + col], bhn_ = bh[256 + col];
        #pragma unroll
        for (int rt = 0; rt < 4; rt++)
            #pragma unroll
            for (int rg = 0; rg < 4; rg++) {
                int row = rt * 16 + kg * 4 + rg;
                int rr = r0 + row;
                if (rr < cnt) {
                    float r_ = fsigm(aR[rt][rg] + bir + bhr);
                    float zg = fsigm(aZ[rt][rg] + biz + bhz);
                    float ng = ftanh(aNi[rt][rg] + bin_ + r_ * (aNh[rt][rg] + bhn_));
                    float om = (float)*(const _Float16*)(rawb + SWA(row, col * 2));
                    new_mem[(size_t)rr * 128 + col] = (_Float16)((1.f - zg) * ng + zg * om);
                }
            }
    }
}

// k_feat: feat[n] = (updated ? new_mem[inv[n]] : memory[n]) + node_feats[n], f16.
// Only for referenced nodes (mask) — unreferenced rows are never read downstream.
__global__ __launch_bounds__(256)
void k_feat(const int* __restrict__ inv, const char* __restrict__ mask,
            const _Float16* __restrict__ new_mem,
            const float* __restrict__ memory, const float* __restrict__ node_feats,
            _Float16* __restrict__ feat)
{
    int idx = blockIdx.x * 256 + threadIdx.x;
    if (idx >= NN * 16) return;
    int n = idx >> 4, g = idx & 15;
    if (!mask[n]) return;
    int c = g * 8;
    int iv = inv[n];
    float4 n0 = *(const float4*)(node_feats + (size_t)n * 128 + c);
    float4 n1 = *(const float4*)(node_feats + (size_t)n * 128 + c + 4);
    f16x8 o;
    if (iv >= 0) {
        f16x8 mv = *(const f16x8*)(new_mem + (size_t)iv * 128 + c);
        o[0] = (_Float16)((float)mv[0] + n0.x); o[1] = (_Float16)((float)mv[1] + n0.y);
        o[2] = (_Float16)((float)mv[2] + n0.z); o[3] = (_Float16)((float)mv[3] + n0.w);
        o[4] = (_Float16)((float)mv[4] + n1.x); o[5] = (_Float16)((float)mv[5] + n1.y);
        o[6] = (_Float16)((float)mv[6] + n1.z); o[7] = (_Float16)((float)mv[7] + n1.w);
    } else {
        float4 m0 = *(const float4*)(memory + (size_t)n * 128 + c);
        float4 m1 = *(const float4*)(memory + (size_t)n * 128 + c + 4);
        o[0] = (_Float16)(m0.x + n0.x); o[1] = (_Float16)(m0.y + n0.y);
        o[2] = (_Float16)(m0.z + n0.z); o[3] = (_Float16)(m0.w + n0.w);
        o[4] = (_Float16)(m1.x + n1.x); o[5] = (_Float16)(m1.y + n1.y);
        o[6] = (_Float16)(m1.z + n1.z); o[7] = (_Float16)(m1.w + n1.w);
    }
    *(f16x8*)(feat + (size_t)n * 128 + c) = o;
}

// ---------------- Stage 2 ----------------
// k2b: gather sfeat tile from feat -> q = sfeat@WqL^T + bq2 (LDS) -> qk_h = q_h@Wkt_h.
// Also writes sfeat rows for the tail kernel. (te-part of q folded into bq2.)
__global__ __launch_bounds__(512, 2)
void k2b(const int* __restrict__ src_nodes, const int* __restrict__ dst_nodes,
         const int* __restrict__ neg_nodes, const _Float16* __restrict__ feat,
         const _Float16* __restrict__ WqLh, const float* __restrict__ bq2,
         const _Float16* __restrict__ Wkth,
         _Float16* __restrict__ sfeat, _Float16* __restrict__ qk_ws)
{
    __shared__ char lds[24 * 1024];    // [0,8K): sfeat tile; [8K,24K): q tile
    __shared__ int snode[32];
    int tid = threadIdx.x;
    int r0 = blockIdx.x * 32;

    if (tid < 32) {
        int q = r0 + tid;
        snode[tid] = (q < BB) ? src_nodes[q] : (q < 2 * BB) ? dst_nodes[q - BB] : neg_nodes[q - 2 * BB];
    }
    __syncthreads();

    // gather sfeat tile [32][128] f16 (rows of 256B, swizzled) + write to HBM
    {
        int r = tid >> 4, g = tid & 15;
        f16x8 v = *(const f16x8*)(feat + (size_t)snode[r] * 128 + g * 8);
        *(f16x8*)(&lds[r * 256 + ((g * 16) ^ ((r & 7) << 4))]) = v;
        *(f16x8*)(sfeat + (size_t)(r0 + r) * 128 + g * 8) = v;
    }
    __syncthreads();

    int wv = tid >> 6, lane = tid & 63;
    int arow = lane & 15, kg = lane >> 4;

    // GEMM1: q = sfeat @ WqL^T + bq2; K=128 (KS=4), 16 cgrps / 8 waves -> NFRAG 2
    f32x4 acc[2][2];
    #pragma unroll
    for (int c = 0; c < 2; c++) { acc[c][0] = z4(); acc[c][1] = z4(); }
    for (int ks = 0; ks < 4; ks++) {
        f16x8 a0 = *(const f16x8*)(&lds[arow * 256 + ((ks * 64 + kg * 16) ^ ((arow & 7) << 4))]);
        f16x8 a1 = *(const f16x8*)(&lds[(16 + arow) * 256 + ((ks * 64 + kg * 16) ^ ((arow & 7) << 4))]);
        #pragma unroll
        for (int c = 0; c < 2; c++) {
            f16x8 b = *(const f16x8*)(WqLh + (((size_t)(wv * 2 + c) * 4 + ks) * 64 + lane) * 8);
            acc[c][0] = MFMA16(a0, b, acc[c][0]);
            acc[c][1] = MFMA16(a1, b, acc[c][1]);
        }
    }
    #pragma unroll
    for (int c = 0; c < 2; c++) {
        int col = (wv * 2 + c) * 16 + arow;
        float bb = bq2[col];
        #pragma unroll
        for (int rt = 0; rt < 2; rt++)
            #pragma unroll
            for (int rg = 0; rg < 4; rg++) {
                int row = rt * 16 + kg * 4 + rg;
                *(_Float16*)(&lds[8192 + row * 512 + ((col * 2) ^ ((row & 7) << 4))]) =
                    (_Float16)(acc[c][rt][rg] + bb);
            }
    }
    __syncthreads();

    // GEMM2: qk_h = q_h @ Wkt_h; per-head K=128 (KS=4); waves 0-3 h0, 4-7 h1
    int h = wv >> 2;
    f32x4 acc2[6][2];
    #pragma unroll
    for (int c = 0; c < 6; c++) { acc2[c][0] = z4(); acc2[c][1] = z4(); }
    for (int ks = 0; ks < 4; ks++) {
        f16x8 a0 = *(const f16x8*)(&lds[8192 + arow * 512 +
                    ((h * 256 + ks * 64 + kg * 16) ^ ((arow & 7) << 4))]);
        f16x8 a1 = *(const f16x8*)(&lds[8192 + (16 + arow) * 512 +
                    ((h * 256 + ks * 64 + kg * 16) ^ ((arow & 7) << 4))]);
        #pragma unroll
        for (int c = 0; c < 6; c++) {
            int cgh = (wv & 3) * 6 + c;
            f16x8 b = *(const f16x8*)(Wkth + (size_t)h * 49152 +
                       (((size_t)cgh * 4 + ks) * 64 + lane) * 8);
            acc2[c][0] = MFMA16(a0, b, acc2[c][0]);
            acc2[c][1] = MFMA16(a1, b, acc2[c][1]);
        }
    }
    #pragma unroll
    for (int c = 0; c < 6; c++) {
        int cgh = (wv & 3) * 6 + c;
        int col = h * 384 + cgh * 16 + arow;
        #pragma unroll
        for (int rt = 0; rt < 2; rt++)
            #pragma unroll
            for (int rg = 0; rg < 4; rg++) {
                int row = rt * 16 + kg * 4 + rg;
                qk_ws[(size_t)(r0 + row) * 768 + col] = (_Float16)acc2[c][rt][rg];
            }
    }
}

// generic 32-row-tile MFMA GEMM, fragment-ordered B (used for Wv fold only).
template<int KD, int NFRAG, bool RELU>
__global__ __launch_bounds__(256, 4)
void k_gemm(const _Float16* __restrict__ A, int lda, int a_ys,
            const _Float16* __restrict__ B, int b_ys,
            const float* __restrict__ bias, int bias_ys,
            _Float16* __restrict__ C, int ldc, int c_ys,
            float* __restrict__ C32,
            const int* __restrict__ rowmask)
{
    constexpr int ROWB = KD * 2;
    __shared__ char As[32 * ROWB];
    int tid = threadIdx.x;
    int r0 = blockIdx.x * 32;
    int aoff = blockIdx.y * a_ys;
    const _Float16* Bp = B + (size_t)blockIdx.y * b_ys;
    int coff = blockIdx.y * c_ys;

    #pragma unroll
    for (int t = 0; t < (32 * KD / 8) / 256; t++) {
        int gi = tid + t * 256;
        int r = gi / (KD / 8), g = gi % (KD / 8);
        f16x8 v = *(const f16x8*)(A + (size_t)(r0 + r) * lda + aoff + g * 8);
        *(f16x8*)(&As[r * ROWB + ((g * 16) ^ ((r & 7) << 4))]) = v;
    }
    __syncthreads();

    int wv = tid >> 6, lane = tid & 63;
    int arow = lane & 15, kg = lane >> 4;
    f32x4 acc[NFRAG][2];
    #pragma unroll
    for (int c = 0; c < NFRAG; c++) { acc[c][0] = z4(); acc[c][1] = z4(); }

    #pragma unroll
    for (int ks = 0; ks < KD / 32; ks++) {
        f16x8 a0 = *(const f16x8*)(&As[arow * ROWB + ((ks * 64 + kg * 16) ^ ((arow & 7) << 4))]);
        f16x8 a1 = *(const f16x8*)(&As[(16 + arow) * ROWB + ((ks * 64 + kg * 16) ^ ((arow & 7) << 4))]);
        #pragma unroll
        for (int c = 0; c < NFRAG; c++) {
            f16x8 b = *(const f16x8*)(Bp +
                (((size_t)(wv * NFRAG + c) * (KD / 32) + ks) * 64 + lane) * 8);
            acc[c][0] = MFMA16(a0, b, acc[c][0]);
            acc[c][1] = MFMA16(a1, b, acc[c][1]);
        }
    }

    #pragma unroll
    for (int c = 0; c < NFRAG; c++) {
        int cg = (wv * NFRAG + c) * 16 + arow;
        float bb = bias ? bias[blockIdx.y * bias_ys + cg] : 0.f;
        #pragma unroll
        for (int rt = 0; rt < 2; rt++)
            #pragma unroll
            for (int rg = 0; rg < 4; rg++) {
                int grow = r0 + rt * 16 + kg * 4 + rg;
                float v = acc[c][rt][rg] + bb;
                if (RELU) v = fmaxf(v, 0.f);
                if (rowmask && rowmask[grow]) v = 0.f;
                if (C)   C[(size_t)grow * ldc + coff + cg] = (_Float16)v;
                if (C32) C32[(size_t)grow * ldc + coff + cg] = v;
            }
    }
}

// k2d: attention core (R10-exact). 1 query/wave, head per half-wave, no LDS,
// depth-1 pipelined gathers; q.bk shift dropped (softmax shift-invariance).
__global__ __launch_bounds__(256)
void k2d(const int* __restrict__ neighbors, const int* __restrict__ nb_eidx,
         const int* __restrict__ nb_et, const int* __restrict__ edge_times,
         const _Float16* __restrict__ feat,
         const float* __restrict__ edge_feats, const float* __restrict__ time_w,
         const float* __restrict__ time_b,
         _Float16* __restrict__ qk_wsum, int* __restrict__ allm)
{
    int tid = threadIdx.x;
    int qi = blockIdx.x * 4 + (tid >> 6);
    int lane = tid & 63;
    int h = lane >> 5, l32 = lane & 31;
    int c0 = l32 * 4;

    float4 tw = *(const float4*)(time_w + c0);
    float4 tb = *(const float4*)(time_b + c0);

    const _Float16* qkp = qk_wsum + (size_t)qi * 768 + h * 384;
    f16x4 t0 = *(const f16x4*)(qkp + c0);
    f16x4 t1 = *(const f16x4*)(qkp + 128 + c0);
    f16x4 t2 = *(const f16x4*)(qkp + 256 + c0);
    float qk0[4], qk1[4], qk2[4];
    #pragma unroll
    for (int t = 0; t < 4; t++) { qk0[t] = (float)t0[t]; qk1[t] = (float)t1[t]; qk2[t] = (float)t2[t]; }

    float ts = (float)edge_times[qi & (BB - 1)];
    float m_run = -3.0e38f, l_run = 0.f;
    float w0[4] = {0,0,0,0}, w1[4] = {0,0,0,0}, w2[4] = {0,0,0,0};
    int anyv = 0;
    const float inv_sqrt = 0.08838834764831845f;

    int base = qi * KK;
    int nb_c = neighbors[base];
    int ei_c = nb_eidx[base];
    int et_c = nb_et[base];
    f16x4 fv;
    float4 ef;
    {
        fv = *(const f16x4*)(feat + (size_t)nb_c * 128 + c0);
        ef = *(const float4*)(edge_feats + (size_t)ei_c * 128 + c0);
    }

    for (int j = 0; j < KK; j++) {
        int nb_n = 0, ei_n = 0, et_n = 0;
        f16x4 fv_n = {0,0,0,0};
        float4 ef_n = {0,0,0,0};
        if (j + 1 < KK) {
            nb_n = neighbors[base + j + 1];
            ei_n = nb_eidx[base + j + 1];
            et_n = nb_et[base + j + 1];
            fv_n = *(const f16x4*)(feat + (size_t)nb_n * 128 + c0);
            ef_n = *(const float4*)(edge_feats + (size_t)ei_n * 128 + c0);
        }

        float dtf = ts - (float)et_c;
        anyv |= (nb_c != 0);
        float k0[4] = { (float)fv[0], (float)fv[1], (float)fv[2], (float)fv[3] };
        float k1[4] = { tenc(dtf, tw.x, tb.x), tenc(dtf, tw.y, tb.y),
                        tenc(dtf, tw.z, tb.z), tenc(dtf, tw.w, tb.w) };
        float k2[4] = { ef.x, ef.y, ef.z, ef.w };

        float sp = 0.f;
        #pragma unroll
        for (int t = 0; t < 4; t++)
            sp += qk0[t] * k0[t] + qk1[t] * k1[t] + qk2[t] * k2[t];
        sp += __shfl_xor(sp, 1, 32);
        sp += __shfl_xor(sp, 2, 32);
        sp += __shfl_xor(sp, 4, 32);
        sp += __shfl_xor(sp, 8, 32);
        sp += __shfl_xor(sp, 16, 32);

        float s = sp * inv_sqrt;
        if (nb_c == 0) s = -1e9f;
        float m_new = fmaxf(m_run, s);
        float sc = __expf(m_run - m_new);
        float p = __expf(s - m_new);
        l_run = l_run * sc + p;
        #pragma unroll
        for (int t = 0; t < 4; t++) {
            w0[t] = w0[t] * sc + p * k0[t];
            w1[t] = w1[t] * sc + p * k1[t];
            w2[t] = w2[t] * sc + p * k2[t];
        }
        m_run = m_new;

        nb_c = nb_n; ei_c = ei_n; et_c = et_n;
        fv = fv_n; ef = ef_n;
    }

    float linv = __builtin_amdgcn_rcpf(l_run);
    _Float16* wp = qk_wsum + (size_t)qi * 768 + h * 384;
    f16x4 o0, o1, o2;
    #pragma unroll
    for (int t = 0; t < 4; t++) {
        o0[t] = (_Float16)(w0[t] * linv);
        o1[t] = (_Float16)(w1[t] * linv);
        o2[t] = (_Float16)(w2[t] * linv);
    }
    *(f16x4*)(wp + c0) = o0;
    *(f16x4*)(wp + 128 + c0) = o1;
    *(f16x4*)(wp + 256 + c0) = o2;
    if (lane == 0) allm[qi] = anyv ? 0 : 1;
}

// k2t2: fused tail. attn = ctx@Wo^T + bo (masked) -> hm = relu([attn|sfeat]@mW1+mb1)
// -> out = hm@mW2 + mb2. Same GEMM shapes as the separate kernels.
__global__ __launch_bounds__(256, 2)
void k2t2(const _Float16* __restrict__ ctx, const _Float16* __restrict__ sfeat,
          const _Float16* __restrict__ Woh, const float* __restrict__ bo,
          const _Float16* __restrict__ mW1h, const float* __restrict__ mb1,
          const _Float16* __restrict__ mW2h, const float* __restrict__ mb2,
          const int* __restrict__ allm, float* __restrict__ out)
{
    __shared__ char lds[48 * 1024];   // A[0,16K): ctx; B[16K,40K): [attn|sfeat]; C[40K,48K): hm
    int tid = threadIdx.x;
    int r0 = blockIdx.x * 32;

    // stage ctx tile [32][256] f16 (rows of 512B, swizzled): 1024 granules -> 4 iters
    #pragma unroll
    for (int t = 0; t < 4; t++) {
        int gi = tid + t * 256;
        int r = gi >> 5, g = gi & 31;
        f16x8 v = *(const f16x8*)(ctx + (size_t)(r0 + r) * 256 + g * 8);
        *(f16x8*)(&lds[r * 512 + ((g * 16) ^ ((r & 7) << 4))]) = v;
    }
    __syncthreads();

    int wv = tid >> 6, lane = tid & 63;
    int arow = lane & 15, kg = lane >> 4;

    // GEMM1: attn = ctx @ Wo^T + bo; K=256 (KS=8), 16 cgrps / 4 waves -> NFRAG 4
    f32x4 acc[4][2];
    #pragma unroll
    for (int c = 0; c < 4; c++) { acc[c][0] = z4(); acc[c][1] = z4(); }
    for (int ks = 0; ks < 8; ks++) {
        f16x8 a0 = *(const f16x8*)(&lds[arow * 512 + ((ks * 64 + kg * 16) ^ ((arow & 7) << 4))]);
        f16x8 a1 = *(const f16x8*)(&lds[(16 + arow) * 512 + ((ks * 64 + kg * 16) ^ ((arow & 7) << 4))]);
        #pragma unroll
        for (int c = 0; c < 4; c++) {
            f16x8 b = *(const f16x8*)(Woh + (((size_t)(wv * 4 + c) * 8 + ks) * 64 + lane) * 8);
            acc[c][0] = MFMA16(a0, b, acc[c][0]);
            acc[c][1] = MFMA16(a1, b, acc[c][1]);
        }
    }
    // write attn (masked) into B region cols 0..255 (rows of 768B)
    #pragma unroll
    for (int c = 0; c < 4; c++) {
        int col = (wv * 4 + c) * 16 + arow;
        float bb = bo[col];
        #pragma unroll
        for (int rt = 0; rt < 2; rt++)
            #pragma unroll
            for (int rg = 0; rg < 4; rg++) {
                int row = rt * 16 + kg * 4 + rg;
                float v = allm[r0 + row] ? 0.f : (acc[c][rt][rg] + bb);
                *(_Float16*)(&lds[16384 + row * 768 + ((col * 2) ^ ((row & 7) << 4))]) = (_Float16)v;
            }
    }
    // load sfeat rows into B cols 256..383
    #pragma unroll
    for (int t = 0; t < 2; t++) {
        int gi = tid + t * 256;
        int r = gi >> 4, g = gi & 15;
        f16x8 v = *(const f16x8*)(sfeat + (size_t)(r0 + r) * 128 + g * 8);
        *(f16x8*)(&lds[16384 + r * 768 + ((512 + g * 16) ^ ((r & 7) << 4))]) = v;
    }
    __syncthreads();

    // GEMM2: hm = relu([attn|sfeat] @ mW1^T + mb1); K=384 (KS=12), 8 cgrps -> NFRAG 2
    f32x4 acc2[2][2];
    #pragma unroll
    for (int c = 0; c < 2; c++) { acc2[c][0] = z4(); acc2[c][1] = z4(); }
    for (int ks = 0; ks < 12; ks++) {
        f16x8 a0 = *(const f16x8*)(&lds[16384 + arow * 768 + ((ks * 64 + kg * 16) ^ ((arow & 7) << 4))]);
        f16x8 a1 = *(const f16x8*)(&lds[16384 + (16 + arow) * 768 + ((ks * 64 + kg * 16) ^ ((arow & 7) << 4))]);
        #pragma unroll
        for (int c = 0; c < 2; c++) {
            f16x8 b = *(const f16x8*)(mW1h + (((size_t)(wv * 2 + c) * 12 + ks) * 64 + lane) * 8);
            acc2[c][0] = MFMA16(a0, b, acc2[c][0]);
            acc2[c][1] = MFMA16(a1, b, acc2[c][1]);
        }
    }
    #pragma unroll
    for (int c = 0; c < 2; c++) {
        int col = (wv * 2 + c) * 16 + arow;
        float bb = mb1[col];
        #pragma unroll
        for (int rt = 0; rt < 2; rt++)
            #pragma unroll
            for (int rg = 0; rg < 4; rg++) {
                int row = rt * 16 + kg * 4 + rg;
                float v = fmaxf(acc2[c][rt][rg] + bb, 0.f);
                *(_Float16*)(&lds[40960 + row * 256 + ((col * 2) ^ ((row & 7) << 4))]) = (_Float16)v;
            }
    }
    __syncthreads();

    // GEMM3: out = hm @ mW2^T + mb2; K=128 (KS=4), 8 cgrps -> NFRAG 2, f32 out
    f32x4 acc3[2][2];
    #pragma unroll
    for (int c = 0; c < 2; c++) { acc3[c][0] = z4(); acc3[c][1] = z4(); }
    for (int ks = 0; ks < 4; ks++) {
        f16x8 a0 = *(const f16x8*)(&lds[40960 + arow * 256 + ((ks * 64 + kg * 16) ^ ((arow & 7) << 4))]);
        f16x8 a1 = *(const f16x8*)(&lds[40960 + (16 + arow) * 256 + ((ks * 64 + kg * 16) ^ ((arow & 7) << 4))]);
        #pragma unroll
        for (int c = 0; c < 2; c++) {
            f16x8 b = *(const f16x8*)(mW2h + (((size_t)(wv * 2 + c) * 4 + ks) * 64 + lane) * 8);
            acc3[c][0] = MFMA16(a0, b, acc3[c][0]);
            acc3[c][1] = MFMA16(a1, b, acc3[c][1]);
        }
    }
    #pragma unroll
    for (int c = 0; c < 2; c++) {
        int col = (wv * 2 + c) * 16 + arow;
        float bb = mb2[col];
        #pragma unroll
        for (int rt = 0; rt < 2; rt++)
            #pragma unroll
            for (int rg = 0; rg < 4; rg++) {
                int row = rt * 16 + kg * 4 + rg;
                out[(size_t)(r0 + row) * 128 + col] = acc3[c][rt][rg] + bb;
            }
    }
}

extern "C" void kernel_launch(void* const* d_in, const int* in_sizes, int n_in,
                              void* d_out, int out_size, void* d_ws, size_t ws_size,
                              hipStream_t stream) {
    (void)in_sizes; (void)n_in; (void)out_size; (void)ws_size;
    const int* src_nodes  = (const int*)d_in[0];
    const int* dst_nodes  = (const int*)d_in[1];
    const int* neg_nodes  = (const int*)d_in[2];
    const int* edge_times = (const int*)d_in[3];
    const int* neighbors  = (const int*)d_in[4];
    const int* nb_eidx    = (const int*)d_in[5];
    const int* nb_et      = (const int*)d_in[6];
    const int* msg_src    = (const int*)d_in[7];
    const int* msg_dst    = (const int*)d_in[8];
    const int* msg_eidx   = (const int*)d_in[9];
    const int* msg_t      = (const int*)d_in[10];
    const int* last_update= (const int*)d_in[11];
    const float* node_feats = (const float*)d_in[12];
    const float* edge_feats = (const float*)d_in[13];
    const float* memory     = (const float*)d_in[14];
    const float* time_w = (const float*)d_in[15];
    const float* time_b = (const float*)d_in[16];
    const float* W1 = (const float*)d_in[17];
    const float* b1 = (const float*)d_in[18];
    const float* W2 = (const float*)d_in[19];
    const float* b2 = (const float*)d_in[20];
    const float* gWi = (const float*)d_in[21];
    const float* gWh = (const float*)d_in[22];
    const float* gbi = (const float*)d_in[23];
    const float* gbh = (const float*)d_in[24];
    const float* Wq = (const float*)d_in[25];
    const float* bq = (const float*)d_in[26];
    const float* Wk = (const float*)d_in[27];
    const float* bk = (const float*)d_in[28];
    const float* Wv = (const float*)d_in[29];
    const float* bv = (const float*)d_in[30];
    const float* Wo = (const float*)d_in[31];
    const float* bo = (const float*)d_in[32];
    const float* mW1 = (const float*)d_in[33];
    const float* mb1 = (const float*)d_in[34];
    const float* mW2 = (const float*)d_in[35];
    const float* mb2 = (const float*)d_in[36];
    float* out = (float*)d_out;
    (void)bk;

    char* w = (char*)d_ws;
    int* lastpos = (int*)w;
    int* inv  = lastpos + NN;
    int* comp = inv + NN;
    int* count = comp + NN;
    int* bcnt = count + 1;
    int* boff = bcnt + NBLK;
    char* mask = (char*)(boff + NBLK);                // NN bytes
    size_t off = ((size_t)(3 * NN + 1 + 2 * NBLK) * 4 + NN + 255) & ~(size_t)255;
    _Float16* new_mem = (_Float16*)(w + off);         // MM*128 f16
    size_t foff = off + (size_t)MM * 128 * 2;
    _Float16* feat = (_Float16*)(w + foff);           // NN*128 f16
    size_t woff = foff + (size_t)NN * 128 * 2;

    _Float16* Hpool = (_Float16*)(w + woff);          // 622592 f16, fragment order
    _Float16* W1h  = Hpool;
    _Float16* W2h  = Hpool + 131072;
    _Float16* Wih  = Hpool + 163840;
    _Float16* Whh  = Hpool + 212992;
    _Float16* WqLh = Hpool + 262144;
    _Float16* Wvh  = Hpool + 294912;
    _Float16* Woh  = Hpool + 393216;
    _Float16* mW1h = Hpool + 458752;
    _Float16* mW2h = Hpool + 507904;
    _Float16* Wkth = Hpool + 524288;
    float* bq2 = (float*)(Hpool + 622592);            // 256 f32
    size_t boff2 = woff + (size_t)622592 * 2 + 1024;

    _Float16* ctx   = (_Float16*)(w + boff2);         // Q3*256
    _Float16* qk_ws = ctx + (size_t)Q3 * 256;         // Q3*768
    _Float16* sfeat = qk_ws + (size_t)Q3 * 768;       // Q3*128
    int* allm       = (int*)(sfeat + (size_t)Q3 * 128);

    k_init<<<dim3(NBLK), dim3(256), 0, stream>>>(lastpos, inv, mask);
    k_scatter<<<dim3((MM + 255) / 256), dim3(256), 0, stream>>>(msg_src, lastpos);
    k_mark<<<dim3((Q3 + Q3 * KK + 255) / 256), dim3(256), 0, stream>>>(
        src_nodes, dst_nodes, neg_nodes, neighbors, mask);
    k_count<<<dim3(NBLK), dim3(256), 0, stream>>>(lastpos, bcnt);
    k_scan<<<dim3(1), dim3(256), 0, stream>>>(bcnt, boff, count);
    k_fill<<<dim3(NBLK), dim3(256), 0, stream>>>(lastpos, boff, comp, inv);
    k_cvtw<<<dim3(304), dim3(256), 0, stream>>>(W1, W2, gWi, gWh, Wq, Wv, Wo, mW1, mW2, Wk, Hpool);
    k_prep<<<dim3(1), dim3(256), 0, stream>>>(Wq, bq, time_b, bq2);
    k_stage1<<<dim3((MM + 63) / 64), dim3(512), 0, stream>>>(
        comp, count, lastpos, msg_dst, msg_eidx, msg_t, last_update,
        memory, edge_feats, time_w, time_b,
        W1h, b1, W2h, b2, Wih, Whh, gbi, gbh, new_mem);
    k_feat<<<dim3(NN * 16 / 256), dim3(256), 0, stream>>>(
        inv, mask, new_mem, memory, node_feats, feat);

    // q = sfeat@WqL + bq2 -> qk per head (q never leaves LDS; sfeat written out)
    k2b<<<dim3(Q3 / 32), dim3(512), 0, stream>>>(
        src_nodes, dst_nodes, neg_nodes, feat, WqLh, bq2, Wkth, sfeat, qk_ws);
    k2d<<<dim3(Q3 / 4), dim3(256), 0, stream>>>(
        neighbors, nb_eidx, nb_et, edge_times, feat,
        edge_feats, time_w, time_b, qk_ws, allm);
    // ctx_h = wsum_h @ Wv_h^T + bv_h (per head)
    k_gemm<384, 2, false><<<dim3(Q3 / 32, 2), dim3(256), 0, stream>>>(
        qk_ws, 768, 384, Wvh, 49152, bv, 128, ctx, 256, 128, nullptr, nullptr);
    // fused tail: attn(Wo) -> merge MLP -> out
    k2t2<<<dim3(Q3 / 32), dim3(256), 0, stream>>>(
        ctx, sfeat, Woh, bo, mW1h, mb1, mW2h, mb2, allm, out);
}